// Round 3
// baseline (6232.665 us; speedup 1.0000x reference)
//
#include <hip/hip_runtime.h>
#include <cstdint>
#include <cstddef>

// ============================================================================
// Threefry2x32 (matches jax._src.prng.threefry2x32: 20 rounds, key-schedule
// injection every 4 rounds, parity constant 0x1BD11BDA).
// ============================================================================
__host__ __device__ inline void threefry2x32(uint32_t k0, uint32_t k1,
                                             uint32_t x0, uint32_t x1,
                                             uint32_t& o0, uint32_t& o1) {
  uint32_t ks2 = k0 ^ k1 ^ 0x1BD11BDAu;
  uint32_t v0 = x0 + k0, v1 = x1 + k1;
#define TF_R(r) { v0 += v1; v1 = (v1 << (r)) | (v1 >> (32 - (r))); v1 ^= v0; }
  TF_R(13) TF_R(15) TF_R(26) TF_R(6)
  v0 += k1; v1 += ks2 + 1u;
  TF_R(17) TF_R(29) TF_R(16) TF_R(24)
  v0 += ks2; v1 += k0 + 2u;
  TF_R(13) TF_R(15) TF_R(26) TF_R(6)
  v0 += k0; v1 += k1 + 3u;
  TF_R(17) TF_R(29) TF_R(16) TF_R(24)
  v0 += k1; v1 += ks2 + 4u;
  TF_R(13) TF_R(15) TF_R(26) TF_R(6)
  v0 += ks2; v1 += k0 + 5u;
#undef TF_R
  o0 = v0; o1 = v1;
}

// jax partitionable random_bits, bit_width=32:
//   bits = shift_right_logical(bits1, 32-32) ^ bits2 = o0 ^ o1
// with counts = 64-bit flat iota -> (hi=0, lo=j).
__device__ __forceinline__ uint32_t tf_bits32(uint32_t k0, uint32_t k1, uint32_t j) {
  uint32_t o0, o1;
  threefry2x32(k0, k1, 0u, j, o0, o1);
  return o0 ^ o1;
}

__device__ __forceinline__ float u01_from_bits(uint32_t bits) {
  return __uint_as_float((bits >> 9) | 0x3f800000u) - 1.0f;  // [0,1)
}

__device__ __forceinline__ float waveSum(float v) {
#pragma unroll
  for (int off = 32; off > 0; off >>= 1) v += __shfl_down(v, off, 64);
  return v;
}

// ============================================================================
// conv1 (3->32, 32x32, pad1) pass A: per-channel (sum,sumsq) partials only.
// grid 16384 = B*4 (8 rows each), block 256 = 8x32 pixels. LDS ~7 KB.
// ============================================================================
__global__ __launch_bounds__(256) void conv1_stats_kernel(
    const float* __restrict__ in, const float* __restrict__ w,
    float* __restrict__ partials) {
  __shared__ float ins[3 * 10 * 34];
  __shared__ float ws[32 * 3 * 12];
  __shared__ float red[4][64];
  const int blk = blockIdx.x, t = threadIdx.x;
  const int b = blk >> 2, r0 = (blk & 3) << 3;
  for (int i = t; i < 32 * 27; i += 256) {
    int cor = i / 9, k = i % 9;
    ws[cor * 12 + k] = w[i];
  }
  for (int i = t; i < 3 * 10 * 34; i += 256) {
    int ci = i / 340, r = i % 340, iy = r / 34, ix = r % 34;
    int y = r0 - 1 + iy, x = ix - 1;
    float v = 0.f;
    if ((unsigned)y < 32u && (unsigned)x < 32u)
      v = in[(((size_t)b * 3 + ci) * 32 + y) * 32 + x];
    ins[i] = v;
  }
  __syncthreads();
  const int ly = t >> 5, x = t & 31, wv = t >> 6, ln = t & 63;
  float win[27];
#pragma unroll
  for (int ci = 0; ci < 3; ci++)
#pragma unroll
    for (int dy = 0; dy < 3; dy++)
#pragma unroll
      for (int dx = 0; dx < 3; dx++)
        win[ci * 9 + dy * 3 + dx] = ins[ci * 340 + (ly + dy) * 34 + (x + dx)];
#pragma unroll 1
  for (int co = 0; co < 32; co++) {
    float a = 0.f;
#pragma unroll
    for (int ci = 0; ci < 3; ci++) {
      const float* wp = &ws[(co * 3 + ci) * 12];
      float4 wA = *(const float4*)wp;
      float4 wB = *(const float4*)(wp + 4);
      float w8 = wp[8];
      a += win[ci * 9 + 0] * wA.x + win[ci * 9 + 1] * wA.y + win[ci * 9 + 2] * wA.z +
           win[ci * 9 + 3] * wA.w + win[ci * 9 + 4] * wB.x + win[ci * 9 + 5] * wB.y +
           win[ci * 9 + 6] * wB.z + win[ci * 9 + 7] * wB.w + win[ci * 9 + 8] * w8;
    }
    float s = waveSum(a), sq = waveSum(a * a);
    if (ln == 0) { red[wv][2 * co] = s; red[wv][2 * co + 1] = sq; }
  }
  __syncthreads();
  for (int i = t; i < 64; i += 256)
    partials[(size_t)blk * 64 + i] = red[0][i] + red[1][i] + red[2][i] + red[3][i];
}

// conv1 pass B: recompute conv, apply BN+ReLU, 2x2 maxpool -> pooled1.
// grid 4096 (b), block 256 = 16x16 pooled pixels. LDS ~15.5 KB.
__global__ __launch_bounds__(256) void conv1_apply_kernel(
    const float* __restrict__ in, const float* __restrict__ w,
    const float* __restrict__ scale, const float* __restrict__ shift,
    float* __restrict__ out) {
  __shared__ float ins[3 * 34 * 34];
  __shared__ float ws[32 * 3 * 12];
  const int b = blockIdx.x, t = threadIdx.x;
  for (int i = t; i < 32 * 27; i += 256) {
    int cor = i / 9, k = i % 9;
    ws[cor * 12 + k] = w[i];
  }
  for (int i = t; i < 3 * 34 * 34; i += 256) {
    int ci = i / 1156, r = i % 1156, iy = r / 34, ix = r % 34;
    int y = iy - 1, x = ix - 1;
    float v = 0.f;
    if ((unsigned)y < 32u && (unsigned)x < 32u)
      v = in[(((size_t)b * 3 + ci) * 32 + y) * 32 + x];
    ins[i] = v;
  }
  __syncthreads();
  const int py = t >> 4, px = t & 15;
  float win[3][4][4];
#pragma unroll
  for (int ci = 0; ci < 3; ci++)
#pragma unroll
    for (int r = 0; r < 4; r++)
#pragma unroll
      for (int c = 0; c < 4; c++)
        win[ci][r][c] = ins[ci * 1156 + (2 * py + r) * 34 + (2 * px + c)];
#pragma unroll 1
  for (int co = 0; co < 32; co++) {
    float acc00 = 0.f, acc01 = 0.f, acc10 = 0.f, acc11 = 0.f;
#pragma unroll
    for (int ci = 0; ci < 3; ci++) {
      const float* wp = &ws[(co * 3 + ci) * 12];
      float4 wA = *(const float4*)wp;
      float4 wB = *(const float4*)(wp + 4);
      float w8 = wp[8];
      float wr[9] = {wA.x, wA.y, wA.z, wA.w, wB.x, wB.y, wB.z, wB.w, w8};
#pragma unroll
      for (int dy = 0; dy < 3; dy++)
#pragma unroll
        for (int dx = 0; dx < 3; dx++) {
          float wv = wr[dy * 3 + dx];
          acc00 += win[ci][dy][dx] * wv;
          acc01 += win[ci][dy][dx + 1] * wv;
          acc10 += win[ci][dy + 1][dx] * wv;
          acc11 += win[ci][dy + 1][dx + 1] * wv;
        }
    }
    float sc = scale[co], sh = shift[co];
    float best = 0.f;  // init 0 == ReLU folded into max
    best = fmaxf(best, acc00 * sc + sh);
    best = fmaxf(best, acc01 * sc + sh);
    best = fmaxf(best, acc10 * sc + sh);
    best = fmaxf(best, acc11 * sc + sh);
    out[(((size_t)b * 32 + co) * 16 + py) * 16 + px] = best;
  }
}

// ============================================================================
// conv2 (32->64, 16x16, pad1) pass A: stats only. 8 co-chunks of 8.
// grid 4096 (b), block 256 = 16x16 pixels. LDS ~56 KB.
// ============================================================================
__global__ __launch_bounds__(256) void conv2_stats_kernel(
    const float* __restrict__ in, const float* __restrict__ w,
    float* __restrict__ partials) {
  __shared__ float ins[32 * 18 * 18];
  __shared__ float ws[8 * 32 * 12];
  __shared__ float red[4][128];
  const int b = blockIdx.x, t = threadIdx.x;
  for (int i = t; i < 32 * 18 * 18; i += 256) {
    int ci = i / 324, r = i % 324, iy = r / 18, ix = r % 18;
    int y = iy - 1, x = ix - 1;
    float v = 0.f;
    if ((unsigned)y < 16u && (unsigned)x < 16u)
      v = in[(((size_t)b * 32 + ci) * 16 + y) * 16 + x];
    ins[i] = v;
  }
  const int y = t >> 4, x = t & 15, wv = t >> 6, ln = t & 63;
  for (int cc = 0; cc < 8; cc++) {
    __syncthreads();
    for (int i = t; i < 8 * 32 * 9; i += 256) {
      int cor = i / 9, k = i % 9;
      ws[cor * 12 + k] = w[cc * (8 * 32 * 9) + i];
    }
    __syncthreads();
    float acc[8];
#pragma unroll
    for (int i = 0; i < 8; i++) acc[i] = 0.f;
#pragma unroll 1
    for (int ci = 0; ci < 32; ci++) {
      float vals[9];
#pragma unroll
      for (int dy = 0; dy < 3; dy++)
#pragma unroll
        for (int dx = 0; dx < 3; dx++)
          vals[dy * 3 + dx] = ins[ci * 324 + (y + dy) * 18 + (x + dx)];
#pragma unroll
      for (int co = 0; co < 8; co++) {
        const float* wp = &ws[(co * 32 + ci) * 12];
        float4 wA = *(const float4*)wp;
        float4 wB = *(const float4*)(wp + 4);
        float w8 = wp[8];
        acc[co] += vals[0] * wA.x + vals[1] * wA.y + vals[2] * wA.z + vals[3] * wA.w +
                   vals[4] * wB.x + vals[5] * wB.y + vals[6] * wB.z + vals[7] * wB.w +
                   vals[8] * w8;
      }
    }
#pragma unroll
    for (int co = 0; co < 8; co++) {
      float a = acc[co];
      float s = waveSum(a), sq = waveSum(a * a);
      if (ln == 0) { red[wv][2 * (cc * 8 + co)] = s; red[wv][2 * (cc * 8 + co) + 1] = sq; }
    }
  }
  __syncthreads();
  for (int i = t; i < 128; i += 256)
    partials[(size_t)b * 128 + i] = red[0][i] + red[1][i] + red[2][i] + red[3][i];
}

// conv2 pass B: recompute conv2, BN+ReLU+2x2 pool fused -> pool2 [4096][64][8][8].
// LDS ~62 KB.
__global__ __launch_bounds__(256) void conv2_apply_kernel(
    const float* __restrict__ in, const float* __restrict__ w,
    const float* __restrict__ scale, const float* __restrict__ shift,
    float* __restrict__ out) {
  __shared__ float ins[32 * 18 * 18];
  __shared__ float ws[8 * 32 * 12];
  __shared__ float os[8 * 256];
  const int b = blockIdx.x, t = threadIdx.x;
  for (int i = t; i < 32 * 18 * 18; i += 256) {
    int ci = i / 324, r = i % 324, iy = r / 18, ix = r % 18;
    int y = iy - 1, x = ix - 1;
    float v = 0.f;
    if ((unsigned)y < 16u && (unsigned)x < 16u)
      v = in[(((size_t)b * 32 + ci) * 16 + y) * 16 + x];
    ins[i] = v;
  }
  const int y = t >> 4, x = t & 15;
  for (int cc = 0; cc < 8; cc++) {
    __syncthreads();  // protects ins (first iter), ws and os (later iters)
    for (int i = t; i < 8 * 32 * 9; i += 256) {
      int cor = i / 9, k = i % 9;
      ws[cor * 12 + k] = w[cc * (8 * 32 * 9) + i];
    }
    __syncthreads();
    float acc[8];
#pragma unroll
    for (int i = 0; i < 8; i++) acc[i] = 0.f;
#pragma unroll 1
    for (int ci = 0; ci < 32; ci++) {
      float vals[9];
#pragma unroll
      for (int dy = 0; dy < 3; dy++)
#pragma unroll
        for (int dx = 0; dx < 3; dx++)
          vals[dy * 3 + dx] = ins[ci * 324 + (y + dy) * 18 + (x + dx)];
#pragma unroll
      for (int co = 0; co < 8; co++) {
        const float* wp = &ws[(co * 32 + ci) * 12];
        float4 wA = *(const float4*)wp;
        float4 wB = *(const float4*)(wp + 4);
        float w8 = wp[8];
        acc[co] += vals[0] * wA.x + vals[1] * wA.y + vals[2] * wA.z + vals[3] * wA.w +
                   vals[4] * wB.x + vals[5] * wB.y + vals[6] * wB.z + vals[7] * wB.w +
                   vals[8] * w8;
      }
    }
#pragma unroll
    for (int co = 0; co < 8; co++) os[co * 256 + t] = acc[co];
    __syncthreads();
    for (int i = t; i < 8 * 64; i += 256) {
      int co = i >> 6, pl = i & 63, py = pl >> 3, px = pl & 7;
      int c = cc * 8 + co;
      float sc = scale[c], sh = shift[c];
      const float* o = &os[co * 256 + (2 * py) * 16 + 2 * px];
      float m = 0.f;  // ReLU folded
      m = fmaxf(m, o[0] * sc + sh);
      m = fmaxf(m, o[1] * sc + sh);
      m = fmaxf(m, o[16] * sc + sh);
      m = fmaxf(m, o[17] * sc + sh);
      out[(((size_t)b * 64 + c) * 8 + py) * 8 + px] = m;
    }
  }
}

// ============================================================================
// conv3 (64->128, 8x8, pad1): STATS=1 -> partials only; STATS=0 -> BN+ReLU store.
// grid 4096 (b), block 256 = 64 px x 4 co-groups of 32. ci chunks of 4. LDS ~51 KB.
// ============================================================================
template <int STATS>
__global__ __launch_bounds__(256) void conv3_kernel(
    const float* __restrict__ in, const float* __restrict__ w,
    const float* __restrict__ scale, const float* __restrict__ shift,
    float* __restrict__ out, float* __restrict__ partials) {
  __shared__ float ins[64 * 10 * 10];
  __shared__ float ws[128 * 4 * 12];
  __shared__ float red[256];
  const int b = blockIdx.x, t = threadIdx.x;
  for (int i = t; i < 64 * 10 * 10; i += 256) {
    int ci = i / 100, r = i % 100, iy = r / 10, ix = r % 10;
    int y = iy - 1, x = ix - 1;
    float v = 0.f;
    if ((unsigned)y < 8u && (unsigned)x < 8u)
      v = in[(((size_t)b * 64 + ci) * 8 + y) * 8 + x];
    ins[i] = v;
  }
  const int px = t & 63, cog = t >> 6;
  const int y = px >> 3, x = px & 7;
  float acc[32];
#pragma unroll
  for (int i = 0; i < 32; i++) acc[i] = 0.f;
  for (int ch = 0; ch < 16; ch++) {
    __syncthreads();
    for (int i = t; i < 128 * 4 * 9; i += 256) {
      int cr = i / 9, k = i % 9;
      int co = cr >> 2, cil = cr & 3;
      ws[cr * 12 + k] = w[((size_t)co * 64 + ch * 4 + cil) * 9 + k];
    }
    __syncthreads();
#pragma unroll 1
    for (int cil = 0; cil < 4; cil++) {
      float vals[9];
#pragma unroll
      for (int dy = 0; dy < 3; dy++)
#pragma unroll
        for (int dx = 0; dx < 3; dx++)
          vals[dy * 3 + dx] = ins[(ch * 4 + cil) * 100 + (y + dy) * 10 + (x + dx)];
#pragma unroll
      for (int co = 0; co < 32; co++) {
        const float* wp = &ws[((cog * 32 + co) * 4 + cil) * 12];
        float4 wA = *(const float4*)wp;
        float4 wB = *(const float4*)(wp + 4);
        float w8 = wp[8];
        acc[co] += vals[0] * wA.x + vals[1] * wA.y + vals[2] * wA.z + vals[3] * wA.w +
                   vals[4] * wB.x + vals[5] * wB.y + vals[6] * wB.z + vals[7] * wB.w +
                   vals[8] * w8;
      }
    }
  }
  if (STATS) {
#pragma unroll
    for (int co = 0; co < 32; co++) {
      float a = acc[co];
      float s = waveSum(a), sq = waveSum(a * a);
      if ((t & 63) == 0) { red[2 * (cog * 32 + co)] = s; red[2 * (cog * 32 + co) + 1] = sq; }
    }
    __syncthreads();
    for (int i = t; i < 256; i += 256) partials[(size_t)b * 256 + i] = red[i];
  } else {
#pragma unroll
    for (int co = 0; co < 32; co++) {
      int c = cog * 32 + co;
      float v = fmaxf(acc[co] * scale[c] + shift[c], 0.f);
      out[(((size_t)b * 128 + c) * 8 + y) * 8 + x] = v;
    }
  }
}

// ============================================================================
// BN helpers
// ============================================================================
__global__ __launch_bounds__(256) void reduce_partials_kernel(
    const float* __restrict__ partials, int nblk, int Q, double* __restrict__ sums) {
  int q = blockIdx.x;
  double acc = 0.0;
  for (int i = threadIdx.x; i < nblk; i += 256) acc += (double)partials[(size_t)i * Q + q];
  __shared__ double red[256];
  red[threadIdx.x] = acc;
  __syncthreads();
  for (int s = 128; s > 0; s >>= 1) {
    if (threadIdx.x < s) red[threadIdx.x] += red[threadIdx.x + s];
    __syncthreads();
  }
  if (threadIdx.x == 0) sums[q] = red[0];
}

__global__ __launch_bounds__(1024) void col_stats_kernel(
    const float* __restrict__ X, int R, int C, double* __restrict__ sums) {
  int c0 = blockIdx.x * 64;
  int cl = threadIdx.x & 63, rg = threadIdx.x >> 6;
  double s = 0.0, sq = 0.0;
  for (int r = rg; r < R; r += 16) {
    float v = X[(size_t)r * C + c0 + cl];
    s += v; sq += (double)v * (double)v;
  }
  __shared__ double red[16][64][2];
  red[rg][cl][0] = s; red[rg][cl][1] = sq;
  __syncthreads();
  if (rg == 0) {
    for (int i = 1; i < 16; i++) { s += red[i][cl][0]; sq += red[i][cl][1]; }
    sums[2 * (c0 + cl)] = s; sums[2 * (c0 + cl) + 1] = sq;
  }
}

__global__ void bn_finalize_kernel(const double* __restrict__ sums,
                                   const float* __restrict__ g, const float* __restrict__ b,
                                   float* __restrict__ scale, float* __restrict__ shift,
                                   int C, double invN) {
  int c = blockIdx.x * blockDim.x + threadIdx.x;
  if (c >= C) return;
  double m = sums[2 * c] * invN;
  double v = sums[2 * c + 1] * invN - m * m;
  double sc = (double)g[c] / sqrt(v + 1e-5);
  scale[c] = (float)sc;
  shift[c] = (float)((double)b[c] - m * sc);
}

__global__ void bn_relu_apply_kernel(float* __restrict__ X, const float* __restrict__ scale,
                                     const float* __restrict__ shift, size_t n, int C) {
  size_t i = (size_t)blockIdx.x * blockDim.x + threadIdx.x;
  if (i >= n) return;
  int c = (int)(i % (size_t)C);
  float v = X[i] * scale[c] + shift[c];
  X[i] = fmaxf(v, 0.f);
}

// ============================================================================
// Tiled fp32 GEMM, NT: C[M,N] = A[M,K] * B[N,K]^T (+bias, relu).
// 64x64 tile, BK=16, 256 threads, 4x4 micro-tile. M%64==N%64==K%16==0.
// ============================================================================
template <int BIASRELU>
__global__ __launch_bounds__(256) void gemm_nt_kernel(
    const float* __restrict__ A, const float* __restrict__ B,
    const float* __restrict__ bias, float* __restrict__ C, int M, int N, int K) {
  __shared__ float As[16][64];
  __shared__ float Bs[16][64];
  const int t = threadIdx.x;
  const int tn = t & 15, tm = t >> 4;
  const int m0 = blockIdx.y << 6, n0 = blockIdx.x << 6;
  const int lr = t >> 2, lk = (t & 3) << 2;
  const float* Ap = A + (size_t)(m0 + lr) * K + lk;
  const float* Bp = B + (size_t)(n0 + lr) * K + lk;
  float acc[4][4];
#pragma unroll
  for (int i = 0; i < 4; i++)
#pragma unroll
    for (int j = 0; j < 4; j++) acc[i][j] = 0.f;
  for (int k0 = 0; k0 < K; k0 += 16) {
    float4 av = *(const float4*)(Ap + k0);
    float4 bv = *(const float4*)(Bp + k0);
    __syncthreads();
    As[lk + 0][lr] = av.x; As[lk + 1][lr] = av.y; As[lk + 2][lr] = av.z; As[lk + 3][lr] = av.w;
    Bs[lk + 0][lr] = bv.x; Bs[lk + 1][lr] = bv.y; Bs[lk + 2][lr] = bv.z; Bs[lk + 3][lr] = bv.w;
    __syncthreads();
#pragma unroll
    for (int kk = 0; kk < 16; kk++) {
      float4 a4 = *(const float4*)&As[kk][tm << 2];
      float4 b4 = *(const float4*)&Bs[kk][tn << 2];
      acc[0][0] += a4.x * b4.x; acc[0][1] += a4.x * b4.y; acc[0][2] += a4.x * b4.z; acc[0][3] += a4.x * b4.w;
      acc[1][0] += a4.y * b4.x; acc[1][1] += a4.y * b4.y; acc[1][2] += a4.y * b4.z; acc[1][3] += a4.y * b4.w;
      acc[2][0] += a4.z * b4.x; acc[2][1] += a4.z * b4.y; acc[2][2] += a4.z * b4.z; acc[2][3] += a4.z * b4.w;
      acc[3][0] += a4.w * b4.x; acc[3][1] += a4.w * b4.y; acc[3][2] += a4.w * b4.z; acc[3][3] += a4.w * b4.w;
    }
  }
#pragma unroll
  for (int i = 0; i < 4; i++) {
    int m = m0 + (tm << 2) + i;
    float4 o;
    float v0 = acc[i][0], v1 = acc[i][1], v2 = acc[i][2], v3 = acc[i][3];
    if (BIASRELU) {
      int nb = n0 + (tn << 2);
      v0 = fmaxf(v0 + bias[nb + 0], 0.f);
      v1 = fmaxf(v1 + bias[nb + 1], 0.f);
      v2 = fmaxf(v2 + bias[nb + 2], 0.f);
      v3 = fmaxf(v3 + bias[nb + 3], 0.f);
    }
    o.x = v0; o.y = v1; o.z = v2; o.w = v3;
    *(float4*)&C[(size_t)m * N + n0 + (tn << 2)] = o;
  }
}

// ============================================================================
// heads: domain_output (-> d_out) and sw_logits (-> ws). block 256 = 64b x 4j.
// Double accumulation: sw_logits errors are amplified 10x by TAU=0.1.
// ============================================================================
__global__ __launch_bounds__(256) void heads_kernel(
    const float* __restrict__ dpen, const float* __restrict__ dfc_w,
    const float* __restrict__ dfc_b, const float* __restrict__ sw_w,
    const float* __restrict__ sw_b, float* __restrict__ out_dom,
    float* __restrict__ swbuf) {
  int t = blockIdx.x * 256 + threadIdx.x;
  int b = t >> 2, j = t & 3;
  const float* row = dpen + (size_t)b * 384;
  const float* wr = (j < 2) ? (dfc_w + j * 384) : (sw_w + (j - 2) * 384);
  double s = 0.0;
  for (int k = 0; k < 384; k++) s += (double)row[k] * (double)wr[k];
  s += (double)((j < 2) ? dfc_b[j] : sw_b[j - 2]);
  if (j < 2) out_dom[b * 2 + j] = (float)s;
  else swbuf[b * 2 + (j - 2)] = (float)s;
}

// ============================================================================
// gumbel-softmax + categorical partition choice (threefry partitionable).
// u01 bit-exact fp32 (as jax); transcendental chain in double (toward np-f64).
// ============================================================================
__global__ __launch_bounds__(256) void partition_kernel(
    const float* __restrict__ swbuf, float* __restrict__ out_pid,
    int* __restrict__ pidxI, float* __restrict__ ysum,
    uint32_t k1a, uint32_t k1b, uint32_t k2a, uint32_t k2b) {
  int b = blockIdx.x * 256 + threadIdx.x;
  if (b >= 4096) return;
  uint32_t j0 = (uint32_t)(2 * b), j1 = (uint32_t)(2 * b + 1);
  // u ~ uniform(k1, minval=1e-10, maxval=1.0), fp32 affine as in jax
  float f0 = u01_from_bits(tf_bits32(k1a, k1b, j0));
  float f1 = u01_from_bits(tf_bits32(k1a, k1b, j1));
  const float MINV = 1e-10f;
  float u0 = fmaxf(MINV, f0 * (1.0f - MINV) + MINV);
  float u1 = fmaxf(MINV, f1 * (1.0f - MINV) + MINV);
  double g0 = -log(-log((double)u0));
  double g1 = -log(-log((double)u1));
  double s0 = (double)swbuf[2 * b], s1 = (double)swbuf[2 * b + 1];
  double x0 = (s0 + g0) / 0.1;
  double x1 = (s1 + g1) / 0.1;
  double mx = fmax(x0, x1);
  double e0 = exp(x0 - mx), e1 = exp(x1 - mx);
  double es = e0 + e1;
  double y0 = e0 / es, y1 = e1 / es;
  // categorical(k2, log(y+1e-20)) = argmax(log(y+1e-20) + gumbel(k2))
  float h0 = u01_from_bits(tf_bits32(k2a, k2b, j0));
  float h1 = u01_from_bits(tf_bits32(k2a, k2b, j1));
  const float TINY = 1.17549435e-38f;
  float v0 = fmaxf(TINY, h0 * (1.0f - TINY) + TINY);
  float v1 = fmaxf(TINY, h1 * (1.0f - TINY) + TINY);
  double gg0 = -log(-log((double)v0));
  double gg1 = -log(-log((double)v1));
  double l0 = log(y0 + 1e-20) + gg0;
  double l1 = log(y1 + 1e-20) + gg1;
  int p = (l1 > l0) ? 1 : 0;  // jnp.argmax: first max wins on tie
  out_pid[b] = (float)p;
  pidxI[b] = p;
  ysum[b] = (float)(y0 + y1);
}

// ============================================================================
// final: class_output[b][c] = (p2_w[p,c,:] . h[b, p*192:+192] + p2_b[p,c]) * ysum[b]
// ============================================================================
__global__ __launch_bounds__(256) void final_kernel(
    const float* __restrict__ h, const float* __restrict__ p2w,
    const float* __restrict__ p2b, const int* __restrict__ pidxI,
    const float* __restrict__ ysum, float* __restrict__ out0) {
  int t = blockIdx.x * 256 + threadIdx.x;
  if (t >= 40960) return;
  int b = t / 10, c = t % 10;
  int p = pidxI[b];
  const float* hr = h + (size_t)b * 384 + p * 192;
  const float* wr = p2w + ((size_t)p * 10 + c) * 192;
  float s = 0.f;
  for (int o = 0; o < 192; o++) s += hr[o] * wr[o];
  s += p2b[p * 10 + c];
  out0[t] = s * ysum[b];
}

// ============================================================================
// Launch orchestration. Workspace layout (float offsets), total ~224 MB.
// ============================================================================
extern "C" void kernel_launch(void* const* d_in, const int* in_sizes, int n_in,
                              void* d_out, int out_size, void* d_ws, size_t ws_size,
                              hipStream_t stream) {
  const float* input   = (const float*)d_in[0];
  const float* conv1_w = (const float*)d_in[1];
  const float* bn1_g   = (const float*)d_in[3];
  const float* bn1_b   = (const float*)d_in[4];
  const float* conv2_w = (const float*)d_in[5];
  const float* bn2_g   = (const float*)d_in[7];
  const float* bn2_b   = (const float*)d_in[8];
  const float* conv3_w = (const float*)d_in[9];
  const float* bn3_g   = (const float*)d_in[11];
  const float* bn3_b   = (const float*)d_in[12];
  const float* pre_w   = (const float*)d_in[13];
  const float* bnp_g   = (const float*)d_in[15];
  const float* bnp_b   = (const float*)d_in[16];
  const float* disc_w  = (const float*)d_in[17];
  const float* bnd_g   = (const float*)d_in[19];
  const float* bnd_b   = (const float*)d_in[20];
  const float* dfc_w   = (const float*)d_in[21];
  const float* dfc_b   = (const float*)d_in[22];
  const float* sw_w    = (const float*)d_in[23];
  const float* sw_b    = (const float*)d_in[24];
  const float* p1_w    = (const float*)d_in[25];
  const float* p1_b    = (const float*)d_in[26];
  const float* p2_w    = (const float*)d_in[27];
  const float* p2_b    = (const float*)d_in[28];

  float* W = (float*)d_ws;
  float* pool1  = W + 0;
  float* pool2  = W + 33554432;
  float* act3   = W + 0;          // alias pool1 (dead by then)
  float* featp  = W + 50331648;
  float* dpen   = W + 54525952;
  float* hbuf   = W + 56098816;
  float* swbuf  = W + 57671680;
  float* ysum   = W + 57679872;
  int*   pidxI  = (int*)(W + 57683968);
  float* part   = W + 57688064;
  double* sums  = (double*)(W + 58736640);
  float* scale  = W + 58740736;
  float* shift  = W + 58741760;

  float* out_cls = (float*)d_out;
  float* out_dom = out_cls + 40960;
  float* out_pid = out_cls + 49152;

  // jax.random.key(42) -> foldlike split (partitionable default):
  // k1 = cipher(0,0) both words, k2 = cipher(0,1) both words
  uint32_t k1a, k1b, k2a, k2b;
  threefry2x32(0u, 42u, 0u, 0u, k1a, k1b);
  threefry2x32(0u, 42u, 0u, 1u, k2a, k2b);

  // --- conv1 + BN1 + ReLU + pool ---
  conv1_stats_kernel<<<dim3(16384), dim3(256), 0, stream>>>(input, conv1_w, part);
  reduce_partials_kernel<<<dim3(64), dim3(256), 0, stream>>>(part, 16384, 64, sums);
  bn_finalize_kernel<<<dim3(1), dim3(64), 0, stream>>>(sums, bn1_g, bn1_b, scale, shift, 32, 1.0 / (4096.0 * 1024.0));
  conv1_apply_kernel<<<dim3(4096), dim3(256), 0, stream>>>(input, conv1_w, scale, shift, pool1);

  // --- conv2 + BN2 + ReLU + pool (stats pass + recompute-apply pass) ---
  conv2_stats_kernel<<<dim3(4096), dim3(256), 0, stream>>>(pool1, conv2_w, part);
  reduce_partials_kernel<<<dim3(128), dim3(256), 0, stream>>>(part, 4096, 128, sums);
  bn_finalize_kernel<<<dim3(1), dim3(64), 0, stream>>>(sums, bn2_g, bn2_b, scale, shift, 64, 1.0 / (4096.0 * 256.0));
  conv2_apply_kernel<<<dim3(4096), dim3(256), 0, stream>>>(pool1, conv2_w, scale, shift, pool2);

  // --- conv3 + BN3 + ReLU (stats pass + recompute-apply pass) ---
  conv3_kernel<1><<<dim3(4096), dim3(256), 0, stream>>>(pool2, conv3_w, nullptr, nullptr, nullptr, part);
  reduce_partials_kernel<<<dim3(256), dim3(256), 0, stream>>>(part, 4096, 256, sums);
  bn_finalize_kernel<<<dim3(1), dim3(128), 0, stream>>>(sums, bn3_g, bn3_b, scale, shift, 128, 1.0 / (4096.0 * 64.0));
  conv3_kernel<0><<<dim3(4096), dim3(256), 0, stream>>>(pool2, conv3_w, scale, shift, act3, nullptr);

  // --- pre FC 8192->1024 + BN + ReLU ---
  gemm_nt_kernel<0><<<dim3(16, 64), dim3(256), 0, stream>>>(act3, pre_w, (const float*)nullptr, featp, 4096, 1024, 8192);
  col_stats_kernel<<<dim3(16), dim3(1024), 0, stream>>>(featp, 4096, 1024, sums);
  bn_finalize_kernel<<<dim3(4), dim3(256), 0, stream>>>(sums, bnp_g, bnp_b, scale, shift, 1024, 1.0 / 4096.0);
  bn_relu_apply_kernel<<<dim3(16384), dim3(256), 0, stream>>>(featp, scale, shift, (size_t)4194304, 1024);

  // --- disc FC 1024->384 + BN + ReLU ---
  gemm_nt_kernel<0><<<dim3(6, 64), dim3(256), 0, stream>>>(featp, disc_w, (const float*)nullptr, dpen, 4096, 384, 1024);
  col_stats_kernel<<<dim3(6), dim3(1024), 0, stream>>>(dpen, 4096, 384, sums);
  bn_finalize_kernel<<<dim3(2), dim3(256), 0, stream>>>(sums, bnd_g, bnd_b, scale, shift, 384, 1.0 / 4096.0);
  bn_relu_apply_kernel<<<dim3(6144), dim3(256), 0, stream>>>(dpen, scale, shift, (size_t)1572864, 384);

  // --- heads + partition sampling ---
  heads_kernel<<<dim3(64), dim3(256), 0, stream>>>(dpen, dfc_w, dfc_b, sw_w, sw_b, out_dom, swbuf);
  partition_kernel<<<dim3(16), dim3(256), 0, stream>>>(swbuf, out_pid, pidxI, ysum, k1a, k1b, k2a, k2b);

  // --- experts: dense p1 for both partitions, then gather + p2 ---
  gemm_nt_kernel<1><<<dim3(6, 64), dim3(256), 0, stream>>>(featp, p1_w, p1_b, hbuf, 4096, 384, 1024);
  final_kernel<<<dim3(160), dim3(256), 0, stream>>>(hbuf, p2_w, p2_b, pidxI, ysum, out_cls);
}

// Round 4
// 6224.126 us; speedup vs baseline: 1.0014x; 1.0014x over previous
//
#include <hip/hip_runtime.h>
#include <cstdint>
#include <cstddef>

// ============================================================================
// Threefry2x32 (matches jax._src.prng.threefry2x32).
// ============================================================================
__host__ __device__ inline void threefry2x32(uint32_t k0, uint32_t k1,
                                             uint32_t x0, uint32_t x1,
                                             uint32_t& o0, uint32_t& o1) {
  uint32_t ks2 = k0 ^ k1 ^ 0x1BD11BDAu;
  uint32_t v0 = x0 + k0, v1 = x1 + k1;
#define TF_R(r) { v0 += v1; v1 = (v1 << (r)) | (v1 >> (32 - (r))); v1 ^= v0; }
  TF_R(13) TF_R(15) TF_R(26) TF_R(6)
  v0 += k1; v1 += ks2 + 1u;
  TF_R(17) TF_R(29) TF_R(16) TF_R(24)
  v0 += ks2; v1 += k0 + 2u;
  TF_R(13) TF_R(15) TF_R(26) TF_R(6)
  v0 += k0; v1 += k1 + 3u;
  TF_R(17) TF_R(29) TF_R(16) TF_R(24)
  v0 += k1; v1 += ks2 + 4u;
  TF_R(13) TF_R(15) TF_R(26) TF_R(6)
  v0 += ks2; v1 += k0 + 5u;
#undef TF_R
  o0 = v0; o1 = v1;
}

// jax partitionable random_bits, bit_width=32: bits = o0 ^ o1 (hi=0, lo=j).
__device__ __forceinline__ uint32_t tf_bits32(uint32_t k0, uint32_t k1, uint32_t j) {
  uint32_t o0, o1;
  threefry2x32(k0, k1, 0u, j, o0, o1);
  return o0 ^ o1;
}

__device__ __forceinline__ float u01_from_bits(uint32_t bits) {
  return __uint_as_float((bits >> 9) | 0x3f800000u) - 1.0f;  // [0,1)
}

__device__ __forceinline__ float waveSum(float v) {
#pragma unroll
  for (int off = 32; off > 0; off >>= 1) v += __shfl_down(v, off, 64);
  return v;
}

// ============================================================================
// conv1 (3->32, 32x32, pad1) pass A: per-channel (sum,sumsq) partials.
// ============================================================================
__global__ __launch_bounds__(256) void conv1_stats_kernel(
    const float* __restrict__ in, const float* __restrict__ w,
    float* __restrict__ partials) {
  __shared__ float ins[3 * 10 * 34];
  __shared__ float ws[32 * 3 * 12];
  __shared__ float red[4][64];
  const int blk = blockIdx.x, t = threadIdx.x;
  const int b = blk >> 2, r0 = (blk & 3) << 3;
  for (int i = t; i < 32 * 27; i += 256) {
    int cor = i / 9, k = i % 9;
    ws[cor * 12 + k] = w[i];
  }
  for (int i = t; i < 3 * 10 * 34; i += 256) {
    int ci = i / 340, r = i % 340, iy = r / 34, ix = r % 34;
    int y = r0 - 1 + iy, x = ix - 1;
    float v = 0.f;
    if ((unsigned)y < 32u && (unsigned)x < 32u)
      v = in[(((size_t)b * 3 + ci) * 32 + y) * 32 + x];
    ins[i] = v;
  }
  __syncthreads();
  const int ly = t >> 5, x = t & 31, wv = t >> 6, ln = t & 63;
  float win[27];
#pragma unroll
  for (int ci = 0; ci < 3; ci++)
#pragma unroll
    for (int dy = 0; dy < 3; dy++)
#pragma unroll
      for (int dx = 0; dx < 3; dx++)
        win[ci * 9 + dy * 3 + dx] = ins[ci * 340 + (ly + dy) * 34 + (x + dx)];
#pragma unroll 1
  for (int co = 0; co < 32; co++) {
    float a = 0.f;
#pragma unroll
    for (int ci = 0; ci < 3; ci++) {
      const float* wp = &ws[(co * 3 + ci) * 12];
      float4 wA = *(const float4*)wp;
      float4 wB = *(const float4*)(wp + 4);
      float w8 = wp[8];
      a += win[ci * 9 + 0] * wA.x + win[ci * 9 + 1] * wA.y + win[ci * 9 + 2] * wA.z +
           win[ci * 9 + 3] * wA.w + win[ci * 9 + 4] * wB.x + win[ci * 9 + 5] * wB.y +
           win[ci * 9 + 6] * wB.z + win[ci * 9 + 7] * wB.w + win[ci * 9 + 8] * w8;
    }
    float s = waveSum(a), sq = waveSum(a * a);
    if (ln == 0) { red[wv][2 * co] = s; red[wv][2 * co + 1] = sq; }
  }
  __syncthreads();
  for (int i = t; i < 64; i += 256)
    partials[(size_t)blk * 64 + i] = red[0][i] + red[1][i] + red[2][i] + red[3][i];
}

// conv1 pass B: recompute conv, BN+ReLU, 2x2 maxpool -> pool1.
__global__ __launch_bounds__(256) void conv1_apply_kernel(
    const float* __restrict__ in, const float* __restrict__ w,
    const float* __restrict__ scale, const float* __restrict__ shift,
    float* __restrict__ out) {
  __shared__ float ins[3 * 34 * 34];
  __shared__ float ws[32 * 3 * 12];
  const int b = blockIdx.x, t = threadIdx.x;
  for (int i = t; i < 32 * 27; i += 256) {
    int cor = i / 9, k = i % 9;
    ws[cor * 12 + k] = w[i];
  }
  for (int i = t; i < 3 * 34 * 34; i += 256) {
    int ci = i / 1156, r = i % 1156, iy = r / 34, ix = r % 34;
    int y = iy - 1, x = ix - 1;
    float v = 0.f;
    if ((unsigned)y < 32u && (unsigned)x < 32u)
      v = in[(((size_t)b * 3 + ci) * 32 + y) * 32 + x];
    ins[i] = v;
  }
  __syncthreads();
  const int py = t >> 4, px = t & 15;
  float win[3][4][4];
#pragma unroll
  for (int ci = 0; ci < 3; ci++)
#pragma unroll
    for (int r = 0; r < 4; r++)
#pragma unroll
      for (int c = 0; c < 4; c++)
        win[ci][r][c] = ins[ci * 1156 + (2 * py + r) * 34 + (2 * px + c)];
#pragma unroll 1
  for (int co = 0; co < 32; co++) {
    float acc00 = 0.f, acc01 = 0.f, acc10 = 0.f, acc11 = 0.f;
#pragma unroll
    for (int ci = 0; ci < 3; ci++) {
      const float* wp = &ws[(co * 3 + ci) * 12];
      float4 wA = *(const float4*)wp;
      float4 wB = *(const float4*)(wp + 4);
      float w8 = wp[8];
      float wr[9] = {wA.x, wA.y, wA.z, wA.w, wB.x, wB.y, wB.z, wB.w, w8};
#pragma unroll
      for (int dy = 0; dy < 3; dy++)
#pragma unroll
        for (int dx = 0; dx < 3; dx++) {
          float wv = wr[dy * 3 + dx];
          acc00 += win[ci][dy][dx] * wv;
          acc01 += win[ci][dy][dx + 1] * wv;
          acc10 += win[ci][dy + 1][dx] * wv;
          acc11 += win[ci][dy + 1][dx + 1] * wv;
        }
    }
    float sc = scale[co], sh = shift[co];
    float best = 0.f;
    best = fmaxf(best, acc00 * sc + sh);
    best = fmaxf(best, acc01 * sc + sh);
    best = fmaxf(best, acc10 * sc + sh);
    best = fmaxf(best, acc11 * sc + sh);
    out[(((size_t)b * 32 + co) * 16 + py) * 16 + px] = best;
  }
}

// ============================================================================
// conv2 single-pass (BIG path): conv(32->64) -> raw act2 [4096][64][16][16].
// Weights in LDS transposed [k][ci][co] (broadcast float4 reads, 9 KB).
// LDS total ~50.7 KB -> 3 blocks/CU.
// ============================================================================
__global__ __launch_bounds__(256) void conv2_full_kernel(
    const float* __restrict__ in, const float* __restrict__ w,
    float* __restrict__ out) {
  __shared__ float ins[32 * 18 * 18];
  __shared__ float ws2[9 * 32 * 8];
  const int b = blockIdx.x, t = threadIdx.x;
  for (int i = t; i < 32 * 18 * 18; i += 256) {
    int ci = i / 324, r = i % 324, iy = r / 18, ix = r % 18;
    int y = iy - 1, x = ix - 1;
    float v = 0.f;
    if ((unsigned)y < 16u && (unsigned)x < 16u)
      v = in[(((size_t)b * 32 + ci) * 16 + y) * 16 + x];
    ins[i] = v;
  }
  const int y = t >> 4, x = t & 15;
  for (int cc = 0; cc < 8; cc++) {
    __syncthreads();
    for (int i = t; i < 8 * 32 * 9; i += 256) {
      int cor = i / 9, k = i % 9;
      int co = cor >> 5, ci = cor & 31;
      ws2[(k * 32 + ci) * 8 + co] = w[((size_t)(cc * 8 + co) * 32 + ci) * 9 + k];
    }
    __syncthreads();
    float acc[8];
#pragma unroll
    for (int i = 0; i < 8; i++) acc[i] = 0.f;
#pragma unroll 1
    for (int ci = 0; ci < 32; ci++) {
      float vals[9];
#pragma unroll
      for (int dy = 0; dy < 3; dy++)
#pragma unroll
        for (int dx = 0; dx < 3; dx++)
          vals[dy * 3 + dx] = ins[ci * 324 + (y + dy) * 18 + (x + dx)];
#pragma unroll
      for (int k = 0; k < 9; k++) {
        const float* wp = &ws2[(k * 32 + ci) * 8];
        float4 wA = *(const float4*)wp;
        float4 wB = *(const float4*)(wp + 4);
        float v = vals[k];
        acc[0] += v * wA.x; acc[1] += v * wA.y; acc[2] += v * wA.z; acc[3] += v * wA.w;
        acc[4] += v * wB.x; acc[5] += v * wB.y; acc[6] += v * wB.z; acc[7] += v * wB.w;
      }
    }
#pragma unroll
    for (int co = 0; co < 8; co++)
      out[((size_t)b * 64 + cc * 8 + co) * 256 + t] = acc[co];
  }
}

// ============================================================================
// Per-image act stats: act [B][C][HW] -> partials[b][2C] (sum,sumsq pairs).
// Channel index is wave-uniform (HW in {64,256}).
// ============================================================================
template <int C, int HW>
__global__ __launch_bounds__(256) void act_stats_kernel(
    const float* __restrict__ act, float* __restrict__ partials) {
  __shared__ float red[4][2 * C];
  const int b = blockIdx.x, t = threadIdx.x, wv = t >> 6, ln = t & 63;
  for (int i = t; i < 8 * C; i += 256) (&red[0][0])[i] = 0.f;
  __syncthreads();
  const float* base = act + (size_t)b * C * HW;
  const int iters = C * HW / 256;
#pragma unroll 4
  for (int j = 0; j < iters; j++) {
    int idx = j * 256 + t;
    float v = base[idx];
    int ch = idx / HW;  // wave-uniform
    float s = waveSum(v), sq = waveSum(v * v);
    if (ln == 0) { red[wv][2 * ch] += s; red[wv][2 * ch + 1] += sq; }
  }
  __syncthreads();
  for (int i = t; i < 2 * C; i += 256)
    partials[(size_t)b * 2 * C + i] = red[0][i] + red[1][i] + red[2][i] + red[3][i];
}

// [4096][64][16][16] -> BN+ReLU+2x2 maxpool -> [4096][64][8][8]
__global__ void bn_relu_pool_kernel(const float* __restrict__ X, float* __restrict__ Y,
                                    const float* __restrict__ scale,
                                    const float* __restrict__ shift) {
  int t = blockIdx.x * blockDim.x + threadIdx.x;
  if (t >= 4096 * 64 * 8 * 8) return;
  int px = t & 7, py = (t >> 3) & 7, c = (t >> 6) & 63, b = t >> 12;
  const float* base = X + ((((size_t)b * 64 + c) * 16 + 2 * py) * 16 + 2 * px);
  float sc = scale[c], sh = shift[c];
  float m = 0.f;
  m = fmaxf(m, base[0] * sc + sh);
  m = fmaxf(m, base[1] * sc + sh);
  m = fmaxf(m, base[16] * sc + sh);
  m = fmaxf(m, base[17] * sc + sh);
  Y[t] = m;
}

// in-place BN+ReLU for NCHW with HW=64, C=128
__global__ void bn_relu_hw_kernel(float* __restrict__ X, const float* __restrict__ scale,
                                  const float* __restrict__ shift, size_t n) {
  size_t i = (size_t)blockIdx.x * blockDim.x + threadIdx.x;
  if (i >= n) return;
  int c = (int)((i >> 6) & 127);
  float v = X[i] * scale[c] + shift[c];
  X[i] = fmaxf(v, 0.f);
}

// ============================================================================
// conv2 fallback pass A: stats only (8 co-chunks of 8).
// ============================================================================
__global__ __launch_bounds__(256) void conv2_stats_kernel(
    const float* __restrict__ in, const float* __restrict__ w,
    float* __restrict__ partials) {
  __shared__ float ins[32 * 18 * 18];
  __shared__ float ws[8 * 32 * 12];
  __shared__ float red[4][128];
  const int b = blockIdx.x, t = threadIdx.x;
  for (int i = t; i < 32 * 18 * 18; i += 256) {
    int ci = i / 324, r = i % 324, iy = r / 18, ix = r % 18;
    int y = iy - 1, x = ix - 1;
    float v = 0.f;
    if ((unsigned)y < 16u && (unsigned)x < 16u)
      v = in[(((size_t)b * 32 + ci) * 16 + y) * 16 + x];
    ins[i] = v;
  }
  const int y = t >> 4, x = t & 15, wv = t >> 6, ln = t & 63;
  for (int cc = 0; cc < 8; cc++) {
    __syncthreads();
    for (int i = t; i < 8 * 32 * 9; i += 256) {
      int cor = i / 9, k = i % 9;
      ws[cor * 12 + k] = w[cc * (8 * 32 * 9) + i];
    }
    __syncthreads();
    float acc[8];
#pragma unroll
    for (int i = 0; i < 8; i++) acc[i] = 0.f;
#pragma unroll 1
    for (int ci = 0; ci < 32; ci++) {
      float vals[9];
#pragma unroll
      for (int dy = 0; dy < 3; dy++)
#pragma unroll
        for (int dx = 0; dx < 3; dx++)
          vals[dy * 3 + dx] = ins[ci * 324 + (y + dy) * 18 + (x + dx)];
#pragma unroll
      for (int co = 0; co < 8; co++) {
        const float* wp = &ws[(co * 32 + ci) * 12];
        float4 wA = *(const float4*)wp;
        float4 wB = *(const float4*)(wp + 4);
        float w8 = wp[8];
        acc[co] += vals[0] * wA.x + vals[1] * wA.y + vals[2] * wA.z + vals[3] * wA.w +
                   vals[4] * wB.x + vals[5] * wB.y + vals[6] * wB.z + vals[7] * wB.w +
                   vals[8] * w8;
      }
    }
#pragma unroll
    for (int co = 0; co < 8; co++) {
      float a = acc[co];
      float s = waveSum(a), sq = waveSum(a * a);
      if (ln == 0) { red[wv][2 * (cc * 8 + co)] = s; red[wv][2 * (cc * 8 + co) + 1] = sq; }
    }
  }
  __syncthreads();
  for (int i = t; i < 128; i += 256)
    partials[(size_t)b * 128 + i] = red[0][i] + red[1][i] + red[2][i] + red[3][i];
}

// conv2 fallback pass B: recompute conv2, BN+ReLU+2x2 pool -> pool2.
__global__ __launch_bounds__(256) void conv2_apply_kernel(
    const float* __restrict__ in, const float* __restrict__ w,
    const float* __restrict__ scale, const float* __restrict__ shift,
    float* __restrict__ out) {
  __shared__ float ins[32 * 18 * 18];
  __shared__ float ws[8 * 32 * 12];
  __shared__ float os[8 * 256];
  const int b = blockIdx.x, t = threadIdx.x;
  for (int i = t; i < 32 * 18 * 18; i += 256) {
    int ci = i / 324, r = i % 324, iy = r / 18, ix = r % 18;
    int y = iy - 1, x = ix - 1;
    float v = 0.f;
    if ((unsigned)y < 16u && (unsigned)x < 16u)
      v = in[(((size_t)b * 32 + ci) * 16 + y) * 16 + x];
    ins[i] = v;
  }
  const int y = t >> 4, x = t & 15;
  for (int cc = 0; cc < 8; cc++) {
    __syncthreads();
    for (int i = t; i < 8 * 32 * 9; i += 256) {
      int cor = i / 9, k = i % 9;
      ws[cor * 12 + k] = w[cc * (8 * 32 * 9) + i];
    }
    __syncthreads();
    float acc[8];
#pragma unroll
    for (int i = 0; i < 8; i++) acc[i] = 0.f;
#pragma unroll 1
    for (int ci = 0; ci < 32; ci++) {
      float vals[9];
#pragma unroll
      for (int dy = 0; dy < 3; dy++)
#pragma unroll
        for (int dx = 0; dx < 3; dx++)
          vals[dy * 3 + dx] = ins[ci * 324 + (y + dy) * 18 + (x + dx)];
#pragma unroll
      for (int co = 0; co < 8; co++) {
        const float* wp = &ws[(co * 32 + ci) * 12];
        float4 wA = *(const float4*)wp;
        float4 wB = *(const float4*)(wp + 4);
        float w8 = wp[8];
        acc[co] += vals[0] * wA.x + vals[1] * wA.y + vals[2] * wA.z + vals[3] * wA.w +
                   vals[4] * wB.x + vals[5] * wB.y + vals[6] * wB.z + vals[7] * wB.w +
                   vals[8] * w8;
      }
    }
#pragma unroll
    for (int co = 0; co < 8; co++) os[co * 256 + t] = acc[co];
    __syncthreads();
    for (int i = t; i < 8 * 64; i += 256) {
      int co = i >> 6, pl = i & 63, py = pl >> 3, px = pl & 7;
      int c = cc * 8 + co;
      float sc = scale[c], sh = shift[c];
      const float* o = &os[co * 256 + (2 * py) * 16 + 2 * px];
      float m = 0.f;
      m = fmaxf(m, o[0] * sc + sh);
      m = fmaxf(m, o[1] * sc + sh);
      m = fmaxf(m, o[16] * sc + sh);
      m = fmaxf(m, o[17] * sc + sh);
      out[(((size_t)b * 64 + c) * 8 + py) * 8 + px] = m;
    }
  }
}

// ============================================================================
// conv3 (64->128, 8x8, pad1). MODE 1: stats partials. MODE 0: BN+ReLU store.
// MODE 2: raw store. grid 4096, block 256 = 64 px x 4 co-groups of 32.
// ============================================================================
template <int MODE>
__global__ __launch_bounds__(256) void conv3_kernel(
    const float* __restrict__ in, const float* __restrict__ w,
    const float* __restrict__ scale, const float* __restrict__ shift,
    float* __restrict__ out, float* __restrict__ partials) {
  __shared__ float ins[64 * 10 * 10];
  __shared__ float ws[128 * 4 * 12];
  __shared__ float red[256];
  const int b = blockIdx.x, t = threadIdx.x;
  for (int i = t; i < 64 * 10 * 10; i += 256) {
    int ci = i / 100, r = i % 100, iy = r / 10, ix = r % 10;
    int y = iy - 1, x = ix - 1;
    float v = 0.f;
    if ((unsigned)y < 8u && (unsigned)x < 8u)
      v = in[(((size_t)b * 64 + ci) * 8 + y) * 8 + x];
    ins[i] = v;
  }
  const int px = t & 63, cog = t >> 6;
  const int y = px >> 3, x = px & 7;
  float acc[32];
#pragma unroll
  for (int i = 0; i < 32; i++) acc[i] = 0.f;
  for (int ch = 0; ch < 16; ch++) {
    __syncthreads();
    for (int i = t; i < 128 * 4 * 9; i += 256) {
      int cr = i / 9, k = i % 9;
      int co = cr >> 2, cil = cr & 3;
      ws[cr * 12 + k] = w[((size_t)co * 64 + ch * 4 + cil) * 9 + k];
    }
    __syncthreads();
#pragma unroll 1
    for (int cil = 0; cil < 4; cil++) {
      float vals[9];
#pragma unroll
      for (int dy = 0; dy < 3; dy++)
#pragma unroll
        for (int dx = 0; dx < 3; dx++)
          vals[dy * 3 + dx] = ins[(ch * 4 + cil) * 100 + (y + dy) * 10 + (x + dx)];
#pragma unroll
      for (int co = 0; co < 32; co++) {
        const float* wp = &ws[((cog * 32 + co) * 4 + cil) * 12];
        float4 wA = *(const float4*)wp;
        float4 wB = *(const float4*)(wp + 4);
        float w8 = wp[8];
        acc[co] += vals[0] * wA.x + vals[1] * wA.y + vals[2] * wA.z + vals[3] * wA.w +
                   vals[4] * wB.x + vals[5] * wB.y + vals[6] * wB.z + vals[7] * wB.w +
                   vals[8] * w8;
      }
    }
  }
  if (MODE == 1) {
#pragma unroll
    for (int co = 0; co < 32; co++) {
      float a = acc[co];
      float s = waveSum(a), sq = waveSum(a * a);
      if ((t & 63) == 0) { red[2 * (cog * 32 + co)] = s; red[2 * (cog * 32 + co) + 1] = sq; }
    }
    __syncthreads();
    for (int i = t; i < 256; i += 256) partials[(size_t)b * 256 + i] = red[i];
  } else if (MODE == 0) {
#pragma unroll
    for (int co = 0; co < 32; co++) {
      int c = cog * 32 + co;
      float v = fmaxf(acc[co] * scale[c] + shift[c], 0.f);
      out[(((size_t)b * 128 + c) * 8 + y) * 8 + x] = v;
    }
  } else {
#pragma unroll
    for (int co = 0; co < 32; co++) {
      int c = cog * 32 + co;
      out[(((size_t)b * 128 + c) * 8 + y) * 8 + x] = acc[co];
    }
  }
}

// ============================================================================
// BN helpers
// ============================================================================
__global__ __launch_bounds__(256) void reduce_partials_kernel(
    const float* __restrict__ partials, int nblk, int Q, double* __restrict__ sums) {
  int q = blockIdx.x;
  double acc = 0.0;
  for (int i = threadIdx.x; i < nblk; i += 256) acc += (double)partials[(size_t)i * Q + q];
  __shared__ double red[256];
  red[threadIdx.x] = acc;
  __syncthreads();
  for (int s = 128; s > 0; s >>= 1) {
    if (threadIdx.x < s) red[threadIdx.x] += red[threadIdx.x + s];
    __syncthreads();
  }
  if (threadIdx.x == 0) sums[q] = red[0];
}

__global__ __launch_bounds__(1024) void col_stats_kernel(
    const float* __restrict__ X, int R, int C, double* __restrict__ sums) {
  int c0 = blockIdx.x * 64;
  int cl = threadIdx.x & 63, rg = threadIdx.x >> 6;
  double s = 0.0, sq = 0.0;
  for (int r = rg; r < R; r += 16) {
    float v = X[(size_t)r * C + c0 + cl];
    s += v; sq += (double)v * (double)v;
  }
  __shared__ double red[16][64][2];
  red[rg][cl][0] = s; red[rg][cl][1] = sq;
  __syncthreads();
  if (rg == 0) {
    for (int i = 1; i < 16; i++) { s += red[i][cl][0]; sq += red[i][cl][1]; }
    sums[2 * (c0 + cl)] = s; sums[2 * (c0 + cl) + 1] = sq;
  }
}

__global__ void bn_finalize_kernel(const double* __restrict__ sums,
                                   const float* __restrict__ g, const float* __restrict__ b,
                                   float* __restrict__ scale, float* __restrict__ shift,
                                   int C, double invN) {
  int c = blockIdx.x * blockDim.x + threadIdx.x;
  if (c >= C) return;
  double m = sums[2 * c] * invN;
  double v = sums[2 * c + 1] * invN - m * m;
  double sc = (double)g[c] / sqrt(v + 1e-5);
  scale[c] = (float)sc;
  shift[c] = (float)((double)b[c] - m * sc);
}

__global__ void bn_relu_apply_kernel(float* __restrict__ X, const float* __restrict__ scale,
                                     const float* __restrict__ shift, size_t n, int C) {
  size_t i = (size_t)blockIdx.x * blockDim.x + threadIdx.x;
  if (i >= n) return;
  int c = (int)(i % (size_t)C);
  float v = X[i] * scale[c] + shift[c];
  X[i] = fmaxf(v, 0.f);
}

// ============================================================================
// Tiled fp32 GEMM, NT: C[M,N] = A[M,K] * B[N,K]^T (+bias, relu).
// ============================================================================
template <int BIASRELU>
__global__ __launch_bounds__(256) void gemm_nt_kernel(
    const float* __restrict__ A, const float* __restrict__ B,
    const float* __restrict__ bias, float* __restrict__ C, int M, int N, int K) {
  __shared__ float As[16][64];
  __shared__ float Bs[16][64];
  const int t = threadIdx.x;
  const int tn = t & 15, tm = t >> 4;
  const int m0 = blockIdx.y << 6, n0 = blockIdx.x << 6;
  const int lr = t >> 2, lk = (t & 3) << 2;
  const float* Ap = A + (size_t)(m0 + lr) * K + lk;
  const float* Bp = B + (size_t)(n0 + lr) * K + lk;
  float acc[4][4];
#pragma unroll
  for (int i = 0; i < 4; i++)
#pragma unroll
    for (int j = 0; j < 4; j++) acc[i][j] = 0.f;
  for (int k0 = 0; k0 < K; k0 += 16) {
    float4 av = *(const float4*)(Ap + k0);
    float4 bv = *(const float4*)(Bp + k0);
    __syncthreads();
    As[lk + 0][lr] = av.x; As[lk + 1][lr] = av.y; As[lk + 2][lr] = av.z; As[lk + 3][lr] = av.w;
    Bs[lk + 0][lr] = bv.x; Bs[lk + 1][lr] = bv.y; Bs[lk + 2][lr] = bv.z; Bs[lk + 3][lr] = bv.w;
    __syncthreads();
#pragma unroll
    for (int kk = 0; kk < 16; kk++) {
      float4 a4 = *(const float4*)&As[kk][tm << 2];
      float4 b4 = *(const float4*)&Bs[kk][tn << 2];
      acc[0][0] += a4.x * b4.x; acc[0][1] += a4.x * b4.y; acc[0][2] += a4.x * b4.z; acc[0][3] += a4.x * b4.w;
      acc[1][0] += a4.y * b4.x; acc[1][1] += a4.y * b4.y; acc[1][2] += a4.y * b4.z; acc[1][3] += a4.y * b4.w;
      acc[2][0] += a4.z * b4.x; acc[2][1] += a4.z * b4.y; acc[2][2] += a4.z * b4.z; acc[2][3] += a4.z * b4.w;
      acc[3][0] += a4.w * b4.x; acc[3][1] += a4.w * b4.y; acc[3][2] += a4.w * b4.z; acc[3][3] += a4.w * b4.w;
    }
  }
#pragma unroll
  for (int i = 0; i < 4; i++) {
    int m = m0 + (tm << 2) + i;
    float4 o;
    float v0 = acc[i][0], v1 = acc[i][1], v2 = acc[i][2], v3 = acc[i][3];
    if (BIASRELU) {
      int nb = n0 + (tn << 2);
      v0 = fmaxf(v0 + bias[nb + 0], 0.f);
      v1 = fmaxf(v1 + bias[nb + 1], 0.f);
      v2 = fmaxf(v2 + bias[nb + 2], 0.f);
      v3 = fmaxf(v3 + bias[nb + 3], 0.f);
    }
    o.x = v0; o.y = v1; o.z = v2; o.w = v3;
    *(float4*)&C[(size_t)m * N + n0 + (tn << 2)] = o;
  }
}

// ============================================================================
// heads (double accumulation; sw_logits amplified 10x by TAU)
// ============================================================================
__global__ __launch_bounds__(256) void heads_kernel(
    const float* __restrict__ dpen, const float* __restrict__ dfc_w,
    const float* __restrict__ dfc_b, const float* __restrict__ sw_w,
    const float* __restrict__ sw_b, float* __restrict__ out_dom,
    float* __restrict__ swbuf) {
  int t = blockIdx.x * 256 + threadIdx.x;
  int b = t >> 2, j = t & 3;
  const float* row = dpen + (size_t)b * 384;
  const float* wr = (j < 2) ? (dfc_w + j * 384) : (sw_w + (j - 2) * 384);
  double s = 0.0;
  for (int k = 0; k < 384; k++) s += (double)row[k] * (double)wr[k];
  s += (double)((j < 2) ? dfc_b[j] : sw_b[j - 2]);
  if (j < 2) out_dom[b * 2 + j] = (float)s;
  else swbuf[b * 2 + (j - 2)] = (float)s;
}

// ============================================================================
// gumbel-softmax + categorical partition choice (threefry partitionable).
// ============================================================================
__global__ __launch_bounds__(256) void partition_kernel(
    const float* __restrict__ swbuf, float* __restrict__ out_pid,
    int* __restrict__ pidxI, float* __restrict__ ysum,
    uint32_t k1a, uint32_t k1b, uint32_t k2a, uint32_t k2b) {
  int b = blockIdx.x * 256 + threadIdx.x;
  if (b >= 4096) return;
  uint32_t j0 = (uint32_t)(2 * b), j1 = (uint32_t)(2 * b + 1);
  float f0 = u01_from_bits(tf_bits32(k1a, k1b, j0));
  float f1 = u01_from_bits(tf_bits32(k1a, k1b, j1));
  const float MINV = 1e-10f;
  float u0 = fmaxf(MINV, f0 * (1.0f - MINV) + MINV);
  float u1 = fmaxf(MINV, f1 * (1.0f - MINV) + MINV);
  double g0 = -log(-log((double)u0));
  double g1 = -log(-log((double)u1));
  double s0 = (double)swbuf[2 * b], s1 = (double)swbuf[2 * b + 1];
  double x0 = (s0 + g0) / 0.1;
  double x1 = (s1 + g1) / 0.1;
  double mx = fmax(x0, x1);
  double e0 = exp(x0 - mx), e1 = exp(x1 - mx);
  double es = e0 + e1;
  double y0 = e0 / es, y1 = e1 / es;
  float h0 = u01_from_bits(tf_bits32(k2a, k2b, j0));
  float h1 = u01_from_bits(tf_bits32(k2a, k2b, j1));
  const float TINY = 1.17549435e-38f;
  float v0 = fmaxf(TINY, h0 * (1.0f - TINY) + TINY);
  float v1 = fmaxf(TINY, h1 * (1.0f - TINY) + TINY);
  double gg0 = -log(-log((double)v0));
  double gg1 = -log(-log((double)v1));
  double l0 = log(y0 + 1e-20) + gg0;
  double l1 = log(y1 + 1e-20) + gg1;
  int p = (l1 > l0) ? 1 : 0;
  out_pid[b] = (float)p;
  pidxI[b] = p;
  ysum[b] = (float)(y0 + y1);
}

// ============================================================================
// final head
// ============================================================================
__global__ __launch_bounds__(256) void final_kernel(
    const float* __restrict__ h, const float* __restrict__ p2w,
    const float* __restrict__ p2b, const int* __restrict__ pidxI,
    const float* __restrict__ ysum, float* __restrict__ out0) {
  int t = blockIdx.x * 256 + threadIdx.x;
  if (t >= 40960) return;
  int b = t / 10, c = t % 10;
  int p = pidxI[b];
  const float* hr = h + (size_t)b * 384 + p * 192;
  const float* wr = p2w + ((size_t)p * 10 + c) * 192;
  float s = 0.f;
  for (int o = 0; o < 192; o++) s += hr[o] * wr[o];
  s += p2b[p * 10 + c];
  out0[t] = s * ysum[b];
}

// ============================================================================
// Launch orchestration. BIG path (ws >= ~503 MB): single-pass conv2/conv3
// storing raw activations; stats/BN via memory-bound elementwise.
// Fallback: round-3 two-pass recompute scheme (~224 MB).
// ============================================================================
extern "C" void kernel_launch(void* const* d_in, const int* in_sizes, int n_in,
                              void* d_out, int out_size, void* d_ws, size_t ws_size,
                              hipStream_t stream) {
  const float* input   = (const float*)d_in[0];
  const float* conv1_w = (const float*)d_in[1];
  const float* bn1_g   = (const float*)d_in[3];
  const float* bn1_b   = (const float*)d_in[4];
  const float* conv2_w = (const float*)d_in[5];
  const float* bn2_g   = (const float*)d_in[7];
  const float* bn2_b   = (const float*)d_in[8];
  const float* conv3_w = (const float*)d_in[9];
  const float* bn3_g   = (const float*)d_in[11];
  const float* bn3_b   = (const float*)d_in[12];
  const float* pre_w   = (const float*)d_in[13];
  const float* bnp_g   = (const float*)d_in[15];
  const float* bnp_b   = (const float*)d_in[16];
  const float* disc_w  = (const float*)d_in[17];
  const float* bnd_g   = (const float*)d_in[19];
  const float* bnd_b   = (const float*)d_in[20];
  const float* dfc_w   = (const float*)d_in[21];
  const float* dfc_b   = (const float*)d_in[22];
  const float* sw_w    = (const float*)d_in[23];
  const float* sw_b    = (const float*)d_in[24];
  const float* p1_w    = (const float*)d_in[25];
  const float* p1_b    = (const float*)d_in[26];
  const float* p2_w    = (const float*)d_in[27];
  const float* p2_b    = (const float*)d_in[28];

  float* W = (float*)d_ws;
  const bool big = ws_size >= (size_t)503406592;

  float *pool1, *act2, *pool2, *act3, *featp, *dpen, *hbuf, *swbuf, *ysum, *part, *scale, *shift;
  int* pidxI;
  double* sums;
  if (big) {
    pool1 = W + 0;
    act2  = W + 33554432;    // [4096][64][16][16] raw
    pool2 = W + 100663296;
    act3  = W + 0;           // alias pool1 (dead after conv2_full)
    featp = W + 117440512;
    dpen  = W + 121634816;
    hbuf  = W + 123207680;
    swbuf = W + 124780544;
    ysum  = W + 124788736;
    pidxI = (int*)(W + 124792832);
    part  = W + 124796928;
    sums  = (double*)(W + 125845504);
    scale = W + 125849600;
    shift = W + 125850624;
  } else {
    pool1 = W + 0;
    act2  = nullptr;
    pool2 = W + 33554432;
    act3  = W + 0;
    featp = W + 50331648;
    dpen  = W + 54525952;
    hbuf  = W + 56098816;
    swbuf = W + 57671680;
    ysum  = W + 57679872;
    pidxI = (int*)(W + 57683968);
    part  = W + 57688064;
    sums  = (double*)(W + 58736640);
    scale = W + 58740736;
    shift = W + 58741760;
  }

  float* out_cls = (float*)d_out;
  float* out_dom = out_cls + 40960;
  float* out_pid = out_cls + 49152;

  uint32_t k1a, k1b, k2a, k2b;
  threefry2x32(0u, 42u, 0u, 0u, k1a, k1b);
  threefry2x32(0u, 42u, 0u, 1u, k2a, k2b);

  // --- conv1 + BN1 + ReLU + pool (2-pass) ---
  conv1_stats_kernel<<<dim3(16384), dim3(256), 0, stream>>>(input, conv1_w, part);
  reduce_partials_kernel<<<dim3(64), dim3(256), 0, stream>>>(part, 16384, 64, sums);
  bn_finalize_kernel<<<dim3(1), dim3(64), 0, stream>>>(sums, bn1_g, bn1_b, scale, shift, 32, 1.0 / (4096.0 * 1024.0));
  conv1_apply_kernel<<<dim3(4096), dim3(256), 0, stream>>>(input, conv1_w, scale, shift, pool1);

  if (big) {
    // --- conv2 once -> act2; stats + BN+ReLU+pool as memory passes ---
    conv2_full_kernel<<<dim3(4096), dim3(256), 0, stream>>>(pool1, conv2_w, act2);
    act_stats_kernel<64, 256><<<dim3(4096), dim3(256), 0, stream>>>(act2, part);
    reduce_partials_kernel<<<dim3(128), dim3(256), 0, stream>>>(part, 4096, 128, sums);
    bn_finalize_kernel<<<dim3(1), dim3(64), 0, stream>>>(sums, bn2_g, bn2_b, scale, shift, 64, 1.0 / (4096.0 * 256.0));
    bn_relu_pool_kernel<<<dim3(65536), dim3(256), 0, stream>>>(act2, pool2, scale, shift);

    // --- conv3 once -> act3 raw; stats + in-place BN+ReLU ---
    conv3_kernel<2><<<dim3(4096), dim3(256), 0, stream>>>(pool2, conv3_w, nullptr, nullptr, act3, nullptr);
    act_stats_kernel<128, 64><<<dim3(4096), dim3(256), 0, stream>>>(act3, part);
    reduce_partials_kernel<<<dim3(256), dim3(256), 0, stream>>>(part, 4096, 256, sums);
    bn_finalize_kernel<<<dim3(1), dim3(128), 0, stream>>>(sums, bn3_g, bn3_b, scale, shift, 128, 1.0 / (4096.0 * 64.0));
    bn_relu_hw_kernel<<<dim3(131072), dim3(256), 0, stream>>>(act3, scale, shift, (size_t)33554432);
  } else {
    // --- fallback: two-pass recompute scheme ---
    conv2_stats_kernel<<<dim3(4096), dim3(256), 0, stream>>>(pool1, conv2_w, part);
    reduce_partials_kernel<<<dim3(128), dim3(256), 0, stream>>>(part, 4096, 128, sums);
    bn_finalize_kernel<<<dim3(1), dim3(64), 0, stream>>>(sums, bn2_g, bn2_b, scale, shift, 64, 1.0 / (4096.0 * 256.0));
    conv2_apply_kernel<<<dim3(4096), dim3(256), 0, stream>>>(pool1, conv2_w, scale, shift, pool2);

    conv3_kernel<1><<<dim3(4096), dim3(256), 0, stream>>>(pool2, conv3_w, nullptr, nullptr, nullptr, part);
    reduce_partials_kernel<<<dim3(256), dim3(256), 0, stream>>>(part, 4096, 256, sums);
    bn_finalize_kernel<<<dim3(1), dim3(128), 0, stream>>>(sums, bn3_g, bn3_b, scale, shift, 128, 1.0 / (4096.0 * 64.0));
    conv3_kernel<0><<<dim3(4096), dim3(256), 0, stream>>>(pool2, conv3_w, scale, shift, act3, nullptr);
  }

  // --- pre FC 8192->1024 + BN + ReLU ---
  gemm_nt_kernel<0><<<dim3(16, 64), dim3(256), 0, stream>>>(act3, pre_w, (const float*)nullptr, featp, 4096, 1024, 8192);
  col_stats_kernel<<<dim3(16), dim3(1024), 0, stream>>>(featp, 4096, 1024, sums);
  bn_finalize_kernel<<<dim3(4), dim3(256), 0, stream>>>(sums, bnp_g, bnp_b, scale, shift, 1024, 1.0 / 4096.0);
  bn_relu_apply_kernel<<<dim3(16384), dim3(256), 0, stream>>>(featp, scale, shift, (size_t)4194304, 1024);

  // --- disc FC 1024->384 + BN + ReLU ---
  gemm_nt_kernel<0><<<dim3(6, 64), dim3(256), 0, stream>>>(featp, disc_w, (const float*)nullptr, dpen, 4096, 384, 1024);
  col_stats_kernel<<<dim3(6), dim3(1024), 0, stream>>>(dpen, 4096, 384, sums);
  bn_finalize_kernel<<<dim3(2), dim3(256), 0, stream>>>(sums, bnd_g, bnd_b, scale, shift, 384, 1.0 / 4096.0);
  bn_relu_apply_kernel<<<dim3(6144), dim3(256), 0, stream>>>(dpen, scale, shift, (size_t)1572864, 384);

  // --- heads + partition sampling ---
  heads_kernel<<<dim3(64), dim3(256), 0, stream>>>(dpen, dfc_w, dfc_b, sw_w, sw_b, out_dom, swbuf);
  partition_kernel<<<dim3(16), dim3(256), 0, stream>>>(swbuf, out_pid, pidxI, ysum, k1a, k1b, k2a, k2b);

  // --- experts: dense p1 for both partitions, then gather + p2 ---
  gemm_nt_kernel<1><<<dim3(6, 64), dim3(256), 0, stream>>>(featp, p1_w, p1_b, hbuf, 4096, 384, 1024);
  final_kernel<<<dim3(160), dim3(256), 0, stream>>>(hbuf, p2_w, p2_b, pidxI, ysum, out_cls);
}

// Round 5
// 5045.176 us; speedup vs baseline: 1.2354x; 1.2337x over previous
//
#include <hip/hip_runtime.h>
#include <cstdint>
#include <cstddef>

// ============================================================================
// Threefry2x32 (matches jax._src.prng.threefry2x32).
// ============================================================================
__host__ __device__ inline void threefry2x32(uint32_t k0, uint32_t k1,
                                             uint32_t x0, uint32_t x1,
                                             uint32_t& o0, uint32_t& o1) {
  uint32_t ks2 = k0 ^ k1 ^ 0x1BD11BDAu;
  uint32_t v0 = x0 + k0, v1 = x1 + k1;
#define TF_R(r) { v0 += v1; v1 = (v1 << (r)) | (v1 >> (32 - (r))); v1 ^= v0; }
  TF_R(13) TF_R(15) TF_R(26) TF_R(6)
  v0 += k1; v1 += ks2 + 1u;
  TF_R(17) TF_R(29) TF_R(16) TF_R(24)
  v0 += ks2; v1 += k0 + 2u;
  TF_R(13) TF_R(15) TF_R(26) TF_R(6)
  v0 += k0; v1 += k1 + 3u;
  TF_R(17) TF_R(29) TF_R(16) TF_R(24)
  v0 += k1; v1 += ks2 + 4u;
  TF_R(13) TF_R(15) TF_R(26) TF_R(6)
  v0 += ks2; v1 += k0 + 5u;
#undef TF_R
  o0 = v0; o1 = v1;
}

// jax partitionable random_bits, bit_width=32: bits = o0 ^ o1 (hi=0, lo=j).
__device__ __forceinline__ uint32_t tf_bits32(uint32_t k0, uint32_t k1, uint32_t j) {
  uint32_t o0, o1;
  threefry2x32(k0, k1, 0u, j, o0, o1);
  return o0 ^ o1;
}

__device__ __forceinline__ float u01_from_bits(uint32_t bits) {
  return __uint_as_float((bits >> 9) | 0x3f800000u) - 1.0f;  // [0,1)
}

__device__ __forceinline__ float waveSum(float v) {
#pragma unroll
  for (int off = 32; off > 0; off >>= 1) v += __shfl_down(v, off, 64);
  return v;
}

// ============================================================================
// conv1 (3->32, 32x32, pad1) pass A: per-channel (sum,sumsq) partials.
// Weights read via wave-uniform global addresses -> SGPR broadcast (s_load).
// ============================================================================
__global__ __launch_bounds__(256) void conv1_stats_kernel(
    const float* __restrict__ in, const float* __restrict__ w,
    float* __restrict__ partials) {
  __shared__ float ins[3 * 10 * 34];
  __shared__ float red[4][64];
  const int blk = blockIdx.x, t = threadIdx.x;
  const int b = blk >> 2, r0 = (blk & 3) << 3;
  for (int i = t; i < 3 * 10 * 34; i += 256) {
    int ci = i / 340, r = i % 340, iy = r / 34, ix = r % 34;
    int y = r0 - 1 + iy, x = ix - 1;
    float v = 0.f;
    if ((unsigned)y < 32u && (unsigned)x < 32u)
      v = in[(((size_t)b * 3 + ci) * 32 + y) * 32 + x];
    ins[i] = v;
  }
  __syncthreads();
  const int ly = t >> 5, x = t & 31, wv = t >> 6, ln = t & 63;
  float win[27];
#pragma unroll
  for (int ci = 0; ci < 3; ci++)
#pragma unroll
    for (int dy = 0; dy < 3; dy++)
#pragma unroll
      for (int dx = 0; dx < 3; dx++)
        win[ci * 9 + dy * 3 + dx] = ins[ci * 340 + (ly + dy) * 34 + (x + dx)];
#pragma unroll 1
  for (int co = 0; co < 32; co++) {
    float a = 0.f;
#pragma unroll
    for (int ci = 0; ci < 3; ci++) {
      const float* wp = w + (co * 3 + ci) * 9;  // uniform -> s_load
#pragma unroll
      for (int k = 0; k < 9; k++) a += win[ci * 9 + k] * wp[k];
    }
    float s = waveSum(a), sq = waveSum(a * a);
    if (ln == 0) { red[wv][2 * co] = s; red[wv][2 * co + 1] = sq; }
  }
  __syncthreads();
  for (int i = t; i < 64; i += 256)
    partials[(size_t)blk * 64 + i] = red[0][i] + red[1][i] + red[2][i] + red[3][i];
}

// conv1 pass B: recompute conv, BN+ReLU, 2x2 maxpool -> pool1.
__global__ __launch_bounds__(256) void conv1_apply_kernel(
    const float* __restrict__ in, const float* __restrict__ w,
    const float* __restrict__ scale, const float* __restrict__ shift,
    float* __restrict__ out) {
  __shared__ float ins[3 * 34 * 34];
  const int b = blockIdx.x, t = threadIdx.x;
  for (int i = t; i < 3 * 34 * 34; i += 256) {
    int ci = i / 1156, r = i % 1156, iy = r / 34, ix = r % 34;
    int y = iy - 1, x = ix - 1;
    float v = 0.f;
    if ((unsigned)y < 32u && (unsigned)x < 32u)
      v = in[(((size_t)b * 3 + ci) * 32 + y) * 32 + x];
    ins[i] = v;
  }
  __syncthreads();
  const int py = t >> 4, px = t & 15;
  float win[3][4][4];
#pragma unroll
  for (int ci = 0; ci < 3; ci++)
#pragma unroll
    for (int r = 0; r < 4; r++)
#pragma unroll
      for (int c = 0; c < 4; c++)
        win[ci][r][c] = ins[ci * 1156 + (2 * py + r) * 34 + (2 * px + c)];
#pragma unroll 1
  for (int co = 0; co < 32; co++) {
    float acc00 = 0.f, acc01 = 0.f, acc10 = 0.f, acc11 = 0.f;
#pragma unroll
    for (int ci = 0; ci < 3; ci++) {
      const float* wp = w + (co * 3 + ci) * 9;  // uniform -> s_load
#pragma unroll
      for (int dy = 0; dy < 3; dy++)
#pragma unroll
        for (int dx = 0; dx < 3; dx++) {
          float wv = wp[dy * 3 + dx];
          acc00 += win[ci][dy][dx] * wv;
          acc01 += win[ci][dy][dx + 1] * wv;
          acc10 += win[ci][dy + 1][dx] * wv;
          acc11 += win[ci][dy + 1][dx + 1] * wv;
        }
    }
    float sc = scale[co], sh = shift[co];
    float best = 0.f;
    best = fmaxf(best, acc00 * sc + sh);
    best = fmaxf(best, acc01 * sc + sh);
    best = fmaxf(best, acc10 * sc + sh);
    best = fmaxf(best, acc11 * sc + sh);
    out[(((size_t)b * 32 + co) * 16 + py) * 16 + px] = best;
  }
}

// ============================================================================
// conv2 (32->64, 16x16, pad1) pass A: stats only. 8 co-chunks of 8.
// Weights via uniform global reads (SGPR). LDS = ins 41.5K + red 2K.
// ============================================================================
__global__ __launch_bounds__(256) void conv2_stats_kernel(
    const float* __restrict__ in, const float* __restrict__ w,
    float* __restrict__ partials) {
  __shared__ float ins[32 * 18 * 18];
  __shared__ float red[4][128];
  const int b = blockIdx.x, t = threadIdx.x;
  for (int i = t; i < 32 * 18 * 18; i += 256) {
    int ci = i / 324, r = i % 324, iy = r / 18, ix = r % 18;
    int y = iy - 1, x = ix - 1;
    float v = 0.f;
    if ((unsigned)y < 16u && (unsigned)x < 16u)
      v = in[(((size_t)b * 32 + ci) * 16 + y) * 16 + x];
    ins[i] = v;
  }
  __syncthreads();
  const int y = t >> 4, x = t & 15, wv = t >> 6, ln = t & 63;
#pragma unroll 1
  for (int cc = 0; cc < 8; cc++) {
    float acc[8];
#pragma unroll
    for (int i = 0; i < 8; i++) acc[i] = 0.f;
#pragma unroll 1
    for (int ci = 0; ci < 32; ci++) {
      float vals[9];
#pragma unroll
      for (int dy = 0; dy < 3; dy++)
#pragma unroll
        for (int dx = 0; dx < 3; dx++)
          vals[dy * 3 + dx] = ins[ci * 324 + (y + dy) * 18 + (x + dx)];
#pragma unroll
      for (int co = 0; co < 8; co++) {
        const float* wp = w + ((size_t)(cc * 8 + co) * 32 + ci) * 9;  // uniform
#pragma unroll
        for (int k = 0; k < 9; k++) acc[co] += vals[k] * wp[k];
      }
    }
#pragma unroll
    for (int co = 0; co < 8; co++) {
      float a = acc[co];
      float s = waveSum(a), sq = waveSum(a * a);
      if (ln == 0) { red[wv][2 * (cc * 8 + co)] = s; red[wv][2 * (cc * 8 + co) + 1] = sq; }
    }
  }
  __syncthreads();
  for (int i = t; i < 128; i += 256)
    partials[(size_t)b * 128 + i] = red[0][i] + red[1][i] + red[2][i] + red[3][i];
}

// conv2 pass B: recompute conv2, BN+ReLU+2x2 pool -> pool2 [4096][64][8][8].
__global__ __launch_bounds__(256) void conv2_apply_kernel(
    const float* __restrict__ in, const float* __restrict__ w,
    const float* __restrict__ scale, const float* __restrict__ shift,
    float* __restrict__ out) {
  __shared__ float ins[32 * 18 * 18];
  __shared__ float os[8 * 256];
  const int b = blockIdx.x, t = threadIdx.x;
  for (int i = t; i < 32 * 18 * 18; i += 256) {
    int ci = i / 324, r = i % 324, iy = r / 18, ix = r % 18;
    int y = iy - 1, x = ix - 1;
    float v = 0.f;
    if ((unsigned)y < 16u && (unsigned)x < 16u)
      v = in[(((size_t)b * 32 + ci) * 16 + y) * 16 + x];
    ins[i] = v;
  }
  __syncthreads();
  const int y = t >> 4, x = t & 15;
#pragma unroll 1
  for (int cc = 0; cc < 8; cc++) {
    if (cc) __syncthreads();  // protect os reuse
    float acc[8];
#pragma unroll
    for (int i = 0; i < 8; i++) acc[i] = 0.f;
#pragma unroll 1
    for (int ci = 0; ci < 32; ci++) {
      float vals[9];
#pragma unroll
      for (int dy = 0; dy < 3; dy++)
#pragma unroll
        for (int dx = 0; dx < 3; dx++)
          vals[dy * 3 + dx] = ins[ci * 324 + (y + dy) * 18 + (x + dx)];
#pragma unroll
      for (int co = 0; co < 8; co++) {
        const float* wp = w + ((size_t)(cc * 8 + co) * 32 + ci) * 9;  // uniform
#pragma unroll
        for (int k = 0; k < 9; k++) acc[co] += vals[k] * wp[k];
      }
    }
#pragma unroll
    for (int co = 0; co < 8; co++) os[co * 256 + t] = acc[co];
    __syncthreads();
    for (int i = t; i < 8 * 64; i += 256) {
      int co = i >> 6, pl = i & 63, py = pl >> 3, px = pl & 7;
      int c = cc * 8 + co;
      float sc = scale[c], sh = shift[c];
      const float* o = &os[co * 256 + (2 * py) * 16 + 2 * px];
      float m = 0.f;
      m = fmaxf(m, o[0] * sc + sh);
      m = fmaxf(m, o[1] * sc + sh);
      m = fmaxf(m, o[16] * sc + sh);
      m = fmaxf(m, o[17] * sc + sh);
      out[(((size_t)b * 64 + c) * 8 + py) * 8 + px] = m;
    }
  }
}

// ============================================================================
// conv3 (64->128, 8x8, pad1). MODE 1: stats partials. MODE 0: BN+ReLU store.
// block 256 = 64 px x 4 co-groups of 32. Weights via readfirstlane-uniform
// global reads. LDS = ins 25.6K + red 1K -> high occupancy.
// ============================================================================
template <int MODE>
__global__ __launch_bounds__(256) void conv3_kernel(
    const float* __restrict__ in, const float* __restrict__ w,
    const float* __restrict__ scale, const float* __restrict__ shift,
    float* __restrict__ out, float* __restrict__ partials) {
  __shared__ float ins[64 * 10 * 10];
  __shared__ float red[256];
  const int b = blockIdx.x, t = threadIdx.x;
  for (int i = t; i < 64 * 10 * 10; i += 256) {
    int ci = i / 100, r = i % 100, iy = r / 10, ix = r % 10;
    int y = iy - 1, x = ix - 1;
    float v = 0.f;
    if ((unsigned)y < 8u && (unsigned)x < 8u)
      v = in[(((size_t)b * 64 + ci) * 8 + y) * 8 + x];
    ins[i] = v;
  }
  __syncthreads();
  const int px = t & 63, cog = t >> 6;
  // wave-uniform co-group base, forced into an SGPR for weight scalarization
  const int cogu = __builtin_amdgcn_readfirstlane(cog);
  const int y = px >> 3, x = px & 7;
  float acc[32];
#pragma unroll
  for (int i = 0; i < 32; i++) acc[i] = 0.f;
#pragma unroll 1
  for (int ci = 0; ci < 64; ci++) {
    float vals[9];
#pragma unroll
    for (int dy = 0; dy < 3; dy++)
#pragma unroll
      for (int dx = 0; dx < 3; dx++)
        vals[dy * 3 + dx] = ins[ci * 100 + (y + dy) * 10 + (x + dx)];
#pragma unroll
    for (int co = 0; co < 32; co++) {
      const float* wp = w + ((size_t)(cogu * 32 + co) * 64 + ci) * 9;  // uniform
#pragma unroll
      for (int k = 0; k < 9; k++) acc[co] += vals[k] * wp[k];
    }
  }
  if (MODE == 1) {
#pragma unroll
    for (int co = 0; co < 32; co++) {
      float a = acc[co];
      float s = waveSum(a), sq = waveSum(a * a);
      if ((t & 63) == 0) { red[2 * (cog * 32 + co)] = s; red[2 * (cog * 32 + co) + 1] = sq; }
    }
    __syncthreads();
    for (int i = t; i < 256; i += 256) partials[(size_t)b * 256 + i] = red[i];
  } else {
#pragma unroll
    for (int co = 0; co < 32; co++) {
      int c = cog * 32 + co;
      float v = fmaxf(acc[co] * scale[c] + shift[c], 0.f);
      out[(((size_t)b * 128 + c) * 8 + y) * 8 + x] = v;
    }
  }
}

// ============================================================================
// BN helpers
// ============================================================================
__global__ __launch_bounds__(256) void reduce_partials_kernel(
    const float* __restrict__ partials, int nblk, int Q, double* __restrict__ sums) {
  int q = blockIdx.x;
  double acc = 0.0;
  for (int i = threadIdx.x; i < nblk; i += 256) acc += (double)partials[(size_t)i * Q + q];
  __shared__ double red[256];
  red[threadIdx.x] = acc;
  __syncthreads();
  for (int s = 128; s > 0; s >>= 1) {
    if (threadIdx.x < s) red[threadIdx.x] += red[threadIdx.x + s];
    __syncthreads();
  }
  if (threadIdx.x == 0) sums[q] = red[0];
}

__global__ __launch_bounds__(1024) void col_stats_kernel(
    const float* __restrict__ X, int R, int C, double* __restrict__ sums) {
  int c0 = blockIdx.x * 64;
  int cl = threadIdx.x & 63, rg = threadIdx.x >> 6;
  double s = 0.0, sq = 0.0;
  for (int r = rg; r < R; r += 16) {
    float v = X[(size_t)r * C + c0 + cl];
    s += v; sq += (double)v * (double)v;
  }
  __shared__ double red[16][64][2];
  red[rg][cl][0] = s; red[rg][cl][1] = sq;
  __syncthreads();
  if (rg == 0) {
    for (int i = 1; i < 16; i++) { s += red[i][cl][0]; sq += red[i][cl][1]; }
    sums[2 * (c0 + cl)] = s; sums[2 * (c0 + cl) + 1] = sq;
  }
}

__global__ void bn_finalize_kernel(const double* __restrict__ sums,
                                   const float* __restrict__ g, const float* __restrict__ b,
                                   float* __restrict__ scale, float* __restrict__ shift,
                                   int C, double invN) {
  int c = blockIdx.x * blockDim.x + threadIdx.x;
  if (c >= C) return;
  double m = sums[2 * c] * invN;
  double v = sums[2 * c + 1] * invN - m * m;
  double sc = (double)g[c] / sqrt(v + 1e-5);
  scale[c] = (float)sc;
  shift[c] = (float)((double)b[c] - m * sc);
}

__global__ void bn_relu_apply_kernel(float* __restrict__ X, const float* __restrict__ scale,
                                     const float* __restrict__ shift, size_t n, int C) {
  size_t i = (size_t)blockIdx.x * blockDim.x + threadIdx.x;
  if (i >= n) return;
  int c = (int)(i % (size_t)C);
  float v = X[i] * scale[c] + shift[c];
  X[i] = fmaxf(v, 0.f);
}

// ============================================================================
// Tiled fp32 GEMM, NT: C[M,N] = A[M,K] * B[N,K]^T (+bias, relu).
// ============================================================================
template <int BIASRELU>
__global__ __launch_bounds__(256) void gemm_nt_kernel(
    const float* __restrict__ A, const float* __restrict__ B,
    const float* __restrict__ bias, float* __restrict__ C, int M, int N, int K) {
  __shared__ float As[16][64];
  __shared__ float Bs[16][64];
  const int t = threadIdx.x;
  const int tn = t & 15, tm = t >> 4;
  const int m0 = blockIdx.y << 6, n0 = blockIdx.x << 6;
  const int lr = t >> 2, lk = (t & 3) << 2;
  const float* Ap = A + (size_t)(m0 + lr) * K + lk;
  const float* Bp = B + (size_t)(n0 + lr) * K + lk;
  float acc[4][4];
#pragma unroll
  for (int i = 0; i < 4; i++)
#pragma unroll
    for (int j = 0; j < 4; j++) acc[i][j] = 0.f;
  for (int k0 = 0; k0 < K; k0 += 16) {
    float4 av = *(const float4*)(Ap + k0);
    float4 bv = *(const float4*)(Bp + k0);
    __syncthreads();
    As[lk + 0][lr] = av.x; As[lk + 1][lr] = av.y; As[lk + 2][lr] = av.z; As[lk + 3][lr] = av.w;
    Bs[lk + 0][lr] = bv.x; Bs[lk + 1][lr] = bv.y; Bs[lk + 2][lr] = bv.z; Bs[lk + 3][lr] = bv.w;
    __syncthreads();
#pragma unroll
    for (int kk = 0; kk < 16; kk++) {
      float4 a4 = *(const float4*)&As[kk][tm << 2];
      float4 b4 = *(const float4*)&Bs[kk][tn << 2];
      acc[0][0] += a4.x * b4.x; acc[0][1] += a4.x * b4.y; acc[0][2] += a4.x * b4.z; acc[0][3] += a4.x * b4.w;
      acc[1][0] += a4.y * b4.x; acc[1][1] += a4.y * b4.y; acc[1][2] += a4.y * b4.z; acc[1][3] += a4.y * b4.w;
      acc[2][0] += a4.z * b4.x; acc[2][1] += a4.z * b4.y; acc[2][2] += a4.z * b4.z; acc[2][3] += a4.z * b4.w;
      acc[3][0] += a4.w * b4.x; acc[3][1] += a4.w * b4.y; acc[3][2] += a4.w * b4.z; acc[3][3] += a4.w * b4.w;
    }
  }
#pragma unroll
  for (int i = 0; i < 4; i++) {
    int m = m0 + (tm << 2) + i;
    float4 o;
    float v0 = acc[i][0], v1 = acc[i][1], v2 = acc[i][2], v3 = acc[i][3];
    if (BIASRELU) {
      int nb = n0 + (tn << 2);
      v0 = fmaxf(v0 + bias[nb + 0], 0.f);
      v1 = fmaxf(v1 + bias[nb + 1], 0.f);
      v2 = fmaxf(v2 + bias[nb + 2], 0.f);
      v3 = fmaxf(v3 + bias[nb + 3], 0.f);
    }
    o.x = v0; o.y = v1; o.z = v2; o.w = v3;
    *(float4*)&C[(size_t)m * N + n0 + (tn << 2)] = o;
  }
}

// ============================================================================
// heads (double accumulation; sw_logits amplified 10x by TAU)
// ============================================================================
__global__ __launch_bounds__(256) void heads_kernel(
    const float* __restrict__ dpen, const float* __restrict__ dfc_w,
    const float* __restrict__ dfc_b, const float* __restrict__ sw_w,
    const float* __restrict__ sw_b, float* __restrict__ out_dom,
    float* __restrict__ swbuf) {
  int t = blockIdx.x * 256 + threadIdx.x;
  int b = t >> 2, j = t & 3;
  const float* row = dpen + (size_t)b * 384;
  const float* wr = (j < 2) ? (dfc_w + j * 384) : (sw_w + (j - 2) * 384);
  double s = 0.0;
  for (int k = 0; k < 384; k++) s += (double)row[k] * (double)wr[k];
  s += (double)((j < 2) ? dfc_b[j] : sw_b[j - 2]);
  if (j < 2) out_dom[b * 2 + j] = (float)s;
  else swbuf[b * 2 + (j - 2)] = (float)s;
}

// ============================================================================
// gumbel-softmax + categorical partition choice (threefry partitionable).
// ============================================================================
__global__ __launch_bounds__(256) void partition_kernel(
    const float* __restrict__ swbuf, float* __restrict__ out_pid,
    int* __restrict__ pidxI, float* __restrict__ ysum,
    uint32_t k1a, uint32_t k1b, uint32_t k2a, uint32_t k2b) {
  int b = blockIdx.x * 256 + threadIdx.x;
  if (b >= 4096) return;
  uint32_t j0 = (uint32_t)(2 * b), j1 = (uint32_t)(2 * b + 1);
  float f0 = u01_from_bits(tf_bits32(k1a, k1b, j0));
  float f1 = u01_from_bits(tf_bits32(k1a, k1b, j1));
  const float MINV = 1e-10f;
  float u0 = fmaxf(MINV, f0 * (1.0f - MINV) + MINV);
  float u1 = fmaxf(MINV, f1 * (1.0f - MINV) + MINV);
  double g0 = -log(-log((double)u0));
  double g1 = -log(-log((double)u1));
  double s0 = (double)swbuf[2 * b], s1 = (double)swbuf[2 * b + 1];
  double x0 = (s0 + g0) / 0.1;
  double x1 = (s1 + g1) / 0.1;
  double mx = fmax(x0, x1);
  double e0 = exp(x0 - mx), e1 = exp(x1 - mx);
  double es = e0 + e1;
  double y0 = e0 / es, y1 = e1 / es;
  float h0 = u01_from_bits(tf_bits32(k2a, k2b, j0));
  float h1 = u01_from_bits(tf_bits32(k2a, k2b, j1));
  const float TINY = 1.17549435e-38f;
  float v0 = fmaxf(TINY, h0 * (1.0f - TINY) + TINY);
  float v1 = fmaxf(TINY, h1 * (1.0f - TINY) + TINY);
  double gg0 = -log(-log((double)v0));
  double gg1 = -log(-log((double)v1));
  double l0 = log(y0 + 1e-20) + gg0;
  double l1 = log(y1 + 1e-20) + gg1;
  int p = (l1 > l0) ? 1 : 0;
  out_pid[b] = (float)p;
  pidxI[b] = p;
  ysum[b] = (float)(y0 + y1);
}

// ============================================================================
// final head
// ============================================================================
__global__ __launch_bounds__(256) void final_kernel(
    const float* __restrict__ h, const float* __restrict__ p2w,
    const float* __restrict__ p2b, const int* __restrict__ pidxI,
    const float* __restrict__ ysum, float* __restrict__ out0) {
  int t = blockIdx.x * 256 + threadIdx.x;
  if (t >= 40960) return;
  int b = t / 10, c = t % 10;
  int p = pidxI[b];
  const float* hr = h + (size_t)b * 384 + p * 192;
  const float* wr = p2w + ((size_t)p * 10 + c) * 192;
  float s = 0.f;
  for (int o = 0; o < 192; o++) s += hr[o] * wr[o];
  s += p2b[p * 10 + c];
  out0[t] = s * ysum[b];
}

// ============================================================================
// Launch orchestration. Two-pass recompute scheme, ~235 MB workspace (proven).
// ============================================================================
extern "C" void kernel_launch(void* const* d_in, const int* in_sizes, int n_in,
                              void* d_out, int out_size, void* d_ws, size_t ws_size,
                              hipStream_t stream) {
  const float* input   = (const float*)d_in[0];
  const float* conv1_w = (const float*)d_in[1];
  const float* bn1_g   = (const float*)d_in[3];
  const float* bn1_b   = (const float*)d_in[4];
  const float* conv2_w = (const float*)d_in[5];
  const float* bn2_g   = (const float*)d_in[7];
  const float* bn2_b   = (const float*)d_in[8];
  const float* conv3_w = (const float*)d_in[9];
  const float* bn3_g   = (const float*)d_in[11];
  const float* bn3_b   = (const float*)d_in[12];
  const float* pre_w   = (const float*)d_in[13];
  const float* bnp_g   = (const float*)d_in[15];
  const float* bnp_b   = (const float*)d_in[16];
  const float* disc_w  = (const float*)d_in[17];
  const float* bnd_g   = (const float*)d_in[19];
  const float* bnd_b   = (const float*)d_in[20];
  const float* dfc_w   = (const float*)d_in[21];
  const float* dfc_b   = (const float*)d_in[22];
  const float* sw_w    = (const float*)d_in[23];
  const float* sw_b    = (const float*)d_in[24];
  const float* p1_w    = (const float*)d_in[25];
  const float* p1_b    = (const float*)d_in[26];
  const float* p2_w    = (const float*)d_in[27];
  const float* p2_b    = (const float*)d_in[28];

  float* W = (float*)d_ws;
  float* pool1  = W + 0;
  float* pool2  = W + 33554432;
  float* act3   = W + 0;          // alias pool1 (dead by then)
  float* featp  = W + 50331648;
  float* dpen   = W + 54525952;
  float* hbuf   = W + 56098816;
  float* swbuf  = W + 57671680;
  float* ysum   = W + 57679872;
  int*   pidxI  = (int*)(W + 57683968);
  float* part   = W + 57688064;
  double* sums  = (double*)(W + 58736640);
  float* scale  = W + 58740736;
  float* shift  = W + 58741760;

  float* out_cls = (float*)d_out;
  float* out_dom = out_cls + 40960;
  float* out_pid = out_cls + 49152;

  uint32_t k1a, k1b, k2a, k2b;
  threefry2x32(0u, 42u, 0u, 0u, k1a, k1b);
  threefry2x32(0u, 42u, 0u, 1u, k2a, k2b);

  // --- conv1 + BN1 + ReLU + pool ---
  conv1_stats_kernel<<<dim3(16384), dim3(256), 0, stream>>>(input, conv1_w, part);
  reduce_partials_kernel<<<dim3(64), dim3(256), 0, stream>>>(part, 16384, 64, sums);
  bn_finalize_kernel<<<dim3(1), dim3(64), 0, stream>>>(sums, bn1_g, bn1_b, scale, shift, 32, 1.0 / (4096.0 * 1024.0));
  conv1_apply_kernel<<<dim3(4096), dim3(256), 0, stream>>>(input, conv1_w, scale, shift, pool1);

  // --- conv2 + BN2 + ReLU + pool (stats pass + recompute-apply pass) ---
  conv2_stats_kernel<<<dim3(4096), dim3(256), 0, stream>>>(pool1, conv2_w, part);
  reduce_partials_kernel<<<dim3(128), dim3(256), 0, stream>>>(part, 4096, 128, sums);
  bn_finalize_kernel<<<dim3(1), dim3(64), 0, stream>>>(sums, bn2_g, bn2_b, scale, shift, 64, 1.0 / (4096.0 * 256.0));
  conv2_apply_kernel<<<dim3(4096), dim3(256), 0, stream>>>(pool1, conv2_w, scale, shift, pool2);

  // --- conv3 + BN3 + ReLU (stats pass + recompute-apply pass) ---
  conv3_kernel<1><<<dim3(4096), dim3(256), 0, stream>>>(pool2, conv3_w, nullptr, nullptr, nullptr, part);
  reduce_partials_kernel<<<dim3(256), dim3(256), 0, stream>>>(part, 4096, 256, sums);
  bn_finalize_kernel<<<dim3(1), dim3(128), 0, stream>>>(sums, bn3_g, bn3_b, scale, shift, 128, 1.0 / (4096.0 * 64.0));
  conv3_kernel<0><<<dim3(4096), dim3(256), 0, stream>>>(pool2, conv3_w, scale, shift, act3, nullptr);

  // --- pre FC 8192->1024 + BN + ReLU ---
  gemm_nt_kernel<0><<<dim3(16, 64), dim3(256), 0, stream>>>(act3, pre_w, (const float*)nullptr, featp, 4096, 1024, 8192);
  col_stats_kernel<<<dim3(16), dim3(1024), 0, stream>>>(featp, 4096, 1024, sums);
  bn_finalize_kernel<<<dim3(4), dim3(256), 0, stream>>>(sums, bnp_g, bnp_b, scale, shift, 1024, 1.0 / 4096.0);
  bn_relu_apply_kernel<<<dim3(16384), dim3(256), 0, stream>>>(featp, scale, shift, (size_t)4194304, 1024);

  // --- disc FC 1024->384 + BN + ReLU ---
  gemm_nt_kernel<0><<<dim3(6, 64), dim3(256), 0, stream>>>(featp, disc_w, (const float*)nullptr, dpen, 4096, 384, 1024);
  col_stats_kernel<<<dim3(6), dim3(1024), 0, stream>>>(dpen, 4096, 384, sums);
  bn_finalize_kernel<<<dim3(2), dim3(256), 0, stream>>>(sums, bnd_g, bnd_b, scale, shift, 384, 1.0 / 4096.0);
  bn_relu_apply_kernel<<<dim3(6144), dim3(256), 0, stream>>>(dpen, scale, shift, (size_t)1572864, 384);

  // --- heads + partition sampling ---
  heads_kernel<<<dim3(64), dim3(256), 0, stream>>>(dpen, dfc_w, dfc_b, sw_w, sw_b, out_dom, swbuf);
  partition_kernel<<<dim3(16), dim3(256), 0, stream>>>(swbuf, out_pid, pidxI, ysum, k1a, k1b, k2a, k2b);

  // --- experts: dense p1 for both partitions, then gather + p2 ---
  gemm_nt_kernel<1><<<dim3(6, 64), dim3(256), 0, stream>>>(featp, p1_w, p1_b, hbuf, 4096, 384, 1024);
  final_kernel<<<dim3(160), dim3(256), 0, stream>>>(hbuf, p2_w, p2_b, pidxI, ysum, out_cls);
}

// Round 6
// 3083.848 us; speedup vs baseline: 2.0211x; 1.6360x over previous
//
#include <hip/hip_runtime.h>
#include <cstdint>
#include <cstddef>

// ============================================================================
// Threefry2x32 (matches jax._src.prng.threefry2x32).
// ============================================================================
__host__ __device__ inline void threefry2x32(uint32_t k0, uint32_t k1,
                                             uint32_t x0, uint32_t x1,
                                             uint32_t& o0, uint32_t& o1) {
  uint32_t ks2 = k0 ^ k1 ^ 0x1BD11BDAu;
  uint32_t v0 = x0 + k0, v1 = x1 + k1;
#define TF_R(r) { v0 += v1; v1 = (v1 << (r)) | (v1 >> (32 - (r))); v1 ^= v0; }
  TF_R(13) TF_R(15) TF_R(26) TF_R(6)
  v0 += k1; v1 += ks2 + 1u;
  TF_R(17) TF_R(29) TF_R(16) TF_R(24)
  v0 += ks2; v1 += k0 + 2u;
  TF_R(13) TF_R(15) TF_R(26) TF_R(6)
  v0 += k0; v1 += k1 + 3u;
  TF_R(17) TF_R(29) TF_R(16) TF_R(24)
  v0 += k1; v1 += ks2 + 4u;
  TF_R(13) TF_R(15) TF_R(26) TF_R(6)
  v0 += ks2; v1 += k0 + 5u;
#undef TF_R
  o0 = v0; o1 = v1;
}

// jax partitionable random_bits, bit_width=32: bits = o0 ^ o1 (hi=0, lo=j).
__device__ __forceinline__ uint32_t tf_bits32(uint32_t k0, uint32_t k1, uint32_t j) {
  uint32_t o0, o1;
  threefry2x32(k0, k1, 0u, j, o0, o1);
  return o0 ^ o1;
}

__device__ __forceinline__ float u01_from_bits(uint32_t bits) {
  return __uint_as_float((bits >> 9) | 0x3f800000u) - 1.0f;  // [0,1)
}

__device__ __forceinline__ float waveSum(float v) {
#pragma unroll
  for (int off = 32; off > 0; off >>= 1) v += __shfl_down(v, off, 64);
  return v;
}

// ============================================================================
// conv1 fused: conv(3->32) + BN partials (unpooled) + RAW 2x2 maxpool store.
// BN+ReLU commutes past max (scale>0) -> applied later elementwise.
// grid 4096 (b), block 256 = 16x16 pooled px. LDS ~15 KB.
// ============================================================================
__global__ __launch_bounds__(256) void conv1_fused_kernel(
    const float* __restrict__ in, const float* __restrict__ w,
    float* __restrict__ outraw, float* __restrict__ partials) {
  __shared__ float ins[3 * 34 * 34];
  __shared__ float red[4][64];
  const int b = blockIdx.x, t = threadIdx.x;
  for (int i = t; i < 3 * 34 * 34; i += 256) {
    int ci = i / 1156, r = i % 1156, iy = r / 34, ix = r % 34;
    int y = iy - 1, x = ix - 1;
    float v = 0.f;
    if ((unsigned)y < 32u && (unsigned)x < 32u)
      v = in[(((size_t)b * 3 + ci) * 32 + y) * 32 + x];
    ins[i] = v;
  }
  __syncthreads();
  const int py = t >> 4, px = t & 15, wv = t >> 6, ln = t & 63;
  float win[3][4][4];
#pragma unroll
  for (int ci = 0; ci < 3; ci++)
#pragma unroll
    for (int r = 0; r < 4; r++)
#pragma unroll
      for (int c = 0; c < 4; c++)
        win[ci][r][c] = ins[ci * 1156 + (2 * py + r) * 34 + (2 * px + c)];
#pragma unroll 1
  for (int co = 0; co < 32; co++) {
    float acc00 = 0.f, acc01 = 0.f, acc10 = 0.f, acc11 = 0.f;
#pragma unroll
    for (int ci = 0; ci < 3; ci++) {
      const float* wp = w + (co * 3 + ci) * 9;  // wave-uniform -> s_load
#pragma unroll
      for (int dy = 0; dy < 3; dy++)
#pragma unroll
        for (int dx = 0; dx < 3; dx++) {
          float wvv = wp[dy * 3 + dx];
          acc00 += win[ci][dy][dx] * wvv;
          acc01 += win[ci][dy][dx + 1] * wvv;
          acc10 += win[ci][dy + 1][dx] * wvv;
          acc11 += win[ci][dy + 1][dx + 1] * wvv;
        }
    }
    float sm = acc00 + acc01 + acc10 + acc11;
    float sq = acc00 * acc00 + acc01 * acc01 + acc10 * acc10 + acc11 * acc11;
    float s = waveSum(sm), q = waveSum(sq);
    if (ln == 0) { red[wv][2 * co] = s; red[wv][2 * co + 1] = q; }
    float m = fmaxf(fmaxf(acc00, acc01), fmaxf(acc10, acc11));  // RAW max
    outraw[(((size_t)b * 32 + co) * 16 + py) * 16 + px] = m;
  }
  __syncthreads();
  for (int i = t; i < 64; i += 256)
    partials[(size_t)b * 64 + i] = red[0][i] + red[1][i] + red[2][i] + red[3][i];
}

// ============================================================================
// conv2 fused: conv(32->64) + BN partials (unpooled) + RAW 2x2 maxpool store.
// grid 4096, block 256 = 16x16 px, 8 co-chunks of 8. LDS ~51.7 KB (3 blk/CU).
// ============================================================================
__global__ __launch_bounds__(256) void conv2_fused_kernel(
    const float* __restrict__ in, const float* __restrict__ w,
    float* __restrict__ outraw, float* __restrict__ partials) {
  __shared__ float ins[32 * 18 * 18];
  __shared__ float os[8 * 256];
  __shared__ float red[4][128];
  const int b = blockIdx.x, t = threadIdx.x;
  for (int i = t; i < 32 * 18 * 18; i += 256) {
    int ci = i / 324, r = i % 324, iy = r / 18, ix = r % 18;
    int y = iy - 1, x = ix - 1;
    float v = 0.f;
    if ((unsigned)y < 16u && (unsigned)x < 16u)
      v = in[(((size_t)b * 32 + ci) * 16 + y) * 16 + x];
    ins[i] = v;
  }
  __syncthreads();
  const int y = t >> 4, x = t & 15, wv = t >> 6, ln = t & 63;
#pragma unroll 1
  for (int cc = 0; cc < 8; cc++) {
    if (cc) __syncthreads();  // protect os reuse
    float acc[8];
#pragma unroll
    for (int i = 0; i < 8; i++) acc[i] = 0.f;
#pragma unroll 1
    for (int ci = 0; ci < 32; ci++) {
      float vals[9];
#pragma unroll
      for (int dy = 0; dy < 3; dy++)
#pragma unroll
        for (int dx = 0; dx < 3; dx++)
          vals[dy * 3 + dx] = ins[ci * 324 + (y + dy) * 18 + (x + dx)];
#pragma unroll
      for (int co = 0; co < 8; co++) {
        const float* wp = w + ((size_t)(cc * 8 + co) * 32 + ci) * 9;  // uniform
#pragma unroll
        for (int k = 0; k < 9; k++) acc[co] += vals[k] * wp[k];
      }
    }
#pragma unroll
    for (int co = 0; co < 8; co++) {
      float a = acc[co];
      float s = waveSum(a), q = waveSum(a * a);
      if (ln == 0) { red[wv][2 * (cc * 8 + co)] = s; red[wv][2 * (cc * 8 + co) + 1] = q; }
      os[co * 256 + t] = a;
    }
    __syncthreads();
    for (int i = t; i < 512; i += 256) {
      int co = i >> 6, pl = i & 63, py = pl >> 3, px = pl & 7;
      const float* o = &os[co * 256 + (2 * py) * 16 + 2 * px];
      float m = fmaxf(fmaxf(o[0], o[1]), fmaxf(o[16], o[17]));  // RAW max
      outraw[(((size_t)b * 64 + cc * 8 + co) * 8 + py) * 8 + px] = m;
    }
  }
  __syncthreads();
  for (int i = t; i < 128; i += 256)
    partials[(size_t)b * 128 + i] = red[0][i] + red[1][i] + red[2][i] + red[3][i];
}

// ============================================================================
// conv3 fused: conv(64->128) + BN partials + RAW store (no pool).
// grid 4096, block 256 = 64 px x 4 co-groups of 32. LDS ~26.6 KB.
// ============================================================================
__global__ __launch_bounds__(256) void conv3_fused_kernel(
    const float* __restrict__ in, const float* __restrict__ w,
    float* __restrict__ outraw, float* __restrict__ partials) {
  __shared__ float ins[64 * 10 * 10];
  __shared__ float red[256];
  const int b = blockIdx.x, t = threadIdx.x;
  for (int i = t; i < 64 * 10 * 10; i += 256) {
    int ci = i / 100, r = i % 100, iy = r / 10, ix = r % 10;
    int y = iy - 1, x = ix - 1;
    float v = 0.f;
    if ((unsigned)y < 8u && (unsigned)x < 8u)
      v = in[(((size_t)b * 64 + ci) * 8 + y) * 8 + x];
    ins[i] = v;
  }
  __syncthreads();
  const int px = t & 63, cog = t >> 6;
  const int cogu = __builtin_amdgcn_readfirstlane(cog);
  const int y = px >> 3, x = px & 7;
  float acc[32];
#pragma unroll
  for (int i = 0; i < 32; i++) acc[i] = 0.f;
#pragma unroll 1
  for (int ci = 0; ci < 64; ci++) {
    float vals[9];
#pragma unroll
    for (int dy = 0; dy < 3; dy++)
#pragma unroll
      for (int dx = 0; dx < 3; dx++)
        vals[dy * 3 + dx] = ins[ci * 100 + (y + dy) * 10 + (x + dx)];
#pragma unroll
    for (int co = 0; co < 32; co++) {
      const float* wp = w + ((size_t)(cogu * 32 + co) * 64 + ci) * 9;  // uniform
#pragma unroll
      for (int k = 0; k < 9; k++) acc[co] += vals[k] * wp[k];
    }
  }
#pragma unroll
  for (int co = 0; co < 32; co++) {
    float a = acc[co];
    float s = waveSum(a), q = waveSum(a * a);
    if ((t & 63) == 0) { red[2 * (cog * 32 + co)] = s; red[2 * (cog * 32 + co) + 1] = q; }
    outraw[(((size_t)b * 128 + cog * 32 + co) * 8 + y) * 8 + x] = a;
  }
  __syncthreads();
  for (int i = t; i < 256; i += 256) partials[(size_t)b * 256 + i] = red[i];
}

// ============================================================================
// BN helpers
// ============================================================================
__global__ __launch_bounds__(256) void reduce_partials_kernel(
    const float* __restrict__ partials, int nblk, int Q, double* __restrict__ sums) {
  int q = blockIdx.x;
  double acc = 0.0;
  for (int i = threadIdx.x; i < nblk; i += 256) acc += (double)partials[(size_t)i * Q + q];
  __shared__ double red[256];
  red[threadIdx.x] = acc;
  __syncthreads();
  for (int s = 128; s > 0; s >>= 1) {
    if (threadIdx.x < s) red[threadIdx.x] += red[threadIdx.x + s];
    __syncthreads();
  }
  if (threadIdx.x == 0) sums[q] = red[0];
}

// col stats over row-chunk: grid (C/64, NCH). sums[chunk][2C] doubles.
__global__ __launch_bounds__(1024) void col_stats_kernel(
    const float* __restrict__ X, int R, int C, int nch, double* __restrict__ sums) {
  int c0 = blockIdx.x * 64, chunk = blockIdx.y;
  int cl = threadIdx.x & 63, rg = threadIdx.x >> 6;
  int rows = R / nch, rbeg = chunk * rows, rend = rbeg + rows;
  double s = 0.0, sq = 0.0;
  for (int r = rbeg + rg; r < rend; r += 16) {
    float v = X[(size_t)r * C + c0 + cl];
    s += v; sq += (double)v * (double)v;
  }
  __shared__ double red[16][64][2];
  red[rg][cl][0] = s; red[rg][cl][1] = sq;
  __syncthreads();
  if (rg == 0) {
    for (int i = 1; i < 16; i++) { s += red[i][cl][0]; sq += red[i][cl][1]; }
    sums[(size_t)chunk * 2 * C + 2 * (c0 + cl)] = s;
    sums[(size_t)chunk * 2 * C + 2 * (c0 + cl) + 1] = sq;
  }
}

__global__ void bn_finalize_kernel(const double* __restrict__ sums, int nch, int cst2,
                                   const float* __restrict__ g, const float* __restrict__ b,
                                   float* __restrict__ scale, float* __restrict__ shift,
                                   int C, double invN) {
  int c = blockIdx.x * blockDim.x + threadIdx.x;
  if (c >= C) return;
  double s = 0.0, sq = 0.0;
  for (int ch = 0; ch < nch; ch++) {
    s += sums[(size_t)ch * cst2 + 2 * c];
    sq += sums[(size_t)ch * cst2 + 2 * c + 1];
  }
  double m = s * invN;
  double v = sq * invN - m * m;
  double sc = (double)g[c] / sqrt(v + 1e-5);
  scale[c] = (float)sc;
  shift[c] = (float)((double)b[c] - m * sc);
}

// in-place BN+ReLU for NCHW, vectorized float4. HW = 1<<LOGHW (>=4).
template <int LOGHW, int CMASK>
__global__ void bn_relu_vec4_kernel(float* __restrict__ X, const float* __restrict__ scale,
                                    const float* __restrict__ shift, int n4) {
  int i = blockIdx.x * blockDim.x + threadIdx.x;
  if (i >= n4) return;
  int c = ((i << 2) >> LOGHW) & CMASK;
  float4 v = ((float4*)X)[i];
  float sc = scale[c], sh = shift[c];
  v.x = fmaxf(v.x * sc + sh, 0.f);
  v.y = fmaxf(v.y * sc + sh, 0.f);
  v.z = fmaxf(v.z * sc + sh, 0.f);
  v.w = fmaxf(v.w * sc + sh, 0.f);
  ((float4*)X)[i] = v;
}

// in-place BN+ReLU for [R][C] row-major, vectorized. C4 = C/4.
__global__ void bn_relu_cols4_kernel(float* __restrict__ X, const float* __restrict__ scale,
                                     const float* __restrict__ shift, int n4, int C4) {
  int i = blockIdx.x * blockDim.x + threadIdx.x;
  if (i >= n4) return;
  int c4 = i % C4;
  float4 v = ((float4*)X)[i];
  float4 sc = ((const float4*)scale)[c4];
  float4 sh = ((const float4*)shift)[c4];
  v.x = fmaxf(v.x * sc.x + sh.x, 0.f);
  v.y = fmaxf(v.y * sc.y + sh.y, 0.f);
  v.z = fmaxf(v.z * sc.z + sh.z, 0.f);
  v.w = fmaxf(v.w * sc.w + sh.w, 0.f);
  ((float4*)X)[i] = v;
}

// ============================================================================
// gemm128: C[M,N] = A[M,K]*B[N,K]^T. 128x128 tile, BK=16, 256 thr, 8x8 micro.
// XOR-swizzled LDS columns (2-way max bank aliasing = free), reg prefetch.
// ============================================================================
__device__ __forceinline__ int swz(int col) {
  return col ^ (((col >> 5) & 1) << 2);
}

__global__ __launch_bounds__(256) void gemm128_kernel(
    const float* __restrict__ A, const float* __restrict__ B,
    float* __restrict__ C, int M, int N, int K) {
  __shared__ float As[16][132];
  __shared__ float Bs[16][132];
  const int t = threadIdx.x;
  const int tm = t >> 4, tn = t & 15;
  const int m0 = blockIdx.y << 7, n0 = blockIdx.x << 7;
  const int lrow = t >> 1, lk = (t & 1) << 3;
  const float* Ap = A + (size_t)(m0 + lrow) * K + lk;
  const float* Bp = B + (size_t)(n0 + lrow) * K + lk;
  const int scol = swz(lrow);
  const int arow = tm << 3, brow = tn << 3;
  const int ac0 = swz(arow), ac1 = swz(arow + 4);
  const int bc0 = swz(brow), bc1 = swz(brow + 4);
  float acc[8][8];
#pragma unroll
  for (int i = 0; i < 8; i++)
#pragma unroll
    for (int j = 0; j < 8; j++) acc[i][j] = 0.f;
  float4 a0 = *(const float4*)(Ap);
  float4 a1 = *(const float4*)(Ap + 4);
  float4 b0 = *(const float4*)(Bp);
  float4 b1 = *(const float4*)(Bp + 4);
  for (int k0 = 0; k0 < K; k0 += 16) {
    __syncthreads();
    As[lk + 0][scol] = a0.x; As[lk + 1][scol] = a0.y; As[lk + 2][scol] = a0.z; As[lk + 3][scol] = a0.w;
    As[lk + 4][scol] = a1.x; As[lk + 5][scol] = a1.y; As[lk + 6][scol] = a1.z; As[lk + 7][scol] = a1.w;
    Bs[lk + 0][scol] = b0.x; Bs[lk + 1][scol] = b0.y; Bs[lk + 2][scol] = b0.z; Bs[lk + 3][scol] = b0.w;
    Bs[lk + 4][scol] = b1.x; Bs[lk + 5][scol] = b1.y; Bs[lk + 6][scol] = b1.z; Bs[lk + 7][scol] = b1.w;
    __syncthreads();
    if (k0 + 16 < K) {  // prefetch next K-slab into registers (hidden by MACs)
      a0 = *(const float4*)(Ap + k0 + 16);
      a1 = *(const float4*)(Ap + k0 + 20);
      b0 = *(const float4*)(Bp + k0 + 16);
      b1 = *(const float4*)(Bp + k0 + 20);
    }
#pragma unroll
    for (int kk = 0; kk < 16; kk++) {
      float4 aA = *(const float4*)&As[kk][ac0];
      float4 aB = *(const float4*)&As[kk][ac1];
      float4 bA = *(const float4*)&Bs[kk][bc0];
      float4 bB = *(const float4*)&Bs[kk][bc1];
      float a8[8] = {aA.x, aA.y, aA.z, aA.w, aB.x, aB.y, aB.z, aB.w};
      float b8[8] = {bA.x, bA.y, bA.z, bA.w, bB.x, bB.y, bB.z, bB.w};
#pragma unroll
      for (int i = 0; i < 8; i++)
#pragma unroll
        for (int j = 0; j < 8; j++) acc[i][j] += a8[i] * b8[j];
    }
  }
#pragma unroll
  for (int i = 0; i < 8; i++) {
    int m = m0 + arow + i;
    float4 o1, o2;
    o1.x = acc[i][0]; o1.y = acc[i][1]; o1.z = acc[i][2]; o1.w = acc[i][3];
    o2.x = acc[i][4]; o2.y = acc[i][5]; o2.z = acc[i][6]; o2.w = acc[i][7];
    *(float4*)&C[(size_t)m * N + n0 + brow] = o1;
    *(float4*)&C[(size_t)m * N + n0 + brow + 4] = o2;
  }
}

// ============================================================================
// Tiled fp32 GEMM, NT, 64x64 (small-N duty): C = A*B^T (+bias, relu).
// Padded LDS (stride 68) -> write conflicts 2-way max.
// ============================================================================
template <int BIASRELU>
__global__ __launch_bounds__(256) void gemm_nt_kernel(
    const float* __restrict__ A, const float* __restrict__ B,
    const float* __restrict__ bias, float* __restrict__ C, int M, int N, int K) {
  __shared__ float As[16][68];
  __shared__ float Bs[16][68];
  const int t = threadIdx.x;
  const int tn = t & 15, tm = t >> 4;
  const int m0 = blockIdx.y << 6, n0 = blockIdx.x << 6;
  const int lr = t >> 2, lk = (t & 3) << 2;
  const float* Ap = A + (size_t)(m0 + lr) * K + lk;
  const float* Bp = B + (size_t)(n0 + lr) * K + lk;
  float acc[4][4];
#pragma unroll
  for (int i = 0; i < 4; i++)
#pragma unroll
    for (int j = 0; j < 4; j++) acc[i][j] = 0.f;
  for (int k0 = 0; k0 < K; k0 += 16) {
    float4 av = *(const float4*)(Ap + k0);
    float4 bv = *(const float4*)(Bp + k0);
    __syncthreads();
    As[lk + 0][lr] = av.x; As[lk + 1][lr] = av.y; As[lk + 2][lr] = av.z; As[lk + 3][lr] = av.w;
    Bs[lk + 0][lr] = bv.x; Bs[lk + 1][lr] = bv.y; Bs[lk + 2][lr] = bv.z; Bs[lk + 3][lr] = bv.w;
    __syncthreads();
#pragma unroll
    for (int kk = 0; kk < 16; kk++) {
      float4 a4 = *(const float4*)&As[kk][tm << 2];
      float4 b4 = *(const float4*)&Bs[kk][tn << 2];
      acc[0][0] += a4.x * b4.x; acc[0][1] += a4.x * b4.y; acc[0][2] += a4.x * b4.z; acc[0][3] += a4.x * b4.w;
      acc[1][0] += a4.y * b4.x; acc[1][1] += a4.y * b4.y; acc[1][2] += a4.y * b4.z; acc[1][3] += a4.y * b4.w;
      acc[2][0] += a4.z * b4.x; acc[2][1] += a4.z * b4.y; acc[2][2] += a4.z * b4.z; acc[2][3] += a4.z * b4.w;
      acc[3][0] += a4.w * b4.x; acc[3][1] += a4.w * b4.y; acc[3][2] += a4.w * b4.z; acc[3][3] += a4.w * b4.w;
    }
  }
#pragma unroll
  for (int i = 0; i < 4; i++) {
    int m = m0 + (tm << 2) + i;
    float4 o;
    float v0 = acc[i][0], v1 = acc[i][1], v2 = acc[i][2], v3 = acc[i][3];
    if (BIASRELU) {
      int nb = n0 + (tn << 2);
      v0 = fmaxf(v0 + bias[nb + 0], 0.f);
      v1 = fmaxf(v1 + bias[nb + 1], 0.f);
      v2 = fmaxf(v2 + bias[nb + 2], 0.f);
      v3 = fmaxf(v3 + bias[nb + 3], 0.f);
    }
    o.x = v0; o.y = v1; o.z = v2; o.w = v3;
    *(float4*)&C[(size_t)m * N + n0 + (tn << 2)] = o;
  }
}

// ============================================================================
// heads (double accumulation; sw_logits amplified 10x by TAU)
// ============================================================================
__global__ __launch_bounds__(256) void heads_kernel(
    const float* __restrict__ dpen, const float* __restrict__ dfc_w,
    const float* __restrict__ dfc_b, const float* __restrict__ sw_w,
    const float* __restrict__ sw_b, float* __restrict__ out_dom,
    float* __restrict__ swbuf) {
  int t = blockIdx.x * 256 + threadIdx.x;
  int b = t >> 2, j = t & 3;
  const float* row = dpen + (size_t)b * 384;
  const float* wr = (j < 2) ? (dfc_w + j * 384) : (sw_w + (j - 2) * 384);
  double s = 0.0;
  for (int k = 0; k < 384; k++) s += (double)row[k] * (double)wr[k];
  s += (double)((j < 2) ? dfc_b[j] : sw_b[j - 2]);
  if (j < 2) out_dom[b * 2 + j] = (float)s;
  else swbuf[b * 2 + (j - 2)] = (float)s;
}

// ============================================================================
// gumbel-softmax + categorical partition choice (threefry partitionable).
// ============================================================================
__global__ __launch_bounds__(256) void partition_kernel(
    const float* __restrict__ swbuf, float* __restrict__ out_pid,
    int* __restrict__ pidxI, float* __restrict__ ysum,
    uint32_t k1a, uint32_t k1b, uint32_t k2a, uint32_t k2b) {
  int b = blockIdx.x * 256 + threadIdx.x;
  if (b >= 4096) return;
  uint32_t j0 = (uint32_t)(2 * b), j1 = (uint32_t)(2 * b + 1);
  float f0 = u01_from_bits(tf_bits32(k1a, k1b, j0));
  float f1 = u01_from_bits(tf_bits32(k1a, k1b, j1));
  const float MINV = 1e-10f;
  float u0 = fmaxf(MINV, f0 * (1.0f - MINV) + MINV);
  float u1 = fmaxf(MINV, f1 * (1.0f - MINV) + MINV);
  double g0 = -log(-log((double)u0));
  double g1 = -log(-log((double)u1));
  double s0 = (double)swbuf[2 * b], s1 = (double)swbuf[2 * b + 1];
  double x0 = (s0 + g0) / 0.1;
  double x1 = (s1 + g1) / 0.1;
  double mx = fmax(x0, x1);
  double e0 = exp(x0 - mx), e1 = exp(x1 - mx);
  double es = e0 + e1;
  double y0 = e0 / es, y1 = e1 / es;
  float h0 = u01_from_bits(tf_bits32(k2a, k2b, j0));
  float h1 = u01_from_bits(tf_bits32(k2a, k2b, j1));
  const float TINY = 1.17549435e-38f;
  float v0 = fmaxf(TINY, h0 * (1.0f - TINY) + TINY);
  float v1 = fmaxf(TINY, h1 * (1.0f - TINY) + TINY);
  double gg0 = -log(-log((double)v0));
  double gg1 = -log(-log((double)v1));
  double l0 = log(y0 + 1e-20) + gg0;
  double l1 = log(y1 + 1e-20) + gg1;
  int p = (l1 > l0) ? 1 : 0;
  out_pid[b] = (float)p;
  pidxI[b] = p;
  ysum[b] = (float)(y0 + y1);
}

// ============================================================================
// final head
// ============================================================================
__global__ __launch_bounds__(256) void final_kernel(
    const float* __restrict__ h, const float* __restrict__ p2w,
    const float* __restrict__ p2b, const int* __restrict__ pidxI,
    const float* __restrict__ ysum, float* __restrict__ out0) {
  int t = blockIdx.x * 256 + threadIdx.x;
  if (t >= 40960) return;
  int b = t / 10, c = t % 10;
  int p = pidxI[b];
  const float* hr = h + (size_t)b * 384 + p * 192;
  const float* wr = p2w + ((size_t)p * 10 + c) * 192;
  float s = 0.f;
  for (int o = 0; o < 192; o++) s += hr[o] * wr[o];
  s += p2b[p * 10 + c];
  out0[t] = s * ysum[b];
}

// ============================================================================
// Launch orchestration. Single-pass fused convs (pool-commute), ~235 MB ws.
// ============================================================================
extern "C" void kernel_launch(void* const* d_in, const int* in_sizes, int n_in,
                              void* d_out, int out_size, void* d_ws, size_t ws_size,
                              hipStream_t stream) {
  const float* input   = (const float*)d_in[0];
  const float* conv1_w = (const float*)d_in[1];
  const float* bn1_g   = (const float*)d_in[3];
  const float* bn1_b   = (const float*)d_in[4];
  const float* conv2_w = (const float*)d_in[5];
  const float* bn2_g   = (const float*)d_in[7];
  const float* bn2_b   = (const float*)d_in[8];
  const float* conv3_w = (const float*)d_in[9];
  const float* bn3_g   = (const float*)d_in[11];
  const float* bn3_b   = (const float*)d_in[12];
  const float* pre_w   = (const float*)d_in[13];
  const float* bnp_g   = (const float*)d_in[15];
  const float* bnp_b   = (const float*)d_in[16];
  const float* disc_w  = (const float*)d_in[17];
  const float* bnd_g   = (const float*)d_in[19];
  const float* bnd_b   = (const float*)d_in[20];
  const float* dfc_w   = (const float*)d_in[21];
  const float* dfc_b   = (const float*)d_in[22];
  const float* sw_w    = (const float*)d_in[23];
  const float* sw_b    = (const float*)d_in[24];
  const float* p1_w    = (const float*)d_in[25];
  const float* p1_b    = (const float*)d_in[26];
  const float* p2_w    = (const float*)d_in[27];
  const float* p2_b    = (const float*)d_in[28];

  float* W = (float*)d_ws;
  float* pool1  = W + 0;           // [4096][32][16][16] raw->bn'd in place
  float* pool2  = W + 33554432;    // [4096][64][8][8]
  float* act3   = W + 0;           // [4096][128][8][8] alias pool1 (dead)
  float* featp  = W + 50331648;    // [4096][1024]
  float* dpen   = W + 54525952;    // [4096][384]
  float* hbuf   = W + 56098816;    // [4096][384]
  float* swbuf  = W + 57671680;
  float* ysum   = W + 57679872;
  int*   pidxI  = (int*)(W + 57683968);
  float* part   = W + 57688064;    // up to 4096*256 floats
  double* sums  = (double*)(W + 58736640);  // up to 8*2048 doubles
  float* scale  = W + 58769408;
  float* shift  = W + 58770432;
  // end: 58,771,456 floats = 235.1 MB

  float* out_cls = (float*)d_out;
  float* out_dom = out_cls + 40960;
  float* out_pid = out_cls + 49152;

  uint32_t k1a, k1b, k2a, k2b;
  threefry2x32(0u, 42u, 0u, 0u, k1a, k1b);
  threefry2x32(0u, 42u, 0u, 1u, k2a, k2b);

  // --- conv1 fused + BN finalize + elementwise BN+ReLU on pooled raw ---
  conv1_fused_kernel<<<dim3(4096), dim3(256), 0, stream>>>(input, conv1_w, pool1, part);
  reduce_partials_kernel<<<dim3(64), dim3(256), 0, stream>>>(part, 4096, 64, sums);
  bn_finalize_kernel<<<dim3(1), dim3(64), 0, stream>>>(sums, 1, 0, bn1_g, bn1_b, scale, shift, 32, 1.0 / (4096.0 * 1024.0));
  bn_relu_vec4_kernel<8, 31><<<dim3(32768), dim3(256), 0, stream>>>(pool1, scale, shift, 8388608);

  // --- conv2 fused ---
  conv2_fused_kernel<<<dim3(4096), dim3(256), 0, stream>>>(pool1, conv2_w, pool2, part);
  reduce_partials_kernel<<<dim3(128), dim3(256), 0, stream>>>(part, 4096, 128, sums);
  bn_finalize_kernel<<<dim3(1), dim3(64), 0, stream>>>(sums, 1, 0, bn2_g, bn2_b, scale, shift, 64, 1.0 / (4096.0 * 256.0));
  bn_relu_vec4_kernel<6, 63><<<dim3(16384), dim3(256), 0, stream>>>(pool2, scale, shift, 4194304);

  // --- conv3 fused ---
  conv3_fused_kernel<<<dim3(4096), dim3(256), 0, stream>>>(pool2, conv3_w, act3, part);
  reduce_partials_kernel<<<dim3(256), dim3(256), 0, stream>>>(part, 4096, 256, sums);
  bn_finalize_kernel<<<dim3(1), dim3(128), 0, stream>>>(sums, 1, 0, bn3_g, bn3_b, scale, shift, 128, 1.0 / (4096.0 * 64.0));
  bn_relu_vec4_kernel<6, 127><<<dim3(32768), dim3(256), 0, stream>>>(act3, scale, shift, 8388608);

  // --- pre FC 8192->1024 + BN + ReLU ---
  gemm128_kernel<<<dim3(8, 32), dim3(256), 0, stream>>>(act3, pre_w, featp, 4096, 1024, 8192);
  col_stats_kernel<<<dim3(16, 8), dim3(1024), 0, stream>>>(featp, 4096, 1024, 8, sums);
  bn_finalize_kernel<<<dim3(4), dim3(256), 0, stream>>>(sums, 8, 2048, bnp_g, bnp_b, scale, shift, 1024, 1.0 / 4096.0);
  bn_relu_cols4_kernel<<<dim3(4096), dim3(256), 0, stream>>>(featp, scale, shift, 1048576, 256);

  // --- disc FC 1024->384 + BN + ReLU ---
  gemm_nt_kernel<0><<<dim3(6, 64), dim3(256), 0, stream>>>(featp, disc_w, (const float*)nullptr, dpen, 4096, 384, 1024);
  col_stats_kernel<<<dim3(6, 8), dim3(1024), 0, stream>>>(dpen, 4096, 384, 8, sums);
  bn_finalize_kernel<<<dim3(2), dim3(256), 0, stream>>>(sums, 8, 768, bnd_g, bnd_b, scale, shift, 384, 1.0 / 4096.0);
  bn_relu_cols4_kernel<<<dim3(1536), dim3(256), 0, stream>>>(dpen, scale, shift, 393216, 96);

  // --- heads + partition sampling ---
  heads_kernel<<<dim3(64), dim3(256), 0, stream>>>(dpen, dfc_w, dfc_b, sw_w, sw_b, out_dom, swbuf);
  partition_kernel<<<dim3(16), dim3(256), 0, stream>>>(swbuf, out_pid, pidxI, ysum, k1a, k1b, k2a, k2b);

  // --- experts: dense p1, then gather + p2 ---
  gemm_nt_kernel<1><<<dim3(6, 64), dim3(256), 0, stream>>>(featp, p1_w, p1_b, hbuf, 4096, 384, 1024);
  final_kernel<<<dim3(160), dim3(256), 0, stream>>>(hbuf, p2_w, p2_b, pidxI, ysum, out_cls);
}

// Round 7
// 2566.093 us; speedup vs baseline: 2.4289x; 1.2018x over previous
//
#include <hip/hip_runtime.h>
#include <cstdint>
#include <cstddef>

typedef __attribute__((ext_vector_type(8))) short short8;    // 8 bf16 (4 VGPR)
typedef __attribute__((ext_vector_type(4))) float f32x4;     // MFMA acc

// ============================================================================
// Threefry2x32 (matches jax._src.prng.threefry2x32).
// ============================================================================
__host__ __device__ inline void threefry2x32(uint32_t k0, uint32_t k1,
                                             uint32_t x0, uint32_t x1,
                                             uint32_t& o0, uint32_t& o1) {
  uint32_t ks2 = k0 ^ k1 ^ 0x1BD11BDAu;
  uint32_t v0 = x0 + k0, v1 = x1 + k1;
#define TF_R(r) { v0 += v1; v1 = (v1 << (r)) | (v1 >> (32 - (r))); v1 ^= v0; }
  TF_R(13) TF_R(15) TF_R(26) TF_R(6)
  v0 += k1; v1 += ks2 + 1u;
  TF_R(17) TF_R(29) TF_R(16) TF_R(24)
  v0 += ks2; v1 += k0 + 2u;
  TF_R(13) TF_R(15) TF_R(26) TF_R(6)
  v0 += k0; v1 += k1 + 3u;
  TF_R(17) TF_R(29) TF_R(16) TF_R(24)
  v0 += k1; v1 += ks2 + 4u;
  TF_R(13) TF_R(15) TF_R(26) TF_R(6)
  v0 += ks2; v1 += k0 + 5u;
#undef TF_R
  o0 = v0; o1 = v1;
}

__device__ __forceinline__ uint32_t tf_bits32(uint32_t k0, uint32_t k1, uint32_t j) {
  uint32_t o0, o1;
  threefry2x32(k0, k1, 0u, j, o0, o1);
  return o0 ^ o1;
}

__device__ __forceinline__ float u01_from_bits(uint32_t bits) {
  return __uint_as_float((bits >> 9) | 0x3f800000u) - 1.0f;  // [0,1)
}

__device__ __forceinline__ float waveSum(float v) {
#pragma unroll
  for (int off = 32; off > 0; off >>= 1) v += __shfl_down(v, off, 64);
  return v;
}

// ============================================================================
// conv1 fused: conv(3->32) + BN partials (unpooled) + RAW 2x2 maxpool store.
// ============================================================================
__global__ __launch_bounds__(256) void conv1_fused_kernel(
    const float* __restrict__ in, const float* __restrict__ w,
    float* __restrict__ outraw, float* __restrict__ partials) {
  __shared__ float ins[3 * 34 * 34];
  __shared__ float red[4][64];
  const int b = blockIdx.x, t = threadIdx.x;
  for (int i = t; i < 3 * 34 * 34; i += 256) {
    int ci = i / 1156, r = i % 1156, iy = r / 34, ix = r % 34;
    int y = iy - 1, x = ix - 1;
    float v = 0.f;
    if ((unsigned)y < 32u && (unsigned)x < 32u)
      v = in[(((size_t)b * 3 + ci) * 32 + y) * 32 + x];
    ins[i] = v;
  }
  __syncthreads();
  const int py = t >> 4, px = t & 15, wv = t >> 6, ln = t & 63;
  float win[3][4][4];
#pragma unroll
  for (int ci = 0; ci < 3; ci++)
#pragma unroll
    for (int r = 0; r < 4; r++)
#pragma unroll
      for (int c = 0; c < 4; c++)
        win[ci][r][c] = ins[ci * 1156 + (2 * py + r) * 34 + (2 * px + c)];
#pragma unroll 1
  for (int co = 0; co < 32; co++) {
    float acc00 = 0.f, acc01 = 0.f, acc10 = 0.f, acc11 = 0.f;
#pragma unroll
    for (int ci = 0; ci < 3; ci++) {
      const float* wp = w + (co * 3 + ci) * 9;  // wave-uniform -> s_load
#pragma unroll
      for (int dy = 0; dy < 3; dy++)
#pragma unroll
        for (int dx = 0; dx < 3; dx++) {
          float wvv = wp[dy * 3 + dx];
          acc00 += win[ci][dy][dx] * wvv;
          acc01 += win[ci][dy][dx + 1] * wvv;
          acc10 += win[ci][dy + 1][dx] * wvv;
          acc11 += win[ci][dy + 1][dx + 1] * wvv;
        }
    }
    float sm = acc00 + acc01 + acc10 + acc11;
    float sq = acc00 * acc00 + acc01 * acc01 + acc10 * acc10 + acc11 * acc11;
    float s = waveSum(sm), q = waveSum(sq);
    if (ln == 0) { red[wv][2 * co] = s; red[wv][2 * co + 1] = q; }
    float m = fmaxf(fmaxf(acc00, acc01), fmaxf(acc10, acc11));  // RAW max
    outraw[(((size_t)b * 32 + co) * 16 + py) * 16 + px] = m;
  }
  __syncthreads();
  for (int i = t; i < 64; i += 256)
    partials[(size_t)b * 64 + i] = red[0][i] + red[1][i] + red[2][i] + red[3][i];
}

// ============================================================================
// conv2 fused: conv(32->64) + BN partials + RAW 2x2 maxpool store.
// ============================================================================
__global__ __launch_bounds__(256) void conv2_fused_kernel(
    const float* __restrict__ in, const float* __restrict__ w,
    float* __restrict__ outraw, float* __restrict__ partials) {
  __shared__ float ins[32 * 18 * 18];
  __shared__ float os[8 * 256];
  __shared__ float red[4][128];
  const int b = blockIdx.x, t = threadIdx.x;
  for (int i = t; i < 32 * 18 * 18; i += 256) {
    int ci = i / 324, r = i % 324, iy = r / 18, ix = r % 18;
    int y = iy - 1, x = ix - 1;
    float v = 0.f;
    if ((unsigned)y < 16u && (unsigned)x < 16u)
      v = in[(((size_t)b * 32 + ci) * 16 + y) * 16 + x];
    ins[i] = v;
  }
  __syncthreads();
  const int y = t >> 4, x = t & 15, wv = t >> 6, ln = t & 63;
#pragma unroll 1
  for (int cc = 0; cc < 8; cc++) {
    if (cc) __syncthreads();  // protect os reuse
    float acc[8];
#pragma unroll
    for (int i = 0; i < 8; i++) acc[i] = 0.f;
#pragma unroll 1
    for (int ci = 0; ci < 32; ci++) {
      float vals[9];
#pragma unroll
      for (int dy = 0; dy < 3; dy++)
#pragma unroll
        for (int dx = 0; dx < 3; dx++)
          vals[dy * 3 + dx] = ins[ci * 324 + (y + dy) * 18 + (x + dx)];
#pragma unroll
      for (int co = 0; co < 8; co++) {
        const float* wp = w + ((size_t)(cc * 8 + co) * 32 + ci) * 9;  // uniform
#pragma unroll
        for (int k = 0; k < 9; k++) acc[co] += vals[k] * wp[k];
      }
    }
#pragma unroll
    for (int co = 0; co < 8; co++) {
      float a = acc[co];
      float s = waveSum(a), q = waveSum(a * a);
      if (ln == 0) { red[wv][2 * (cc * 8 + co)] = s; red[wv][2 * (cc * 8 + co) + 1] = q; }
      os[co * 256 + t] = a;
    }
    __syncthreads();
    for (int i = t; i < 512; i += 256) {
      int co = i >> 6, pl = i & 63, py = pl >> 3, px = pl & 7;
      const float* o = &os[co * 256 + (2 * py) * 16 + 2 * px];
      float m = fmaxf(fmaxf(o[0], o[1]), fmaxf(o[16], o[17]));  // RAW max
      outraw[(((size_t)b * 64 + cc * 8 + co) * 8 + py) * 8 + px] = m;
    }
  }
  __syncthreads();
  for (int i = t; i < 128; i += 256)
    partials[(size_t)b * 128 + i] = red[0][i] + red[1][i] + red[2][i] + red[3][i];
}

// ============================================================================
// conv3 fused: conv(64->128) + BN partials + RAW store (no pool).
// ============================================================================
__global__ __launch_bounds__(256) void conv3_fused_kernel(
    const float* __restrict__ in, const float* __restrict__ w,
    float* __restrict__ outraw, float* __restrict__ partials) {
  __shared__ float ins[64 * 10 * 10];
  __shared__ float red[256];
  const int b = blockIdx.x, t = threadIdx.x;
  for (int i = t; i < 64 * 10 * 10; i += 256) {
    int ci = i / 100, r = i % 100, iy = r / 10, ix = r % 10;
    int y = iy - 1, x = ix - 1;
    float v = 0.f;
    if ((unsigned)y < 8u && (unsigned)x < 8u)
      v = in[(((size_t)b * 64 + ci) * 8 + y) * 8 + x];
    ins[i] = v;
  }
  __syncthreads();
  const int px = t & 63, cog = t >> 6;
  const int cogu = __builtin_amdgcn_readfirstlane(cog);
  const int y = px >> 3, x = px & 7;
  float acc[32];
#pragma unroll
  for (int i = 0; i < 32; i++) acc[i] = 0.f;
#pragma unroll 1
  for (int ci = 0; ci < 64; ci++) {
    float vals[9];
#pragma unroll
    for (int dy = 0; dy < 3; dy++)
#pragma unroll
      for (int dx = 0; dx < 3; dx++)
        vals[dy * 3 + dx] = ins[ci * 100 + (y + dy) * 10 + (x + dx)];
#pragma unroll
    for (int co = 0; co < 32; co++) {
      const float* wp = w + ((size_t)(cogu * 32 + co) * 64 + ci) * 9;  // uniform
#pragma unroll
      for (int k = 0; k < 9; k++) acc[co] += vals[k] * wp[k];
    }
  }
#pragma unroll
  for (int co = 0; co < 32; co++) {
    float a = acc[co];
    float s = waveSum(a), q = waveSum(a * a);
    if ((t & 63) == 0) { red[2 * (cog * 32 + co)] = s; red[2 * (cog * 32 + co) + 1] = q; }
    outraw[(((size_t)b * 128 + cog * 32 + co) * 8 + y) * 8 + x] = a;
  }
  __syncthreads();
  for (int i = t; i < 256; i += 256) partials[(size_t)b * 256 + i] = red[i];
}

// ============================================================================
// BN helpers
// ============================================================================
__global__ __launch_bounds__(256) void reduce_partials_kernel(
    const float* __restrict__ partials, int nblk, int Q, double* __restrict__ sums) {
  int q = blockIdx.x;
  double acc = 0.0;
  for (int i = threadIdx.x; i < nblk; i += 256) acc += (double)partials[(size_t)i * Q + q];
  __shared__ double red[256];
  red[threadIdx.x] = acc;
  __syncthreads();
  for (int s = 128; s > 0; s >>= 1) {
    if (threadIdx.x < s) red[threadIdx.x] += red[threadIdx.x + s];
    __syncthreads();
  }
  if (threadIdx.x == 0) sums[q] = red[0];
}

__global__ __launch_bounds__(1024) void col_stats_kernel(
    const float* __restrict__ X, int R, int C, int nch, double* __restrict__ sums) {
  int c0 = blockIdx.x * 64, chunk = blockIdx.y;
  int cl = threadIdx.x & 63, rg = threadIdx.x >> 6;
  int rows = R / nch, rbeg = chunk * rows, rend = rbeg + rows;
  double s = 0.0, sq = 0.0;
  for (int r = rbeg + rg; r < rend; r += 16) {
    float v = X[(size_t)r * C + c0 + cl];
    s += v; sq += (double)v * (double)v;
  }
  __shared__ double red[16][64][2];
  red[rg][cl][0] = s; red[rg][cl][1] = sq;
  __syncthreads();
  if (rg == 0) {
    for (int i = 1; i < 16; i++) { s += red[i][cl][0]; sq += red[i][cl][1]; }
    sums[(size_t)chunk * 2 * C + 2 * (c0 + cl)] = s;
    sums[(size_t)chunk * 2 * C + 2 * (c0 + cl) + 1] = sq;
  }
}

__global__ void bn_finalize_kernel(const double* __restrict__ sums, int nch, int cst2,
                                   const float* __restrict__ g, const float* __restrict__ b,
                                   float* __restrict__ scale, float* __restrict__ shift,
                                   int C, double invN) {
  int c = blockIdx.x * blockDim.x + threadIdx.x;
  if (c >= C) return;
  double s = 0.0, sq = 0.0;
  for (int ch = 0; ch < nch; ch++) {
    s += sums[(size_t)ch * cst2 + 2 * c];
    sq += sums[(size_t)ch * cst2 + 2 * c + 1];
  }
  double m = s * invN;
  double v = sq * invN - m * m;
  double sc = (double)g[c] / sqrt(v + 1e-5);
  scale[c] = (float)sc;
  shift[c] = (float)((double)b[c] - m * sc);
}

template <int LOGHW, int CMASK>
__global__ void bn_relu_vec4_kernel(float* __restrict__ X, const float* __restrict__ scale,
                                    const float* __restrict__ shift, int n4) {
  int i = blockIdx.x * blockDim.x + threadIdx.x;
  if (i >= n4) return;
  int c = ((i << 2) >> LOGHW) & CMASK;
  float4 v = ((float4*)X)[i];
  float sc = scale[c], sh = shift[c];
  v.x = fmaxf(v.x * sc + sh, 0.f);
  v.y = fmaxf(v.y * sc + sh, 0.f);
  v.z = fmaxf(v.z * sc + sh, 0.f);
  v.w = fmaxf(v.w * sc + sh, 0.f);
  ((float4*)X)[i] = v;
}

__global__ void bn_relu_cols4_kernel(float* __restrict__ X, const float* __restrict__ scale,
                                     const float* __restrict__ shift, int n4, int C4) {
  int i = blockIdx.x * blockDim.x + threadIdx.x;
  if (i >= n4) return;
  int c4 = i % C4;
  float4 v = ((float4*)X)[i];
  float4 sc = ((const float4*)scale)[c4];
  float4 sh = ((const float4*)shift)[c4];
  v.x = fmaxf(v.x * sc.x + sh.x, 0.f);
  v.y = fmaxf(v.y * sc.y + sh.y, 0.f);
  v.z = fmaxf(v.z * sc.z + sh.z, 0.f);
  v.w = fmaxf(v.w * sc.w + sh.w, 0.f);
  ((float4*)X)[i] = v;
}

// ============================================================================
// fp32 -> packed (bf16_hi<<16 | bf16_lo) conversion, vectorized x4.
// hi = RNE-bf16(x); lo = RNE-bf16(x - hi). Safe in-place (same-index R/W).
// ============================================================================
__device__ __forceinline__ uint32_t pack_bf16q(float x) {
  uint32_t u = __float_as_uint(x);
  uint32_t hi = (u + 0x7fffu + ((u >> 16) & 1u)) & 0xffff0000u;
  float r = x - __uint_as_float(hi);
  uint32_t v = __float_as_uint(r);
  uint32_t lo = (v + 0x7fffu + ((v >> 16) & 1u)) >> 16;
  return hi | lo;
}

__global__ void cvt_bf16q_kernel(const float* X, uint32_t* Y, int n4) {
  int i = blockIdx.x * blockDim.x + threadIdx.x;
  if (i >= n4) return;
  float4 x = ((const float4*)X)[i];
  uint4 o;
  o.x = pack_bf16q(x.x); o.y = pack_bf16q(x.y);
  o.z = pack_bf16q(x.z); o.w = pack_bf16q(x.w);
  ((uint4*)Y)[i] = o;
}

// ============================================================================
// bf16-split MFMA GEMM: C[M,N] = A[M,K]*B[N,K]^T in fp32-equivalent precision.
// A,B packed u32 (hi<<16|lo). Tile 128x64, BK=32, 4 waves of 64x32.
// 4 mfma terms per frag-pair: (hi+lo)*(hi'+lo') exact; err ~2^-17 rel.
// LDS 24 KB, grid (N/64, M/128) = 512 blocks -> 2 blocks/CU.
// ============================================================================
__global__ __launch_bounds__(256) void gemm_bf16q_kernel(
    const uint32_t* __restrict__ A, const uint32_t* __restrict__ B,
    float* __restrict__ C, int M, int N, int K) {
  __shared__ short Ah[128 * 32], Al[128 * 32], Bh[64 * 32], Bl[64 * 32];
  const int t = threadIdx.x;
  const int m0 = blockIdx.y << 7, n0 = blockIdx.x << 6;
  const int w = t >> 6, l = t & 63;
  const int wrow = (w >> 1) << 6, wcol = (w & 1) << 5;
  const int lr = l & 15, lg = l >> 4;
  const int ar = t >> 1, akh = (t & 1) << 4;   // A staging: row, k-base (16 wide)
  const int br = t >> 2, bkh = (t & 3) << 3;   // B staging: row, k-base (8 wide)
  const int asw = (ar & 3) << 3, bsw = (br & 3) << 3;
  const uint32_t* Ap = A + (size_t)(m0 + ar) * K + akh;
  const uint32_t* Bp = B + (size_t)(n0 + br) * K + bkh;
  f32x4 acc[4][2];
#pragma unroll
  for (int i = 0; i < 4; i++)
#pragma unroll
    for (int j = 0; j < 2; j++) acc[i][j] = (f32x4){0.f, 0.f, 0.f, 0.f};
  uint4 ra0 = *(const uint4*)(Ap + 0), ra1 = *(const uint4*)(Ap + 4);
  uint4 ra2 = *(const uint4*)(Ap + 8), ra3 = *(const uint4*)(Ap + 12);
  uint4 rb0 = *(const uint4*)(Bp + 0), rb1 = *(const uint4*)(Bp + 4);
  const int NS = K >> 5;
  for (int s = 0; s < NS; s++) {
    __syncthreads();
    // ---- split-store staging regs to LDS (hi/lo separated) ----
#define STORE_G(ARR_H, ARR_L, ROW, KB, SW, U)                                   \
    {                                                                           \
      uint32_t h0 = (U.x >> 16) | (U.y & 0xffff0000u);                          \
      uint32_t h1 = (U.z >> 16) | (U.w & 0xffff0000u);                          \
      uint32_t l0 = (U.x & 0xffffu) | (U.y << 16);                              \
      uint32_t l1 = (U.z & 0xffffu) | (U.w << 16);                              \
      int idx = (ROW) * 32 + ((KB) ^ (SW));                                     \
      *(uint2*)&ARR_H[idx] = make_uint2(h0, h1);                                \
      *(uint2*)&ARR_L[idx] = make_uint2(l0, l1);                                \
    }
    STORE_G(Ah, Al, ar, akh + 0, asw, ra0)
    STORE_G(Ah, Al, ar, akh + 4, asw, ra1)
    STORE_G(Ah, Al, ar, akh + 8, asw, ra2)
    STORE_G(Ah, Al, ar, akh + 12, asw, ra3)
    STORE_G(Bh, Bl, br, bkh + 0, bsw, rb0)
    STORE_G(Bh, Bl, br, bkh + 4, bsw, rb1)
#undef STORE_G
    __syncthreads();
    if (s + 1 < NS) {  // prefetch next K-slab (hidden under MFMA)
      int ko = (s + 1) << 5;
      ra0 = *(const uint4*)(Ap + ko); ra1 = *(const uint4*)(Ap + ko + 4);
      ra2 = *(const uint4*)(Ap + ko + 8); ra3 = *(const uint4*)(Ap + ko + 12);
      rb0 = *(const uint4*)(Bp + ko); rb1 = *(const uint4*)(Bp + ko + 4);
    }
    short8 ahf[4], alf[4], bhf[2], blf[2];
#pragma unroll
    for (int i = 0; i < 4; i++) {
      int R = wrow + i * 16 + lr;
      int kk = (lg << 3) ^ ((R & 3) << 3);
      ahf[i] = *(const short8*)&Ah[R * 32 + kk];
      alf[i] = *(const short8*)&Al[R * 32 + kk];
    }
#pragma unroll
    for (int j = 0; j < 2; j++) {
      int Cc = wcol + j * 16 + lr;
      int kk = (lg << 3) ^ ((Cc & 3) << 3);
      bhf[j] = *(const short8*)&Bh[Cc * 32 + kk];
      blf[j] = *(const short8*)&Bl[Cc * 32 + kk];
    }
#pragma unroll
    for (int i = 0; i < 4; i++)
#pragma unroll
      for (int j = 0; j < 2; j++) {
        acc[i][j] = __builtin_amdgcn_mfma_f32_16x16x32_bf16(ahf[i], bhf[j], acc[i][j], 0, 0, 0);
        acc[i][j] = __builtin_amdgcn_mfma_f32_16x16x32_bf16(ahf[i], blf[j], acc[i][j], 0, 0, 0);
        acc[i][j] = __builtin_amdgcn_mfma_f32_16x16x32_bf16(alf[i], bhf[j], acc[i][j], 0, 0, 0);
        acc[i][j] = __builtin_amdgcn_mfma_f32_16x16x32_bf16(alf[i], blf[j], acc[i][j], 0, 0, 0);
      }
  }
  // C/D layout (m89-verified): col = lane&15, row = (lane>>4)*4 + reg
#pragma unroll
  for (int i = 0; i < 4; i++)
#pragma unroll
    for (int j = 0; j < 2; j++) {
      int n = n0 + wcol + j * 16 + lr;
#pragma unroll
      for (int r = 0; r < 4; r++) {
        int m = m0 + wrow + i * 16 + lg * 4 + r;
        C[(size_t)m * N + n] = acc[i][j][r];
      }
    }
}

// ============================================================================
// fp32 64x64 GEMM NT (small-N duty): C = A*B^T (+bias, relu). Padded LDS.
// ============================================================================
template <int BIASRELU>
__global__ __launch_bounds__(256) void gemm_nt_kernel(
    const float* __restrict__ A, const float* __restrict__ B,
    const float* __restrict__ bias, float* __restrict__ C, int M, int N, int K) {
  __shared__ float As[16][68];
  __shared__ float Bs[16][68];
  const int t = threadIdx.x;
  const int tn = t & 15, tm = t >> 4;
  const int m0 = blockIdx.y << 6, n0 = blockIdx.x << 6;
  const int lr = t >> 2, lk = (t & 3) << 2;
  const float* Ap = A + (size_t)(m0 + lr) * K + lk;
  const float* Bp = B + (size_t)(n0 + lr) * K + lk;
  float acc[4][4];
#pragma unroll
  for (int i = 0; i < 4; i++)
#pragma unroll
    for (int j = 0; j < 4; j++) acc[i][j] = 0.f;
  for (int k0 = 0; k0 < K; k0 += 16) {
    float4 av = *(const float4*)(Ap + k0);
    float4 bv = *(const float4*)(Bp + k0);
    __syncthreads();
    As[lk + 0][lr] = av.x; As[lk + 1][lr] = av.y; As[lk + 2][lr] = av.z; As[lk + 3][lr] = av.w;
    Bs[lk + 0][lr] = bv.x; Bs[lk + 1][lr] = bv.y; Bs[lk + 2][lr] = bv.z; Bs[lk + 3][lr] = bv.w;
    __syncthreads();
#pragma unroll
    for (int kk = 0; kk < 16; kk++) {
      float4 a4 = *(const float4*)&As[kk][tm << 2];
      float4 b4 = *(const float4*)&Bs[kk][tn << 2];
      acc[0][0] += a4.x * b4.x; acc[0][1] += a4.x * b4.y; acc[0][2] += a4.x * b4.z; acc[0][3] += a4.x * b4.w;
      acc[1][0] += a4.y * b4.x; acc[1][1] += a4.y * b4.y; acc[1][2] += a4.y * b4.z; acc[1][3] += a4.y * b4.w;
      acc[2][0] += a4.z * b4.x; acc[2][1] += a4.z * b4.y; acc[2][2] += a4.z * b4.z; acc[2][3] += a4.z * b4.w;
      acc[3][0] += a4.w * b4.x; acc[3][1] += a4.w * b4.y; acc[3][2] += a4.w * b4.z; acc[3][3] += a4.w * b4.w;
    }
  }
#pragma unroll
  for (int i = 0; i < 4; i++) {
    int m = m0 + (tm << 2) + i;
    float4 o;
    float v0 = acc[i][0], v1 = acc[i][1], v2 = acc[i][2], v3 = acc[i][3];
    if (BIASRELU) {
      int nb = n0 + (tn << 2);
      v0 = fmaxf(v0 + bias[nb + 0], 0.f);
      v1 = fmaxf(v1 + bias[nb + 1], 0.f);
      v2 = fmaxf(v2 + bias[nb + 2], 0.f);
      v3 = fmaxf(v3 + bias[nb + 3], 0.f);
    }
    o.x = v0; o.y = v1; o.z = v2; o.w = v3;
    *(float4*)&C[(size_t)m * N + n0 + (tn << 2)] = o;
  }
}

// ============================================================================
// heads (double accumulation; sw_logits amplified 10x by TAU)
// ============================================================================
__global__ __launch_bounds__(256) void heads_kernel(
    const float* __restrict__ dpen, const float* __restrict__ dfc_w,
    const float* __restrict__ dfc_b, const float* __restrict__ sw_w,
    const float* __restrict__ sw_b, float* __restrict__ out_dom,
    float* __restrict__ swbuf) {
  int t = blockIdx.x * 256 + threadIdx.x;
  int b = t >> 2, j = t & 3;
  const float* row = dpen + (size_t)b * 384;
  const float* wr = (j < 2) ? (dfc_w + j * 384) : (sw_w + (j - 2) * 384);
  double s = 0.0;
  for (int k = 0; k < 384; k++) s += (double)row[k] * (double)wr[k];
  s += (double)((j < 2) ? dfc_b[j] : sw_b[j - 2]);
  if (j < 2) out_dom[b * 2 + j] = (float)s;
  else swbuf[b * 2 + (j - 2)] = (float)s;
}

// ============================================================================
// gumbel-softmax + categorical partition choice (threefry partitionable).
// ============================================================================
__global__ __launch_bounds__(256) void partition_kernel(
    const float* __restrict__ swbuf, float* __restrict__ out_pid,
    int* __restrict__ pidxI, float* __restrict__ ysum,
    uint32_t k1a, uint32_t k1b, uint32_t k2a, uint32_t k2b) {
  int b = blockIdx.x * 256 + threadIdx.x;
  if (b >= 4096) return;
  uint32_t j0 = (uint32_t)(2 * b), j1 = (uint32_t)(2 * b + 1);
  float f0 = u01_from_bits(tf_bits32(k1a, k1b, j0));
  float f1 = u01_from_bits(tf_bits32(k1a, k1b, j1));
  const float MINV = 1e-10f;
  float u0 = fmaxf(MINV, f0 * (1.0f - MINV) + MINV);
  float u1 = fmaxf(MINV, f1 * (1.0f - MINV) + MINV);
  double g0 = -log(-log((double)u0));
  double g1 = -log(-log((double)u1));
  double s0 = (double)swbuf[2 * b], s1 = (double)swbuf[2 * b + 1];
  double x0 = (s0 + g0) / 0.1;
  double x1 = (s1 + g1) / 0.1;
  double mx = fmax(x0, x1);
  double e0 = exp(x0 - mx), e1 = exp(x1 - mx);
  double es = e0 + e1;
  double y0 = e0 / es, y1 = e1 / es;
  float h0 = u01_from_bits(tf_bits32(k2a, k2b, j0));
  float h1 = u01_from_bits(tf_bits32(k2a, k2b, j1));
  const float TINY = 1.17549435e-38f;
  float v0 = fmaxf(TINY, h0 * (1.0f - TINY) + TINY);
  float v1 = fmaxf(TINY, h1 * (1.0f - TINY) + TINY);
  double gg0 = -log(-log((double)v0));
  double gg1 = -log(-log((double)v1));
  double l0 = log(y0 + 1e-20) + gg0;
  double l1 = log(y1 + 1e-20) + gg1;
  int p = (l1 > l0) ? 1 : 0;
  out_pid[b] = (float)p;
  pidxI[b] = p;
  ysum[b] = (float)(y0 + y1);
}

// ============================================================================
// final head
// ============================================================================
__global__ __launch_bounds__(256) void final_kernel(
    const float* __restrict__ h, const float* __restrict__ p2w,
    const float* __restrict__ p2b, const int* __restrict__ pidxI,
    const float* __restrict__ ysum, float* __restrict__ out0) {
  int t = blockIdx.x * 256 + threadIdx.x;
  if (t >= 40960) return;
  int b = t / 10, c = t % 10;
  int p = pidxI[b];
  const float* hr = h + (size_t)b * 384 + p * 192;
  const float* wr = p2w + ((size_t)p * 10 + c) * 192;
  float s = 0.f;
  for (int o = 0; o < 192; o++) s += hr[o] * wr[o];
  s += p2b[p * 10 + c];
  out0[t] = s * ysum[b];
}

// ============================================================================
// Launch orchestration. Fused convs + bf16-split MFMA pre-GEMM. ~235 MB ws.
// ============================================================================
extern "C" void kernel_launch(void* const* d_in, const int* in_sizes, int n_in,
                              void* d_out, int out_size, void* d_ws, size_t ws_size,
                              hipStream_t stream) {
  const float* input   = (const float*)d_in[0];
  const float* conv1_w = (const float*)d_in[1];
  const float* bn1_g   = (const float*)d_in[3];
  const float* bn1_b   = (const float*)d_in[4];
  const float* conv2_w = (const float*)d_in[5];
  const float* bn2_g   = (const float*)d_in[7];
  const float* bn2_b   = (const float*)d_in[8];
  const float* conv3_w = (const float*)d_in[9];
  const float* bn3_g   = (const float*)d_in[11];
  const float* bn3_b   = (const float*)d_in[12];
  const float* pre_w   = (const float*)d_in[13];
  const float* bnp_g   = (const float*)d_in[15];
  const float* bnp_b   = (const float*)d_in[16];
  const float* disc_w  = (const float*)d_in[17];
  const float* bnd_g   = (const float*)d_in[19];
  const float* bnd_b   = (const float*)d_in[20];
  const float* dfc_w   = (const float*)d_in[21];
  const float* dfc_b   = (const float*)d_in[22];
  const float* sw_w    = (const float*)d_in[23];
  const float* sw_b    = (const float*)d_in[24];
  const float* p1_w    = (const float*)d_in[25];
  const float* p1_b    = (const float*)d_in[26];
  const float* p2_w    = (const float*)d_in[27];
  const float* p2_b    = (const float*)d_in[28];

  float* W = (float*)d_ws;
  float* pool1  = W + 0;           // [4096][32][16][16]
  float* pool2  = W + 33554432;    // [4096][64][8][8]
  float* act3   = W + 0;           // [4096][128][8][8] = [4096][8192], alias pool1
  uint32_t* Acvt = (uint32_t*)(W + 0);         // act3 converted in-place
  uint32_t* Bcvt = (uint32_t*)(W + 33554432);  // pre_w packed, in dead pool2 region
  float* featp  = W + 50331648;    // [4096][1024]
  float* dpen   = W + 54525952;    // [4096][384]
  float* hbuf   = W + 56098816;    // [4096][384]
  float* swbuf  = W + 57671680;
  float* ysum   = W + 57679872;
  int*   pidxI  = (int*)(W + 57683968);
  float* part   = W + 57688064;
  double* sums  = (double*)(W + 58736640);
  float* scale  = W + 58769408;
  float* shift  = W + 58770432;

  float* out_cls = (float*)d_out;
  float* out_dom = out_cls + 40960;
  float* out_pid = out_cls + 49152;

  uint32_t k1a, k1b, k2a, k2b;
  threefry2x32(0u, 42u, 0u, 0u, k1a, k1b);
  threefry2x32(0u, 42u, 0u, 1u, k2a, k2b);

  // --- conv1 fused + BN ---
  conv1_fused_kernel<<<dim3(4096), dim3(256), 0, stream>>>(input, conv1_w, pool1, part);
  reduce_partials_kernel<<<dim3(64), dim3(256), 0, stream>>>(part, 4096, 64, sums);
  bn_finalize_kernel<<<dim3(1), dim3(64), 0, stream>>>(sums, 1, 0, bn1_g, bn1_b, scale, shift, 32, 1.0 / (4096.0 * 1024.0));
  bn_relu_vec4_kernel<8, 31><<<dim3(32768), dim3(256), 0, stream>>>(pool1, scale, shift, 8388608);

  // --- conv2 fused + BN ---
  conv2_fused_kernel<<<dim3(4096), dim3(256), 0, stream>>>(pool1, conv2_w, pool2, part);
  reduce_partials_kernel<<<dim3(128), dim3(256), 0, stream>>>(part, 4096, 128, sums);
  bn_finalize_kernel<<<dim3(1), dim3(64), 0, stream>>>(sums, 1, 0, bn2_g, bn2_b, scale, shift, 64, 1.0 / (4096.0 * 256.0));
  bn_relu_vec4_kernel<6, 63><<<dim3(16384), dim3(256), 0, stream>>>(pool2, scale, shift, 4194304);

  // --- conv3 fused + BN ---
  conv3_fused_kernel<<<dim3(4096), dim3(256), 0, stream>>>(pool2, conv3_w, act3, part);
  reduce_partials_kernel<<<dim3(256), dim3(256), 0, stream>>>(part, 4096, 256, sums);
  bn_finalize_kernel<<<dim3(1), dim3(128), 0, stream>>>(sums, 1, 0, bn3_g, bn3_b, scale, shift, 128, 1.0 / (4096.0 * 64.0));
  bn_relu_vec4_kernel<6, 127><<<dim3(32768), dim3(256), 0, stream>>>(act3, scale, shift, 8388608);

  // --- convert act3 (in-place) and pre_w to packed bf16-split ---
  cvt_bf16q_kernel<<<dim3(32768), dim3(256), 0, stream>>>(act3, Acvt, 8388608);
  cvt_bf16q_kernel<<<dim3(8192), dim3(256), 0, stream>>>(pre_w, Bcvt, 2097152);

  // --- pre FC 8192->1024 via bf16-split MFMA + BN + ReLU ---
  gemm_bf16q_kernel<<<dim3(16, 32), dim3(256), 0, stream>>>(Acvt, Bcvt, featp, 4096, 1024, 8192);
  col_stats_kernel<<<dim3(16, 8), dim3(1024), 0, stream>>>(featp, 4096, 1024, 8, sums);
  bn_finalize_kernel<<<dim3(4), dim3(256), 0, stream>>>(sums, 8, 2048, bnp_g, bnp_b, scale, shift, 1024, 1.0 / 4096.0);
  bn_relu_cols4_kernel<<<dim3(4096), dim3(256), 0, stream>>>(featp, scale, shift, 1048576, 256);

  // --- disc FC 1024->384 + BN + ReLU ---
  gemm_nt_kernel<0><<<dim3(6, 64), dim3(256), 0, stream>>>(featp, disc_w, (const float*)nullptr, dpen, 4096, 384, 1024);
  col_stats_kernel<<<dim3(6, 8), dim3(1024), 0, stream>>>(dpen, 4096, 384, 8, sums);
  bn_finalize_kernel<<<dim3(2), dim3(256), 0, stream>>>(sums, 8, 768, bnd_g, bnd_b, scale, shift, 384, 1.0 / 4096.0);
  bn_relu_cols4_kernel<<<dim3(1536), dim3(256), 0, stream>>>(dpen, scale, shift, 393216, 96);

  // --- heads + partition sampling ---
  heads_kernel<<<dim3(64), dim3(256), 0, stream>>>(dpen, dfc_w, dfc_b, sw_w, sw_b, out_dom, swbuf);
  partition_kernel<<<dim3(16), dim3(256), 0, stream>>>(swbuf, out_pid, pidxI, ysum, k1a, k1b, k2a, k2b);

  // --- experts: dense p1, then gather + p2 ---
  gemm_nt_kernel<1><<<dim3(6, 64), dim3(256), 0, stream>>>(featp, p1_w, p1_b, hbuf, 4096, 384, 1024);
  final_kernel<<<dim3(160), dim3(256), 0, stream>>>(hbuf, p2_w, p2_b, pidxI, ysum, out_cls);
}

// Round 8
// 1845.852 us; speedup vs baseline: 3.3766x; 1.3902x over previous
//
#include <hip/hip_runtime.h>
#include <cstdint>
#include <cstddef>

typedef __attribute__((ext_vector_type(8))) short short8;    // 8 bf16 (4 VGPR)
typedef __attribute__((ext_vector_type(4))) float f32x4;     // MFMA acc

// ============================================================================
// Threefry2x32 (matches jax._src.prng.threefry2x32).
// ============================================================================
__host__ __device__ inline void threefry2x32(uint32_t k0, uint32_t k1,
                                             uint32_t x0, uint32_t x1,
                                             uint32_t& o0, uint32_t& o1) {
  uint32_t ks2 = k0 ^ k1 ^ 0x1BD11BDAu;
  uint32_t v0 = x0 + k0, v1 = x1 + k1;
#define TF_R(r) { v0 += v1; v1 = (v1 << (r)) | (v1 >> (32 - (r))); v1 ^= v0; }
  TF_R(13) TF_R(15) TF_R(26) TF_R(6)
  v0 += k1; v1 += ks2 + 1u;
  TF_R(17) TF_R(29) TF_R(16) TF_R(24)
  v0 += ks2; v1 += k0 + 2u;
  TF_R(13) TF_R(15) TF_R(26) TF_R(6)
  v0 += k0; v1 += k1 + 3u;
  TF_R(17) TF_R(29) TF_R(16) TF_R(24)
  v0 += k1; v1 += ks2 + 4u;
  TF_R(13) TF_R(15) TF_R(26) TF_R(6)
  v0 += ks2; v1 += k0 + 5u;
#undef TF_R
  o0 = v0; o1 = v1;
}

__device__ __forceinline__ uint32_t tf_bits32(uint32_t k0, uint32_t k1, uint32_t j) {
  uint32_t o0, o1;
  threefry2x32(k0, k1, 0u, j, o0, o1);
  return o0 ^ o1;
}

__device__ __forceinline__ float u01_from_bits(uint32_t bits) {
  return __uint_as_float((bits >> 9) | 0x3f800000u) - 1.0f;  // [0,1)
}

__device__ __forceinline__ float waveSum(float v) {
#pragma unroll
  for (int off = 32; off > 0; off >>= 1) v += __shfl_down(v, off, 64);
  return v;
}

// ============================================================================
// conv1 fused: conv(3->32) + BN partials (unpooled) + RAW 2x2 maxpool store.
// ============================================================================
__global__ __launch_bounds__(256) void conv1_fused_kernel(
    const float* __restrict__ in, const float* __restrict__ w,
    float* __restrict__ outraw, float* __restrict__ partials) {
  __shared__ float ins[3 * 34 * 34];
  __shared__ float red[4][64];
  const int b = blockIdx.x, t = threadIdx.x;
  for (int i = t; i < 3 * 34 * 34; i += 256) {
    int ci = i / 1156, r = i % 1156, iy = r / 34, ix = r % 34;
    int y = iy - 1, x = ix - 1;
    float v = 0.f;
    if ((unsigned)y < 32u && (unsigned)x < 32u)
      v = in[(((size_t)b * 3 + ci) * 32 + y) * 32 + x];
    ins[i] = v;
  }
  __syncthreads();
  const int py = t >> 4, px = t & 15, wv = t >> 6, ln = t & 63;
  float win[3][4][4];
#pragma unroll
  for (int ci = 0; ci < 3; ci++)
#pragma unroll
    for (int r = 0; r < 4; r++)
#pragma unroll
      for (int c = 0; c < 4; c++)
        win[ci][r][c] = ins[ci * 1156 + (2 * py + r) * 34 + (2 * px + c)];
#pragma unroll 1
  for (int co = 0; co < 32; co++) {
    float acc00 = 0.f, acc01 = 0.f, acc10 = 0.f, acc11 = 0.f;
#pragma unroll
    for (int ci = 0; ci < 3; ci++) {
      const float* wp = w + (co * 3 + ci) * 9;  // wave-uniform -> s_load
#pragma unroll
      for (int dy = 0; dy < 3; dy++)
#pragma unroll
        for (int dx = 0; dx < 3; dx++) {
          float wvv = wp[dy * 3 + dx];
          acc00 += win[ci][dy][dx] * wvv;
          acc01 += win[ci][dy][dx + 1] * wvv;
          acc10 += win[ci][dy + 1][dx] * wvv;
          acc11 += win[ci][dy + 1][dx + 1] * wvv;
        }
    }
    float sm = acc00 + acc01 + acc10 + acc11;
    float sq = acc00 * acc00 + acc01 * acc01 + acc10 * acc10 + acc11 * acc11;
    float s = waveSum(sm), q = waveSum(sq);
    if (ln == 0) { red[wv][2 * co] = s; red[wv][2 * co + 1] = q; }
    float m = fmaxf(fmaxf(acc00, acc01), fmaxf(acc10, acc11));  // RAW max
    outraw[(((size_t)b * 32 + co) * 16 + py) * 16 + px] = m;
  }
  __syncthreads();
  for (int i = t; i < 64; i += 256)
    partials[(size_t)b * 64 + i] = red[0][i] + red[1][i] + red[2][i] + red[3][i];
}

// ============================================================================
// conv2 fused: conv(32->64) + BN partials + RAW 2x2 maxpool store.
// ============================================================================
__global__ __launch_bounds__(256) void conv2_fused_kernel(
    const float* __restrict__ in, const float* __restrict__ w,
    float* __restrict__ outraw, float* __restrict__ partials) {
  __shared__ float ins[32 * 18 * 18];
  __shared__ float os[8 * 256];
  __shared__ float red[4][128];
  const int b = blockIdx.x, t = threadIdx.x;
  for (int i = t; i < 32 * 18 * 18; i += 256) {
    int ci = i / 324, r = i % 324, iy = r / 18, ix = r % 18;
    int y = iy - 1, x = ix - 1;
    float v = 0.f;
    if ((unsigned)y < 16u && (unsigned)x < 16u)
      v = in[(((size_t)b * 32 + ci) * 16 + y) * 16 + x];
    ins[i] = v;
  }
  __syncthreads();
  const int y = t >> 4, x = t & 15, wv = t >> 6, ln = t & 63;
#pragma unroll 1
  for (int cc = 0; cc < 8; cc++) {
    if (cc) __syncthreads();  // protect os reuse
    float acc[8];
#pragma unroll
    for (int i = 0; i < 8; i++) acc[i] = 0.f;
#pragma unroll 1
    for (int ci = 0; ci < 32; ci++) {
      float vals[9];
#pragma unroll
      for (int dy = 0; dy < 3; dy++)
#pragma unroll
        for (int dx = 0; dx < 3; dx++)
          vals[dy * 3 + dx] = ins[ci * 324 + (y + dy) * 18 + (x + dx)];
#pragma unroll
      for (int co = 0; co < 8; co++) {
        const float* wp = w + ((size_t)(cc * 8 + co) * 32 + ci) * 9;  // uniform
#pragma unroll
        for (int k = 0; k < 9; k++) acc[co] += vals[k] * wp[k];
      }
    }
#pragma unroll
    for (int co = 0; co < 8; co++) {
      float a = acc[co];
      float s = waveSum(a), q = waveSum(a * a);
      if (ln == 0) { red[wv][2 * (cc * 8 + co)] = s; red[wv][2 * (cc * 8 + co) + 1] = q; }
      os[co * 256 + t] = a;
    }
    __syncthreads();
    for (int i = t; i < 512; i += 256) {
      int co = i >> 6, pl = i & 63, py = pl >> 3, px = pl & 7;
      const float* o = &os[co * 256 + (2 * py) * 16 + 2 * px];
      float m = fmaxf(fmaxf(o[0], o[1]), fmaxf(o[16], o[17]));  // RAW max
      outraw[(((size_t)b * 64 + cc * 8 + co) * 8 + py) * 8 + px] = m;
    }
  }
  __syncthreads();
  for (int i = t; i < 128; i += 256)
    partials[(size_t)b * 128 + i] = red[0][i] + red[1][i] + red[2][i] + red[3][i];
}

// ============================================================================
// conv3 via MFMA implicit GEMM (bf16-split exact, 4 terms).
// Input: pool2 packed u32 (hi16|lo16) [4096][64][8][8]. Weights prepacked
// [tap][co][ci] hi/lo bf16 planes. Per block: 1 image; 4 waves x (32co x 64px).
// K-loop: 9 taps x 2 ci-slices of 32. LDS: padded 10x10 image, hi/lo planes,
// XOR-swizzled ci ( ^ (row&7)<<3 ) for conflict-free ds_read_b128.
// Outputs: raw conv fp32 + exact BN partials.
// ============================================================================
__global__ __launch_bounds__(256) void conv3_mfma_kernel(
    const uint32_t* __restrict__ inq, const short* __restrict__ wh,
    const short* __restrict__ wl, float* __restrict__ outraw,
    float* __restrict__ partials) {
  __shared__ short Xh[100 * 64], Xl[100 * 64];
  __shared__ float red[256];
  const int b = blockIdx.x, t = threadIdx.x;
  // zero halo (u32 granularity: 2 ci per word)
  for (int i = t; i < 100 * 32; i += 256) {
    int row = i >> 5;
    int py = row / 10, pxx = row % 10;
    if (py == 0 || py == 9 || pxx == 0 || pxx == 9) {
      ((uint32_t*)Xh)[i] = 0u;
      ((uint32_t*)Xl)[i] = 0u;
    }
  }
  // interior: 32 ci-pairs x 64 px
  for (int i = t; i < 2048; i += 256) {
    int p = i >> 6, px = i & 63;
    int y = px >> 3, x = px & 7;
    uint32_t ua = inq[((size_t)b * 64 + 2 * p) * 64 + px];
    uint32_t ub = inq[((size_t)b * 64 + 2 * p + 1) * 64 + px];
    uint32_t h = (ua >> 16) | (ub & 0xffff0000u);
    uint32_t l = (ua & 0xffffu) | (ub << 16);
    int row = (y + 1) * 10 + (x + 1);
    int ci2 = (2 * p) ^ ((row & 7) << 3);  // swizzled (stays even)
    ((uint32_t*)Xh)[(row * 64 + ci2) >> 1] = h;
    ((uint32_t*)Xl)[(row * 64 + ci2) >> 1] = l;
  }
  __syncthreads();
  const int w = t >> 6, l = t & 63;
  const int lr = l & 15, lg = l >> 4;
  const int co_base = w * 32;
  f32x4 acc[2][4];
#pragma unroll
  for (int i = 0; i < 2; i++)
#pragma unroll
    for (int j = 0; j < 4; j++) acc[i][j] = (f32x4){0.f, 0.f, 0.f, 0.f};
#pragma unroll 1
  for (int tap = 0; tap < 9; tap++) {
    const int dy = tap / 3, dx = tap % 3;
#pragma unroll
    for (int sl = 0; sl < 2; sl++) {
      short8 awh[2], awl[2];
#pragma unroll
      for (int i = 0; i < 2; i++) {
        size_t off = ((size_t)tap * 128 + co_base + i * 16 + lr) * 64 + sl * 32 + lg * 8;
        awh[i] = *(const short8*)(wh + off);
        awl[i] = *(const short8*)(wl + off);
      }
      short8 bxh[4], bxl[4];
#pragma unroll
      for (int j = 0; j < 4; j++) {
        int px = j * 16 + lr;
        int row = ((px >> 3) + dy) * 10 + (px & 7) + dx;
        int ci = (sl * 32 + lg * 8) ^ ((row & 7) << 3);
        bxh[j] = *(const short8*)&Xh[row * 64 + ci];
        bxl[j] = *(const short8*)&Xl[row * 64 + ci];
      }
#pragma unroll
      for (int i = 0; i < 2; i++)
#pragma unroll
        for (int j = 0; j < 4; j++) {
          acc[i][j] = __builtin_amdgcn_mfma_f32_16x16x32_bf16(awh[i], bxh[j], acc[i][j], 0, 0, 0);
          acc[i][j] = __builtin_amdgcn_mfma_f32_16x16x32_bf16(awh[i], bxl[j], acc[i][j], 0, 0, 0);
          acc[i][j] = __builtin_amdgcn_mfma_f32_16x16x32_bf16(awl[i], bxh[j], acc[i][j], 0, 0, 0);
          acc[i][j] = __builtin_amdgcn_mfma_f32_16x16x32_bf16(awl[i], bxl[j], acc[i][j], 0, 0, 0);
        }
    }
  }
  // D layout: px = l&15 (col), co = co_base + i*16 + lg*4 + r (row)
#pragma unroll
  for (int i = 0; i < 2; i++)
#pragma unroll
    for (int r = 0; r < 4; r++) {
      int co = co_base + i * 16 + lg * 4 + r;
      float s = 0.f, q = 0.f;
#pragma unroll
      for (int j = 0; j < 4; j++) {
        float v = acc[i][j][r];
        outraw[((size_t)b * 128 + co) * 64 + j * 16 + lr] = v;
        s += v; q += v * v;
      }
#pragma unroll
      for (int off = 1; off <= 8; off <<= 1) {
        s += __shfl_xor(s, off, 64);
        q += __shfl_xor(q, off, 64);
      }
      if (lr == 0) { red[2 * co] = s; red[2 * co + 1] = q; }
    }
  __syncthreads();
  for (int i = t; i < 256; i += 256) partials[(size_t)b * 256 + i] = red[i];
}

// conv3 weight prepack: w [128][64][9] fp32 -> wh/wl [9][128][64] bf16 planes.
__device__ __forceinline__ uint32_t pack_bf16q(float x) {
  uint32_t u = __float_as_uint(x);
  uint32_t hi = (u + 0x7fffu + ((u >> 16) & 1u)) & 0xffff0000u;
  float r = x - __uint_as_float(hi);
  uint32_t v = __float_as_uint(r);
  uint32_t lo = (v + 0x7fffu + ((v >> 16) & 1u)) >> 16;
  return hi | lo;
}

__global__ void prep_w3_kernel(const float* __restrict__ w, short* __restrict__ wh,
                               short* __restrict__ wl) {
  int idx = blockIdx.x * 256 + threadIdx.x;
  if (idx >= 128 * 64 * 9) return;
  int tp = idx % 9, rem = idx / 9;
  int ci = rem % 64, co = rem / 64;
  uint32_t pq = pack_bf16q(w[idx]);
  size_t o = ((size_t)tp * 128 + co) * 64 + ci;
  wh[o] = (short)(pq >> 16);
  wl[o] = (short)(pq & 0xffffu);
}

// ============================================================================
// BN helpers
// ============================================================================
__global__ __launch_bounds__(256) void reduce_partials_kernel(
    const float* __restrict__ partials, int nblk, int Q, double* __restrict__ sums) {
  int q = blockIdx.x;
  double acc = 0.0;
  for (int i = threadIdx.x; i < nblk; i += 256) acc += (double)partials[(size_t)i * Q + q];
  __shared__ double red[256];
  red[threadIdx.x] = acc;
  __syncthreads();
  for (int s = 128; s > 0; s >>= 1) {
    if (threadIdx.x < s) red[threadIdx.x] += red[threadIdx.x + s];
    __syncthreads();
  }
  if (threadIdx.x == 0) sums[q] = red[0];
}

__global__ __launch_bounds__(1024) void col_stats_kernel(
    const float* __restrict__ X, int R, int C, int nch, double* __restrict__ sums) {
  int c0 = blockIdx.x * 64, chunk = blockIdx.y;
  int cl = threadIdx.x & 63, rg = threadIdx.x >> 6;
  int rows = R / nch, rbeg = chunk * rows, rend = rbeg + rows;
  double s = 0.0, sq = 0.0;
  for (int r = rbeg + rg; r < rend; r += 16) {
    float v = X[(size_t)r * C + c0 + cl];
    s += v; sq += (double)v * (double)v;
  }
  __shared__ double red[16][64][2];
  red[rg][cl][0] = s; red[rg][cl][1] = sq;
  __syncthreads();
  if (rg == 0) {
    for (int i = 1; i < 16; i++) { s += red[i][cl][0]; sq += red[i][cl][1]; }
    sums[(size_t)chunk * 2 * C + 2 * (c0 + cl)] = s;
    sums[(size_t)chunk * 2 * C + 2 * (c0 + cl) + 1] = sq;
  }
}

__global__ void bn_finalize_kernel(const double* __restrict__ sums, int nch, int cst2,
                                   const float* __restrict__ g, const float* __restrict__ b,
                                   float* __restrict__ scale, float* __restrict__ shift,
                                   int C, double invN) {
  int c = blockIdx.x * blockDim.x + threadIdx.x;
  if (c >= C) return;
  double s = 0.0, sq = 0.0;
  for (int ch = 0; ch < nch; ch++) {
    s += sums[(size_t)ch * cst2 + 2 * c];
    sq += sums[(size_t)ch * cst2 + 2 * c + 1];
  }
  double m = s * invN;
  double v = sq * invN - m * m;
  double sc = (double)g[c] / sqrt(v + 1e-5);
  scale[c] = (float)sc;
  shift[c] = (float)((double)b[c] - m * sc);
}

template <int LOGHW, int CMASK>
__global__ void bn_relu_vec4_kernel(float* __restrict__ X, const float* __restrict__ scale,
                                    const float* __restrict__ shift, int n4) {
  int i = blockIdx.x * blockDim.x + threadIdx.x;
  if (i >= n4) return;
  int c = ((i << 2) >> LOGHW) & CMASK;
  float4 v = ((float4*)X)[i];
  float sc = scale[c], sh = shift[c];
  v.x = fmaxf(v.x * sc + sh, 0.f);
  v.y = fmaxf(v.y * sc + sh, 0.f);
  v.z = fmaxf(v.z * sc + sh, 0.f);
  v.w = fmaxf(v.w * sc + sh, 0.f);
  ((float4*)X)[i] = v;
}

__global__ void bn_relu_cols4_kernel(float* __restrict__ X, const float* __restrict__ scale,
                                     const float* __restrict__ shift, int n4, int C4) {
  int i = blockIdx.x * blockDim.x + threadIdx.x;
  if (i >= n4) return;
  int c4 = i % C4;
  float4 v = ((float4*)X)[i];
  float4 sc = ((const float4*)scale)[c4];
  float4 sh = ((const float4*)shift)[c4];
  v.x = fmaxf(v.x * sc.x + sh.x, 0.f);
  v.y = fmaxf(v.y * sc.y + sh.y, 0.f);
  v.z = fmaxf(v.z * sc.z + sh.z, 0.f);
  v.w = fmaxf(v.w * sc.w + sh.w, 0.f);
  ((float4*)X)[i] = v;
}

__global__ void cvt_bf16q_kernel(const float* X, uint32_t* Y, int n4) {
  int i = blockIdx.x * blockDim.x + threadIdx.x;
  if (i >= n4) return;
  float4 x = ((const float4*)X)[i];
  uint4 o;
  o.x = pack_bf16q(x.x); o.y = pack_bf16q(x.y);
  o.z = pack_bf16q(x.z); o.w = pack_bf16q(x.w);
  ((uint4*)Y)[i] = o;
}

// ============================================================================
// bf16-split MFMA GEMM: C[M,N] = A[M,K]*B[N,K]^T. Tile 128x64, BK=32.
// ============================================================================
__global__ __launch_bounds__(256) void gemm_bf16q_kernel(
    const uint32_t* __restrict__ A, const uint32_t* __restrict__ B,
    float* __restrict__ C, int M, int N, int K) {
  __shared__ short Ah[128 * 32], Al[128 * 32], Bh[64 * 32], Bl[64 * 32];
  const int t = threadIdx.x;
  const int m0 = blockIdx.y << 7, n0 = blockIdx.x << 6;
  const int w = t >> 6, l = t & 63;
  const int wrow = (w >> 1) << 6, wcol = (w & 1) << 5;
  const int lr = l & 15, lg = l >> 4;
  const int ar = t >> 1, akh = (t & 1) << 4;
  const int br = t >> 2, bkh = (t & 3) << 3;
  const int asw = (ar & 3) << 3, bsw = (br & 3) << 3;
  const uint32_t* Ap = A + (size_t)(m0 + ar) * K + akh;
  const uint32_t* Bp = B + (size_t)(n0 + br) * K + bkh;
  f32x4 acc[4][2];
#pragma unroll
  for (int i = 0; i < 4; i++)
#pragma unroll
    for (int j = 0; j < 2; j++) acc[i][j] = (f32x4){0.f, 0.f, 0.f, 0.f};
  uint4 ra0 = *(const uint4*)(Ap + 0), ra1 = *(const uint4*)(Ap + 4);
  uint4 ra2 = *(const uint4*)(Ap + 8), ra3 = *(const uint4*)(Ap + 12);
  uint4 rb0 = *(const uint4*)(Bp + 0), rb1 = *(const uint4*)(Bp + 4);
  const int NS = K >> 5;
  for (int s = 0; s < NS; s++) {
    __syncthreads();
#define STORE_G(ARR_H, ARR_L, ROW, KB, SW, U)                                   \
    {                                                                           \
      uint32_t h0 = (U.x >> 16) | (U.y & 0xffff0000u);                          \
      uint32_t h1 = (U.z >> 16) | (U.w & 0xffff0000u);                          \
      uint32_t l0 = (U.x & 0xffffu) | (U.y << 16);                              \
      uint32_t l1 = (U.z & 0xffffu) | (U.w << 16);                              \
      int idx = (ROW) * 32 + ((KB) ^ (SW));                                     \
      *(uint2*)&ARR_H[idx] = make_uint2(h0, h1);                                \
      *(uint2*)&ARR_L[idx] = make_uint2(l0, l1);                                \
    }
    STORE_G(Ah, Al, ar, akh + 0, asw, ra0)
    STORE_G(Ah, Al, ar, akh + 4, asw, ra1)
    STORE_G(Ah, Al, ar, akh + 8, asw, ra2)
    STORE_G(Ah, Al, ar, akh + 12, asw, ra3)
    STORE_G(Bh, Bl, br, bkh + 0, bsw, rb0)
    STORE_G(Bh, Bl, br, bkh + 4, bsw, rb1)
#undef STORE_G
    __syncthreads();
    if (s + 1 < NS) {
      int ko = (s + 1) << 5;
      ra0 = *(const uint4*)(Ap + ko); ra1 = *(const uint4*)(Ap + ko + 4);
      ra2 = *(const uint4*)(Ap + ko + 8); ra3 = *(const uint4*)(Ap + ko + 12);
      rb0 = *(const uint4*)(Bp + ko); rb1 = *(const uint4*)(Bp + ko + 4);
    }
    short8 ahf[4], alf[4], bhf[2], blf[2];
#pragma unroll
    for (int i = 0; i < 4; i++) {
      int R = wrow + i * 16 + lr;
      int kk = (lg << 3) ^ ((R & 3) << 3);
      ahf[i] = *(const short8*)&Ah[R * 32 + kk];
      alf[i] = *(const short8*)&Al[R * 32 + kk];
    }
#pragma unroll
    for (int j = 0; j < 2; j++) {
      int Cc = wcol + j * 16 + lr;
      int kk = (lg << 3) ^ ((Cc & 3) << 3);
      bhf[j] = *(const short8*)&Bh[Cc * 32 + kk];
      blf[j] = *(const short8*)&Bl[Cc * 32 + kk];
    }
#pragma unroll
    for (int i = 0; i < 4; i++)
#pragma unroll
      for (int j = 0; j < 2; j++) {
        acc[i][j] = __builtin_amdgcn_mfma_f32_16x16x32_bf16(ahf[i], bhf[j], acc[i][j], 0, 0, 0);
        acc[i][j] = __builtin_amdgcn_mfma_f32_16x16x32_bf16(ahf[i], blf[j], acc[i][j], 0, 0, 0);
        acc[i][j] = __builtin_amdgcn_mfma_f32_16x16x32_bf16(alf[i], bhf[j], acc[i][j], 0, 0, 0);
        acc[i][j] = __builtin_amdgcn_mfma_f32_16x16x32_bf16(alf[i], blf[j], acc[i][j], 0, 0, 0);
      }
  }
#pragma unroll
  for (int i = 0; i < 4; i++)
#pragma unroll
    for (int j = 0; j < 2; j++) {
      int n = n0 + wcol + j * 16 + lr;
#pragma unroll
      for (int r = 0; r < 4; r++) {
        int m = m0 + wrow + i * 16 + lg * 4 + r;
        C[(size_t)m * N + n] = acc[i][j][r];
      }
    }
}

// ============================================================================
// fp32 64x64 GEMM NT (small-N duty): C = A*B^T (+bias, relu). Padded LDS.
// ============================================================================
template <int BIASRELU>
__global__ __launch_bounds__(256) void gemm_nt_kernel(
    const float* __restrict__ A, const float* __restrict__ B,
    const float* __restrict__ bias, float* __restrict__ C, int M, int N, int K) {
  __shared__ float As[16][68];
  __shared__ float Bs[16][68];
  const int t = threadIdx.x;
  const int tn = t & 15, tm = t >> 4;
  const int m0 = blockIdx.y << 6, n0 = blockIdx.x << 6;
  const int lr = t >> 2, lk = (t & 3) << 2;
  const float* Ap = A + (size_t)(m0 + lr) * K + lk;
  const float* Bp = B + (size_t)(n0 + lr) * K + lk;
  float acc[4][4];
#pragma unroll
  for (int i = 0; i < 4; i++)
#pragma unroll
    for (int j = 0; j < 4; j++) acc[i][j] = 0.f;
  for (int k0 = 0; k0 < K; k0 += 16) {
    float4 av = *(const float4*)(Ap + k0);
    float4 bv = *(const float4*)(Bp + k0);
    __syncthreads();
    As[lk + 0][lr] = av.x; As[lk + 1][lr] = av.y; As[lk + 2][lr] = av.z; As[lk + 3][lr] = av.w;
    Bs[lk + 0][lr] = bv.x; Bs[lk + 1][lr] = bv.y; Bs[lk + 2][lr] = bv.z; Bs[lk + 3][lr] = bv.w;
    __syncthreads();
#pragma unroll
    for (int kk = 0; kk < 16; kk++) {
      float4 a4 = *(const float4*)&As[kk][tm << 2];
      float4 b4 = *(const float4*)&Bs[kk][tn << 2];
      acc[0][0] += a4.x * b4.x; acc[0][1] += a4.x * b4.y; acc[0][2] += a4.x * b4.z; acc[0][3] += a4.x * b4.w;
      acc[1][0] += a4.y * b4.x; acc[1][1] += a4.y * b4.y; acc[1][2] += a4.y * b4.z; acc[1][3] += a4.y * b4.w;
      acc[2][0] += a4.z * b4.x; acc[2][1] += a4.z * b4.y; acc[2][2] += a4.z * b4.z; acc[2][3] += a4.z * b4.w;
      acc[3][0] += a4.w * b4.x; acc[3][1] += a4.w * b4.y; acc[3][2] += a4.w * b4.z; acc[3][3] += a4.w * b4.w;
    }
  }
#pragma unroll
  for (int i = 0; i < 4; i++) {
    int m = m0 + (tm << 2) + i;
    float4 o;
    float v0 = acc[i][0], v1 = acc[i][1], v2 = acc[i][2], v3 = acc[i][3];
    if (BIASRELU) {
      int nb = n0 + (tn << 2);
      v0 = fmaxf(v0 + bias[nb + 0], 0.f);
      v1 = fmaxf(v1 + bias[nb + 1], 0.f);
      v2 = fmaxf(v2 + bias[nb + 2], 0.f);
      v3 = fmaxf(v3 + bias[nb + 3], 0.f);
    }
    o.x = v0; o.y = v1; o.z = v2; o.w = v3;
    *(float4*)&C[(size_t)m * N + n0 + (tn << 2)] = o;
  }
}

// ============================================================================
// heads (double accumulation; sw_logits amplified 10x by TAU)
// ============================================================================
__global__ __launch_bounds__(256) void heads_kernel(
    const float* __restrict__ dpen, const float* __restrict__ dfc_w,
    const float* __restrict__ dfc_b, const float* __restrict__ sw_w,
    const float* __restrict__ sw_b, float* __restrict__ out_dom,
    float* __restrict__ swbuf) {
  int t = blockIdx.x * 256 + threadIdx.x;
  int b = t >> 2, j = t & 3;
  const float* row = dpen + (size_t)b * 384;
  const float* wr = (j < 2) ? (dfc_w + j * 384) : (sw_w + (j - 2) * 384);
  double s = 0.0;
  for (int k = 0; k < 384; k++) s += (double)row[k] * (double)wr[k];
  s += (double)((j < 2) ? dfc_b[j] : sw_b[j - 2]);
  if (j < 2) out_dom[b * 2 + j] = (float)s;
  else swbuf[b * 2 + (j - 2)] = (float)s;
}

// ============================================================================
// gumbel-softmax + categorical partition choice (threefry partitionable).
// ============================================================================
__global__ __launch_bounds__(256) void partition_kernel(
    const float* __restrict__ swbuf, float* __restrict__ out_pid,
    int* __restrict__ pidxI, float* __restrict__ ysum,
    uint32_t k1a, uint32_t k1b, uint32_t k2a, uint32_t k2b) {
  int b = blockIdx.x * 256 + threadIdx.x;
  if (b >= 4096) return;
  uint32_t j0 = (uint32_t)(2 * b), j1 = (uint32_t)(2 * b + 1);
  float f0 = u01_from_bits(tf_bits32(k1a, k1b, j0));
  float f1 = u01_from_bits(tf_bits32(k1a, k1b, j1));
  const float MINV = 1e-10f;
  float u0 = fmaxf(MINV, f0 * (1.0f - MINV) + MINV);
  float u1 = fmaxf(MINV, f1 * (1.0f - MINV) + MINV);
  double g0 = -log(-log((double)u0));
  double g1 = -log(-log((double)u1));
  double s0 = (double)swbuf[2 * b], s1 = (double)swbuf[2 * b + 1];
  double x0 = (s0 + g0) / 0.1;
  double x1 = (s1 + g1) / 0.1;
  double mx = fmax(x0, x1);
  double e0 = exp(x0 - mx), e1 = exp(x1 - mx);
  double es = e0 + e1;
  double y0 = e0 / es, y1 = e1 / es;
  float h0 = u01_from_bits(tf_bits32(k2a, k2b, j0));
  float h1 = u01_from_bits(tf_bits32(k2a, k2b, j1));
  const float TINY = 1.17549435e-38f;
  float v0 = fmaxf(TINY, h0 * (1.0f - TINY) + TINY);
  float v1 = fmaxf(TINY, h1 * (1.0f - TINY) + TINY);
  double gg0 = -log(-log((double)v0));
  double gg1 = -log(-log((double)v1));
  double l0 = log(y0 + 1e-20) + gg0;
  double l1 = log(y1 + 1e-20) + gg1;
  int p = (l1 > l0) ? 1 : 0;
  out_pid[b] = (float)p;
  pidxI[b] = p;
  ysum[b] = (float)(y0 + y1);
}

// ============================================================================
// final head
// ============================================================================
__global__ __launch_bounds__(256) void final_kernel(
    const float* __restrict__ h, const float* __restrict__ p2w,
    const float* __restrict__ p2b, const int* __restrict__ pidxI,
    const float* __restrict__ ysum, float* __restrict__ out0) {
  int t = blockIdx.x * 256 + threadIdx.x;
  if (t >= 40960) return;
  int b = t / 10, c = t % 10;
  int p = pidxI[b];
  const float* hr = h + (size_t)b * 384 + p * 192;
  const float* wr = p2w + ((size_t)p * 10 + c) * 192;
  float s = 0.f;
  for (int o = 0; o < 192; o++) s += hr[o] * wr[o];
  s += p2b[p * 10 + c];
  out0[t] = s * ysum[b];
}

// ============================================================================
// Launch orchestration. Fused convs, MFMA conv3 + MFMA pre-FC. ~235 MB ws.
// ============================================================================
extern "C" void kernel_launch(void* const* d_in, const int* in_sizes, int n_in,
                              void* d_out, int out_size, void* d_ws, size_t ws_size,
                              hipStream_t stream) {
  const float* input   = (const float*)d_in[0];
  const float* conv1_w = (const float*)d_in[1];
  const float* bn1_g   = (const float*)d_in[3];
  const float* bn1_b   = (const float*)d_in[4];
  const float* conv2_w = (const float*)d_in[5];
  const float* bn2_g   = (const float*)d_in[7];
  const float* bn2_b   = (const float*)d_in[8];
  const float* conv3_w = (const float*)d_in[9];
  const float* bn3_g   = (const float*)d_in[11];
  const float* bn3_b   = (const float*)d_in[12];
  const float* pre_w   = (const float*)d_in[13];
  const float* bnp_g   = (const float*)d_in[15];
  const float* bnp_b   = (const float*)d_in[16];
  const float* disc_w  = (const float*)d_in[17];
  const float* bnd_g   = (const float*)d_in[19];
  const float* bnd_b   = (const float*)d_in[20];
  const float* dfc_w   = (const float*)d_in[21];
  const float* dfc_b   = (const float*)d_in[22];
  const float* sw_w    = (const float*)d_in[23];
  const float* sw_b    = (const float*)d_in[24];
  const float* p1_w    = (const float*)d_in[25];
  const float* p1_b    = (const float*)d_in[26];
  const float* p2_w    = (const float*)d_in[27];
  const float* p2_b    = (const float*)d_in[28];

  float* W = (float*)d_ws;
  float* pool1  = W + 0;           // [4096][32][16][16]
  float* pool2  = W + 33554432;    // [4096][64][8][8] fp32 -> packed in place
  uint32_t* pool2q = (uint32_t*)pool2;
  float* act3   = W + 0;           // [4096][128][8][8], alias pool1 (dead)
  uint32_t* Acvt = (uint32_t*)(W + 0);         // act3 packed in place
  uint32_t* Bcvt = (uint32_t*)(W + 33554432);  // pre_w packed (pool2q dead then)
  float* featp  = W + 50331648;    // [4096][1024]
  short* wh3    = (short*)(W + 50331648);      // conv3 weights hi (featp region,
  short* wl3    = (short*)(W + 50368512);      //  dead until pre-FC gemm writes)
  float* dpen   = W + 54525952;
  float* hbuf   = W + 56098816;
  float* swbuf  = W + 57671680;
  float* ysum   = W + 57679872;
  int*   pidxI  = (int*)(W + 57683968);
  float* part   = W + 57688064;
  double* sums  = (double*)(W + 58736640);
  float* scale  = W + 58769408;
  float* shift  = W + 58770432;

  float* out_cls = (float*)d_out;
  float* out_dom = out_cls + 40960;
  float* out_pid = out_cls + 49152;

  uint32_t k1a, k1b, k2a, k2b;
  threefry2x32(0u, 42u, 0u, 0u, k1a, k1b);
  threefry2x32(0u, 42u, 0u, 1u, k2a, k2b);

  // --- conv1 fused + BN ---
  conv1_fused_kernel<<<dim3(4096), dim3(256), 0, stream>>>(input, conv1_w, pool1, part);
  reduce_partials_kernel<<<dim3(64), dim3(256), 0, stream>>>(part, 4096, 64, sums);
  bn_finalize_kernel<<<dim3(1), dim3(64), 0, stream>>>(sums, 1, 0, bn1_g, bn1_b, scale, shift, 32, 1.0 / (4096.0 * 1024.0));
  bn_relu_vec4_kernel<8, 31><<<dim3(32768), dim3(256), 0, stream>>>(pool1, scale, shift, 8388608);

  // --- conv2 fused + BN ---
  conv2_fused_kernel<<<dim3(4096), dim3(256), 0, stream>>>(pool1, conv2_w, pool2, part);
  reduce_partials_kernel<<<dim3(128), dim3(256), 0, stream>>>(part, 4096, 128, sums);
  bn_finalize_kernel<<<dim3(1), dim3(64), 0, stream>>>(sums, 1, 0, bn2_g, bn2_b, scale, shift, 64, 1.0 / (4096.0 * 256.0));
  bn_relu_vec4_kernel<6, 63><<<dim3(16384), dim3(256), 0, stream>>>(pool2, scale, shift, 4194304);

  // --- conv3 via MFMA implicit GEMM + BN ---
  cvt_bf16q_kernel<<<dim3(16384), dim3(256), 0, stream>>>(pool2, pool2q, 4194304);
  prep_w3_kernel<<<dim3(288), dim3(256), 0, stream>>>(conv3_w, wh3, wl3);
  conv3_mfma_kernel<<<dim3(4096), dim3(256), 0, stream>>>(pool2q, wh3, wl3, act3, part);
  reduce_partials_kernel<<<dim3(256), dim3(256), 0, stream>>>(part, 4096, 256, sums);
  bn_finalize_kernel<<<dim3(1), dim3(128), 0, stream>>>(sums, 1, 0, bn3_g, bn3_b, scale, shift, 128, 1.0 / (4096.0 * 64.0));
  bn_relu_vec4_kernel<6, 127><<<dim3(32768), dim3(256), 0, stream>>>(act3, scale, shift, 8388608);

  // --- convert act3 (in-place) and pre_w to packed bf16-split ---
  cvt_bf16q_kernel<<<dim3(32768), dim3(256), 0, stream>>>(act3, Acvt, 8388608);
  cvt_bf16q_kernel<<<dim3(8192), dim3(256), 0, stream>>>(pre_w, Bcvt, 2097152);

  // --- pre FC 8192->1024 via bf16-split MFMA + BN + ReLU ---
  gemm_bf16q_kernel<<<dim3(16, 32), dim3(256), 0, stream>>>(Acvt, Bcvt, featp, 4096, 1024, 8192);
  col_stats_kernel<<<dim3(16, 8), dim3(1024), 0, stream>>>(featp, 4096, 1024, 8, sums);
  bn_finalize_kernel<<<dim3(4), dim3(256), 0, stream>>>(sums, 8, 2048, bnp_g, bnp_b, scale, shift, 1024, 1.0 / 4096.0);
  bn_relu_cols4_kernel<<<dim3(4096), dim3(256), 0, stream>>>(featp, scale, shift, 1048576, 256);

  // --- disc FC 1024->384 + BN + ReLU ---
  gemm_nt_kernel<0><<<dim3(6, 64), dim3(256), 0, stream>>>(featp, disc_w, (const float*)nullptr, dpen, 4096, 384, 1024);
  col_stats_kernel<<<dim3(6, 8), dim3(1024), 0, stream>>>(dpen, 4096, 384, 8, sums);
  bn_finalize_kernel<<<dim3(2), dim3(256), 0, stream>>>(sums, 8, 768, bnd_g, bnd_b, scale, shift, 384, 1.0 / 4096.0);
  bn_relu_cols4_kernel<<<dim3(1536), dim3(256), 0, stream>>>(dpen, scale, shift, 393216, 96);

  // --- heads + partition sampling ---
  heads_kernel<<<dim3(64), dim3(256), 0, stream>>>(dpen, dfc_w, dfc_b, sw_w, sw_b, out_dom, swbuf);
  partition_kernel<<<dim3(16), dim3(256), 0, stream>>>(swbuf, out_pid, pidxI, ysum, k1a, k1b, k2a, k2b);

  // --- experts: dense p1, then gather + p2 ---
  gemm_nt_kernel<1><<<dim3(6, 64), dim3(256), 0, stream>>>(featp, p1_w, p1_b, hbuf, 4096, 384, 1024);
  final_kernel<<<dim3(160), dim3(256), 0, stream>>>(hbuf, p2_w, p2_b, pidxI, ysum, out_cls);
}

// Round 9
// 1232.162 us; speedup vs baseline: 5.0583x; 1.4981x over previous
//
#include <hip/hip_runtime.h>
#include <cstdint>
#include <cstddef>

typedef __attribute__((ext_vector_type(8))) short short8;    // 8 bf16 (4 VGPR)
typedef __attribute__((ext_vector_type(4))) float f32x4;     // MFMA acc

// ============================================================================
// Threefry2x32 (matches jax._src.prng.threefry2x32).
// ============================================================================
__host__ __device__ inline void threefry2x32(uint32_t k0, uint32_t k1,
                                             uint32_t x0, uint32_t x1,
                                             uint32_t& o0, uint32_t& o1) {
  uint32_t ks2 = k0 ^ k1 ^ 0x1BD11BDAu;
  uint32_t v0 = x0 + k0, v1 = x1 + k1;
#define TF_R(r) { v0 += v1; v1 = (v1 << (r)) | (v1 >> (32 - (r))); v1 ^= v0; }
  TF_R(13) TF_R(15) TF_R(26) TF_R(6)
  v0 += k1; v1 += ks2 + 1u;
  TF_R(17) TF_R(29) TF_R(16) TF_R(24)
  v0 += ks2; v1 += k0 + 2u;
  TF_R(13) TF_R(15) TF_R(26) TF_R(6)
  v0 += k0; v1 += k1 + 3u;
  TF_R(17) TF_R(29) TF_R(16) TF_R(24)
  v0 += k1; v1 += ks2 + 4u;
  TF_R(13) TF_R(15) TF_R(26) TF_R(6)
  v0 += ks2; v1 += k0 + 5u;
#undef TF_R
  o0 = v0; o1 = v1;
}

__device__ __forceinline__ uint32_t tf_bits32(uint32_t k0, uint32_t k1, uint32_t j) {
  uint32_t o0, o1;
  threefry2x32(k0, k1, 0u, j, o0, o1);
  return o0 ^ o1;
}

__device__ __forceinline__ float u01_from_bits(uint32_t bits) {
  return __uint_as_float((bits >> 9) | 0x3f800000u) - 1.0f;  // [0,1)
}

__device__ __forceinline__ float waveSum(float v) {
#pragma unroll
  for (int off = 32; off > 0; off >>= 1) v += __shfl_down(v, off, 64);
  return v;
}

// ============================================================================
// conv1 fused: conv(3->32) + BN partials (unpooled) + RAW 2x2 maxpool store.
// ============================================================================
__global__ __launch_bounds__(256) void conv1_fused_kernel(
    const float* __restrict__ in, const float* __restrict__ w,
    float* __restrict__ outraw, float* __restrict__ partials) {
  __shared__ float ins[3 * 34 * 34];
  __shared__ float red[4][64];
  const int b = blockIdx.x, t = threadIdx.x;
  for (int i = t; i < 3 * 34 * 34; i += 256) {
    int ci = i / 1156, r = i % 1156, iy = r / 34, ix = r % 34;
    int y = iy - 1, x = ix - 1;
    float v = 0.f;
    if ((unsigned)y < 32u && (unsigned)x < 32u)
      v = in[(((size_t)b * 3 + ci) * 32 + y) * 32 + x];
    ins[i] = v;
  }
  __syncthreads();
  const int py = t >> 4, px = t & 15, wv = t >> 6, ln = t & 63;
  float win[3][4][4];
#pragma unroll
  for (int ci = 0; ci < 3; ci++)
#pragma unroll
    for (int r = 0; r < 4; r++)
#pragma unroll
      for (int c = 0; c < 4; c++)
        win[ci][r][c] = ins[ci * 1156 + (2 * py + r) * 34 + (2 * px + c)];
#pragma unroll 1
  for (int co = 0; co < 32; co++) {
    float acc00 = 0.f, acc01 = 0.f, acc10 = 0.f, acc11 = 0.f;
#pragma unroll
    for (int ci = 0; ci < 3; ci++) {
      const float* wp = w + (co * 3 + ci) * 9;  // wave-uniform -> s_load
#pragma unroll
      for (int dy = 0; dy < 3; dy++)
#pragma unroll
        for (int dx = 0; dx < 3; dx++) {
          float wvv = wp[dy * 3 + dx];
          acc00 += win[ci][dy][dx] * wvv;
          acc01 += win[ci][dy][dx + 1] * wvv;
          acc10 += win[ci][dy + 1][dx] * wvv;
          acc11 += win[ci][dy + 1][dx + 1] * wvv;
        }
    }
    float sm = acc00 + acc01 + acc10 + acc11;
    float sq = acc00 * acc00 + acc01 * acc01 + acc10 * acc10 + acc11 * acc11;
    float s = waveSum(sm), q = waveSum(sq);
    if (ln == 0) { red[wv][2 * co] = s; red[wv][2 * co + 1] = q; }
    float m = fmaxf(fmaxf(acc00, acc01), fmaxf(acc10, acc11));  // RAW max
    outraw[(((size_t)b * 32 + co) * 16 + py) * 16 + px] = m;
  }
  __syncthreads();
  for (int i = t; i < 64; i += 256)
    partials[(size_t)b * 64 + i] = red[0][i] + red[1][i] + red[2][i] + red[3][i];
}

// ============================================================================
// bf16-split helpers
// ============================================================================
__device__ __forceinline__ uint32_t pack_bf16q(float x) {
  uint32_t u = __float_as_uint(x);
  uint32_t hi = (u + 0x7fffu + ((u >> 16) & 1u)) & 0xffff0000u;
  float r = x - __uint_as_float(hi);
  uint32_t v = __float_as_uint(r);
  uint32_t lo = (v + 0x7fffu + ((v >> 16) & 1u)) >> 16;
  return hi | lo;
}

__global__ void cvt_bf16q_kernel(const float* X, uint32_t* Y, int n4) {
  int i = blockIdx.x * blockDim.x + threadIdx.x;
  if (i >= n4) return;
  float4 x = ((const float4*)X)[i];
  uint4 o;
  o.x = pack_bf16q(x.x); o.y = pack_bf16q(x.y);
  o.z = pack_bf16q(x.z); o.w = pack_bf16q(x.w);
  ((uint4*)Y)[i] = o;
}

// conv2 weight prepack: w [64][32][9] fp32 -> wh/wl [9][64][32] bf16 planes.
__global__ void prep_w2_kernel(const float* __restrict__ w, short* __restrict__ wh,
                               short* __restrict__ wl) {
  int idx = blockIdx.x * 256 + threadIdx.x;
  if (idx >= 64 * 32 * 9) return;
  int tp = idx % 9, rem = idx / 9;
  int ci = rem % 32, co = rem / 32;
  uint32_t pq = pack_bf16q(w[idx]);
  size_t o = ((size_t)tp * 64 + co) * 32 + ci;
  wh[o] = (short)(pq >> 16);
  wl[o] = (short)(pq & 0xffffu);
}

// conv3 weight prepack: w [128][64][9] fp32 -> wh/wl [9][128][64] bf16 planes.
__global__ void prep_w3_kernel(const float* __restrict__ w, short* __restrict__ wh,
                               short* __restrict__ wl) {
  int idx = blockIdx.x * 256 + threadIdx.x;
  if (idx >= 128 * 64 * 9) return;
  int tp = idx % 9, rem = idx / 9;
  int ci = rem % 64, co = rem / 64;
  uint32_t pq = pack_bf16q(w[idx]);
  size_t o = ((size_t)tp * 128 + co) * 64 + ci;
  wh[o] = (short)(pq >> 16);
  wl[o] = (short)(pq & 0xffffu);
}

// ============================================================================
// conv2 via MFMA implicit GEMM (bf16-split exact, 4 terms).
// Input: pool1 packed u32 [4096][32][16][16]. Weights [tap][64co][32ci] hi/lo.
// Block = 1 image, 4 waves; wave w computes all 64 co x 64 px (y = w*4+j).
// LDS: padded 18x18 image rows x 32 ci, hi/lo, XOR swizzle (row&3)<<3 on 8-ci
// blocks. Outputs: exact unpooled BN partials + RAW 2x2 maxpooled conv.
// ============================================================================
__global__ __launch_bounds__(256) void conv2_mfma_kernel(
    const uint32_t* __restrict__ inq, const short* __restrict__ wh,
    const short* __restrict__ wl, float* __restrict__ outpool,
    float* __restrict__ partials) {
  __shared__ short Xh[324 * 32], Xl[324 * 32];
  __shared__ float red[4][128];
  const int b = blockIdx.x, t = threadIdx.x;
  // zero halo (u32 = 2 ci)
  for (int i = t; i < 324 * 16; i += 256) {
    int row = i >> 4;
    int py = row / 18, pxx = row % 18;
    if (py == 0 || py == 17 || pxx == 0 || pxx == 17) {
      ((uint32_t*)Xh)[i] = 0u;
      ((uint32_t*)Xl)[i] = 0u;
    }
  }
  // interior: 16 ci-pairs x 256 px
  for (int i = t; i < 4096; i += 256) {
    int p = i >> 8, px = i & 255;
    int y = px >> 4, x = px & 15;
    uint32_t ua = inq[((size_t)b * 32 + 2 * p) * 256 + px];
    uint32_t ub = inq[((size_t)b * 32 + 2 * p + 1) * 256 + px];
    uint32_t h = (ua >> 16) | (ub & 0xffff0000u);
    uint32_t l = (ua & 0xffffu) | (ub << 16);
    int row = (y + 1) * 18 + (x + 1);
    int ci2 = (2 * p) ^ ((row & 3) << 3);  // swizzled, stays even
    ((uint32_t*)Xh)[(row * 32 + ci2) >> 1] = h;
    ((uint32_t*)Xl)[(row * 32 + ci2) >> 1] = l;
  }
  __syncthreads();
  const int w = t >> 6, l = t & 63;
  const int lr = l & 15, lg = l >> 4;
  f32x4 acc[4][4];  // [co block][px block]
#pragma unroll
  for (int i = 0; i < 4; i++)
#pragma unroll
    for (int j = 0; j < 4; j++) acc[i][j] = (f32x4){0.f, 0.f, 0.f, 0.f};
#pragma unroll 1
  for (int tap = 0; tap < 9; tap++) {
    const int dy = tap / 3, dx = tap % 3;
    short8 awh[4], awl[4];
#pragma unroll
    for (int i = 0; i < 4; i++) {
      size_t off = ((size_t)tap * 64 + i * 16 + lr) * 32 + lg * 8;
      awh[i] = *(const short8*)(wh + off);
      awl[i] = *(const short8*)(wl + off);
    }
    short8 bxh[4], bxl[4];
#pragma unroll
    for (int j = 0; j < 4; j++) {
      int y = w * 4 + j, x = lr;
      int row = (y + dy) * 18 + (x + dx);
      int ci = (lg * 8) ^ ((row & 3) << 3);
      bxh[j] = *(const short8*)&Xh[row * 32 + ci];
      bxl[j] = *(const short8*)&Xl[row * 32 + ci];
    }
#pragma unroll
    for (int i = 0; i < 4; i++)
#pragma unroll
      for (int j = 0; j < 4; j++) {
        acc[i][j] = __builtin_amdgcn_mfma_f32_16x16x32_bf16(awh[i], bxh[j], acc[i][j], 0, 0, 0);
        acc[i][j] = __builtin_amdgcn_mfma_f32_16x16x32_bf16(awh[i], bxl[j], acc[i][j], 0, 0, 0);
        acc[i][j] = __builtin_amdgcn_mfma_f32_16x16x32_bf16(awl[i], bxh[j], acc[i][j], 0, 0, 0);
        acc[i][j] = __builtin_amdgcn_mfma_f32_16x16x32_bf16(awl[i], bxl[j], acc[i][j], 0, 0, 0);
      }
  }
  // D layout: px col = j*16 + lr (y = w*4+j, x = lr); co = i*16 + lg*4 + r.
#pragma unroll
  for (int i = 0; i < 4; i++)
#pragma unroll
    for (int r = 0; r < 4; r++) {
      int co = i * 16 + lg * 4 + r;
      float v0 = acc[i][0][r], v1 = acc[i][1][r], v2 = acc[i][2][r], v3 = acc[i][3][r];
      // exact unpooled partials over this wave's 64 px
      float s = v0 + v1 + v2 + v3;
      float q = v0 * v0 + v1 * v1 + v2 * v2 + v3 * v3;
#pragma unroll
      for (int off = 1; off <= 8; off <<= 1) {
        s += __shfl_xor(s, off, 64);
        q += __shfl_xor(q, off, 64);
      }
      if (lr == 0) { red[w][2 * co] = s; red[w][2 * co + 1] = q; }
      // RAW 2x2 maxpool: horizontal via lane^1, vertical via j-pairs
      float h0 = fmaxf(v0, __shfl_xor(v0, 1, 64));
      float h1 = fmaxf(v1, __shfl_xor(v1, 1, 64));
      float h2 = fmaxf(v2, __shfl_xor(v2, 1, 64));
      float h3 = fmaxf(v3, __shfl_xor(v3, 1, 64));
      float pm0 = fmaxf(h0, h1);  // pooled row w*2
      float pm1 = fmaxf(h2, h3);  // pooled row w*2+1
      if ((lr & 1) == 0) {
        size_t base = ((size_t)b * 64 + co) * 64 + (w * 2) * 8 + (lr >> 1);
        outpool[base] = pm0;
        outpool[base + 8] = pm1;
      }
    }
  __syncthreads();
  for (int i = t; i < 128; i += 256)
    partials[(size_t)b * 128 + i] = red[0][i] + red[1][i] + red[2][i] + red[3][i];
}

// ============================================================================
// conv3 via MFMA implicit GEMM (bf16-split exact, 4 terms).
// ============================================================================
__global__ __launch_bounds__(256) void conv3_mfma_kernel(
    const uint32_t* __restrict__ inq, const short* __restrict__ wh,
    const short* __restrict__ wl, float* __restrict__ outraw,
    float* __restrict__ partials) {
  __shared__ short Xh[100 * 64], Xl[100 * 64];
  __shared__ float red[256];
  const int b = blockIdx.x, t = threadIdx.x;
  for (int i = t; i < 100 * 32; i += 256) {
    int row = i >> 5;
    int py = row / 10, pxx = row % 10;
    if (py == 0 || py == 9 || pxx == 0 || pxx == 9) {
      ((uint32_t*)Xh)[i] = 0u;
      ((uint32_t*)Xl)[i] = 0u;
    }
  }
  for (int i = t; i < 2048; i += 256) {
    int p = i >> 6, px = i & 63;
    int y = px >> 3, x = px & 7;
    uint32_t ua = inq[((size_t)b * 64 + 2 * p) * 64 + px];
    uint32_t ub = inq[((size_t)b * 64 + 2 * p + 1) * 64 + px];
    uint32_t h = (ua >> 16) | (ub & 0xffff0000u);
    uint32_t l = (ua & 0xffffu) | (ub << 16);
    int row = (y + 1) * 10 + (x + 1);
    int ci2 = (2 * p) ^ ((row & 7) << 3);
    ((uint32_t*)Xh)[(row * 64 + ci2) >> 1] = h;
    ((uint32_t*)Xl)[(row * 64 + ci2) >> 1] = l;
  }
  __syncthreads();
  const int w = t >> 6, l = t & 63;
  const int lr = l & 15, lg = l >> 4;
  const int co_base = w * 32;
  f32x4 acc[2][4];
#pragma unroll
  for (int i = 0; i < 2; i++)
#pragma unroll
    for (int j = 0; j < 4; j++) acc[i][j] = (f32x4){0.f, 0.f, 0.f, 0.f};
#pragma unroll 1
  for (int tap = 0; tap < 9; tap++) {
    const int dy = tap / 3, dx = tap % 3;
#pragma unroll
    for (int sl = 0; sl < 2; sl++) {
      short8 awh[2], awl[2];
#pragma unroll
      for (int i = 0; i < 2; i++) {
        size_t off = ((size_t)tap * 128 + co_base + i * 16 + lr) * 64 + sl * 32 + lg * 8;
        awh[i] = *(const short8*)(wh + off);
        awl[i] = *(const short8*)(wl + off);
      }
      short8 bxh[4], bxl[4];
#pragma unroll
      for (int j = 0; j < 4; j++) {
        int px = j * 16 + lr;
        int row = ((px >> 3) + dy) * 10 + (px & 7) + dx;
        int ci = (sl * 32 + lg * 8) ^ ((row & 7) << 3);
        bxh[j] = *(const short8*)&Xh[row * 64 + ci];
        bxl[j] = *(const short8*)&Xl[row * 64 + ci];
      }
#pragma unroll
      for (int i = 0; i < 2; i++)
#pragma unroll
        for (int j = 0; j < 4; j++) {
          acc[i][j] = __builtin_amdgcn_mfma_f32_16x16x32_bf16(awh[i], bxh[j], acc[i][j], 0, 0, 0);
          acc[i][j] = __builtin_amdgcn_mfma_f32_16x16x32_bf16(awh[i], bxl[j], acc[i][j], 0, 0, 0);
          acc[i][j] = __builtin_amdgcn_mfma_f32_16x16x32_bf16(awl[i], bxh[j], acc[i][j], 0, 0, 0);
          acc[i][j] = __builtin_amdgcn_mfma_f32_16x16x32_bf16(awl[i], bxl[j], acc[i][j], 0, 0, 0);
        }
    }
  }
#pragma unroll
  for (int i = 0; i < 2; i++)
#pragma unroll
    for (int r = 0; r < 4; r++) {
      int co = co_base + i * 16 + lg * 4 + r;
      float s = 0.f, q = 0.f;
#pragma unroll
      for (int j = 0; j < 4; j++) {
        float v = acc[i][j][r];
        outraw[((size_t)b * 128 + co) * 64 + j * 16 + lr] = v;
        s += v; q += v * v;
      }
#pragma unroll
      for (int off = 1; off <= 8; off <<= 1) {
        s += __shfl_xor(s, off, 64);
        q += __shfl_xor(q, off, 64);
      }
      if (lr == 0) { red[2 * co] = s; red[2 * co + 1] = q; }
    }
  __syncthreads();
  for (int i = t; i < 256; i += 256) partials[(size_t)b * 256 + i] = red[i];
}

// ============================================================================
// BN helpers
// ============================================================================
__global__ __launch_bounds__(256) void reduce_partials_kernel(
    const float* __restrict__ partials, int nblk, int Q, double* __restrict__ sums) {
  int q = blockIdx.x;
  double acc = 0.0;
  for (int i = threadIdx.x; i < nblk; i += 256) acc += (double)partials[(size_t)i * Q + q];
  __shared__ double red[256];
  red[threadIdx.x] = acc;
  __syncthreads();
  for (int s = 128; s > 0; s >>= 1) {
    if (threadIdx.x < s) red[threadIdx.x] += red[threadIdx.x + s];
    __syncthreads();
  }
  if (threadIdx.x == 0) sums[q] = red[0];
}

__global__ __launch_bounds__(1024) void col_stats_kernel(
    const float* __restrict__ X, int R, int C, int nch, double* __restrict__ sums) {
  int c0 = blockIdx.x * 64, chunk = blockIdx.y;
  int cl = threadIdx.x & 63, rg = threadIdx.x >> 6;
  int rows = R / nch, rbeg = chunk * rows, rend = rbeg + rows;
  double s = 0.0, sq = 0.0;
  for (int r = rbeg + rg; r < rend; r += 16) {
    float v = X[(size_t)r * C + c0 + cl];
    s += v; sq += (double)v * (double)v;
  }
  __shared__ double red[16][64][2];
  red[rg][cl][0] = s; red[rg][cl][1] = sq;
  __syncthreads();
  if (rg == 0) {
    for (int i = 1; i < 16; i++) { s += red[i][cl][0]; sq += red[i][cl][1]; }
    sums[(size_t)chunk * 2 * C + 2 * (c0 + cl)] = s;
    sums[(size_t)chunk * 2 * C + 2 * (c0 + cl) + 1] = sq;
  }
}

__global__ void bn_finalize_kernel(const double* __restrict__ sums, int nch, int cst2,
                                   const float* __restrict__ g, const float* __restrict__ b,
                                   float* __restrict__ scale, float* __restrict__ shift,
                                   int C, double invN) {
  int c = blockIdx.x * blockDim.x + threadIdx.x;
  if (c >= C) return;
  double s = 0.0, sq = 0.0;
  for (int ch = 0; ch < nch; ch++) {
    s += sums[(size_t)ch * cst2 + 2 * c];
    sq += sums[(size_t)ch * cst2 + 2 * c + 1];
  }
  double m = s * invN;
  double v = sq * invN - m * m;
  double sc = (double)g[c] / sqrt(v + 1e-5);
  scale[c] = (float)sc;
  shift[c] = (float)((double)b[c] - m * sc);
}

template <int LOGHW, int CMASK>
__global__ void bn_relu_vec4_kernel(float* __restrict__ X, const float* __restrict__ scale,
                                    const float* __restrict__ shift, int n4) {
  int i = blockIdx.x * blockDim.x + threadIdx.x;
  if (i >= n4) return;
  int c = ((i << 2) >> LOGHW) & CMASK;
  float4 v = ((float4*)X)[i];
  float sc = scale[c], sh = shift[c];
  v.x = fmaxf(v.x * sc + sh, 0.f);
  v.y = fmaxf(v.y * sc + sh, 0.f);
  v.z = fmaxf(v.z * sc + sh, 0.f);
  v.w = fmaxf(v.w * sc + sh, 0.f);
  ((float4*)X)[i] = v;
}

__global__ void bn_relu_cols4_kernel(float* __restrict__ X, const float* __restrict__ scale,
                                     const float* __restrict__ shift, int n4, int C4) {
  int i = blockIdx.x * blockDim.x + threadIdx.x;
  if (i >= n4) return;
  int c4 = i % C4;
  float4 v = ((float4*)X)[i];
  float4 sc = ((const float4*)scale)[c4];
  float4 sh = ((const float4*)shift)[c4];
  v.x = fmaxf(v.x * sc.x + sh.x, 0.f);
  v.y = fmaxf(v.y * sc.y + sh.y, 0.f);
  v.z = fmaxf(v.z * sc.z + sh.z, 0.f);
  v.w = fmaxf(v.w * sc.w + sh.w, 0.f);
  ((float4*)X)[i] = v;
}

// ============================================================================
// bf16-split MFMA GEMM: C[M,N] = A[M,K]*B[N,K]^T. Tile 128x64, BK=32.
// ============================================================================
__global__ __launch_bounds__(256) void gemm_bf16q_kernel(
    const uint32_t* __restrict__ A, const uint32_t* __restrict__ B,
    float* __restrict__ C, int M, int N, int K) {
  __shared__ short Ah[128 * 32], Al[128 * 32], Bh[64 * 32], Bl[64 * 32];
  const int t = threadIdx.x;
  const int m0 = blockIdx.y << 7, n0 = blockIdx.x << 6;
  const int w = t >> 6, l = t & 63;
  const int wrow = (w >> 1) << 6, wcol = (w & 1) << 5;
  const int lr = l & 15, lg = l >> 4;
  const int ar = t >> 1, akh = (t & 1) << 4;
  const int br = t >> 2, bkh = (t & 3) << 3;
  const int asw = (ar & 3) << 3, bsw = (br & 3) << 3;
  const uint32_t* Ap = A + (size_t)(m0 + ar) * K + akh;
  const uint32_t* Bp = B + (size_t)(n0 + br) * K + bkh;
  f32x4 acc[4][2];
#pragma unroll
  for (int i = 0; i < 4; i++)
#pragma unroll
    for (int j = 0; j < 2; j++) acc[i][j] = (f32x4){0.f, 0.f, 0.f, 0.f};
  uint4 ra0 = *(const uint4*)(Ap + 0), ra1 = *(const uint4*)(Ap + 4);
  uint4 ra2 = *(const uint4*)(Ap + 8), ra3 = *(const uint4*)(Ap + 12);
  uint4 rb0 = *(const uint4*)(Bp + 0), rb1 = *(const uint4*)(Bp + 4);
  const int NS = K >> 5;
  for (int s = 0; s < NS; s++) {
    __syncthreads();
#define STORE_G(ARR_H, ARR_L, ROW, KB, SW, U)                                   \
    {                                                                           \
      uint32_t h0 = (U.x >> 16) | (U.y & 0xffff0000u);                          \
      uint32_t h1 = (U.z >> 16) | (U.w & 0xffff0000u);                          \
      uint32_t l0 = (U.x & 0xffffu) | (U.y << 16);                              \
      uint32_t l1 = (U.z & 0xffffu) | (U.w << 16);                              \
      int idx = (ROW) * 32 + ((KB) ^ (SW));                                     \
      *(uint2*)&ARR_H[idx] = make_uint2(h0, h1);                                \
      *(uint2*)&ARR_L[idx] = make_uint2(l0, l1);                                \
    }
    STORE_G(Ah, Al, ar, akh + 0, asw, ra0)
    STORE_G(Ah, Al, ar, akh + 4, asw, ra1)
    STORE_G(Ah, Al, ar, akh + 8, asw, ra2)
    STORE_G(Ah, Al, ar, akh + 12, asw, ra3)
    STORE_G(Bh, Bl, br, bkh + 0, bsw, rb0)
    STORE_G(Bh, Bl, br, bkh + 4, bsw, rb1)
#undef STORE_G
    __syncthreads();
    if (s + 1 < NS) {
      int ko = (s + 1) << 5;
      ra0 = *(const uint4*)(Ap + ko); ra1 = *(const uint4*)(Ap + ko + 4);
      ra2 = *(const uint4*)(Ap + ko + 8); ra3 = *(const uint4*)(Ap + ko + 12);
      rb0 = *(const uint4*)(Bp + ko); rb1 = *(const uint4*)(Bp + ko + 4);
    }
    short8 ahf[4], alf[4], bhf[2], blf[2];
#pragma unroll
    for (int i = 0; i < 4; i++) {
      int R = wrow + i * 16 + lr;
      int kk = (lg << 3) ^ ((R & 3) << 3);
      ahf[i] = *(const short8*)&Ah[R * 32 + kk];
      alf[i] = *(const short8*)&Al[R * 32 + kk];
    }
#pragma unroll
    for (int j = 0; j < 2; j++) {
      int Cc = wcol + j * 16 + lr;
      int kk = (lg << 3) ^ ((Cc & 3) << 3);
      bhf[j] = *(const short8*)&Bh[Cc * 32 + kk];
      blf[j] = *(const short8*)&Bl[Cc * 32 + kk];
    }
#pragma unroll
    for (int i = 0; i < 4; i++)
#pragma unroll
      for (int j = 0; j < 2; j++) {
        acc[i][j] = __builtin_amdgcn_mfma_f32_16x16x32_bf16(ahf[i], bhf[j], acc[i][j], 0, 0, 0);
        acc[i][j] = __builtin_amdgcn_mfma_f32_16x16x32_bf16(ahf[i], blf[j], acc[i][j], 0, 0, 0);
        acc[i][j] = __builtin_amdgcn_mfma_f32_16x16x32_bf16(alf[i], bhf[j], acc[i][j], 0, 0, 0);
        acc[i][j] = __builtin_amdgcn_mfma_f32_16x16x32_bf16(alf[i], blf[j], acc[i][j], 0, 0, 0);
      }
  }
#pragma unroll
  for (int i = 0; i < 4; i++)
#pragma unroll
    for (int j = 0; j < 2; j++) {
      int n = n0 + wcol + j * 16 + lr;
#pragma unroll
      for (int r = 0; r < 4; r++) {
        int m = m0 + wrow + i * 16 + lg * 4 + r;
        C[(size_t)m * N + n] = acc[i][j][r];
      }
    }
}

// ============================================================================
// fp32 64x64 GEMM NT (small-N duty): C = A*B^T (+bias, relu). Padded LDS.
// ============================================================================
template <int BIASRELU>
__global__ __launch_bounds__(256) void gemm_nt_kernel(
    const float* __restrict__ A, const float* __restrict__ B,
    const float* __restrict__ bias, float* __restrict__ C, int M, int N, int K) {
  __shared__ float As[16][68];
  __shared__ float Bs[16][68];
  const int t = threadIdx.x;
  const int tn = t & 15, tm = t >> 4;
  const int m0 = blockIdx.y << 6, n0 = blockIdx.x << 6;
  const int lr = t >> 2, lk = (t & 3) << 2;
  const float* Ap = A + (size_t)(m0 + lr) * K + lk;
  const float* Bp = B + (size_t)(n0 + lr) * K + lk;
  float acc[4][4];
#pragma unroll
  for (int i = 0; i < 4; i++)
#pragma unroll
    for (int j = 0; j < 4; j++) acc[i][j] = 0.f;
  for (int k0 = 0; k0 < K; k0 += 16) {
    float4 av = *(const float4*)(Ap + k0);
    float4 bv = *(const float4*)(Bp + k0);
    __syncthreads();
    As[lk + 0][lr] = av.x; As[lk + 1][lr] = av.y; As[lk + 2][lr] = av.z; As[lk + 3][lr] = av.w;
    Bs[lk + 0][lr] = bv.x; Bs[lk + 1][lr] = bv.y; Bs[lk + 2][lr] = bv.z; Bs[lk + 3][lr] = bv.w;
    __syncthreads();
#pragma unroll
    for (int kk = 0; kk < 16; kk++) {
      float4 a4 = *(const float4*)&As[kk][tm << 2];
      float4 b4 = *(const float4*)&Bs[kk][tn << 2];
      acc[0][0] += a4.x * b4.x; acc[0][1] += a4.x * b4.y; acc[0][2] += a4.x * b4.z; acc[0][3] += a4.x * b4.w;
      acc[1][0] += a4.y * b4.x; acc[1][1] += a4.y * b4.y; acc[1][2] += a4.y * b4.z; acc[1][3] += a4.y * b4.w;
      acc[2][0] += a4.z * b4.x; acc[2][1] += a4.z * b4.y; acc[2][2] += a4.z * b4.z; acc[2][3] += a4.z * b4.w;
      acc[3][0] += a4.w * b4.x; acc[3][1] += a4.w * b4.y; acc[3][2] += a4.w * b4.z; acc[3][3] += a4.w * b4.w;
    }
  }
#pragma unroll
  for (int i = 0; i < 4; i++) {
    int m = m0 + (tm << 2) + i;
    float4 o;
    float v0 = acc[i][0], v1 = acc[i][1], v2 = acc[i][2], v3 = acc[i][3];
    if (BIASRELU) {
      int nb = n0 + (tn << 2);
      v0 = fmaxf(v0 + bias[nb + 0], 0.f);
      v1 = fmaxf(v1 + bias[nb + 1], 0.f);
      v2 = fmaxf(v2 + bias[nb + 2], 0.f);
      v3 = fmaxf(v3 + bias[nb + 3], 0.f);
    }
    o.x = v0; o.y = v1; o.z = v2; o.w = v3;
    *(float4*)&C[(size_t)m * N + n0 + (tn << 2)] = o;
  }
}

// ============================================================================
// heads (double accumulation; sw_logits amplified 10x by TAU)
// ============================================================================
__global__ __launch_bounds__(256) void heads_kernel(
    const float* __restrict__ dpen, const float* __restrict__ dfc_w,
    const float* __restrict__ dfc_b, const float* __restrict__ sw_w,
    const float* __restrict__ sw_b, float* __restrict__ out_dom,
    float* __restrict__ swbuf) {
  int t = blockIdx.x * 256 + threadIdx.x;
  int b = t >> 2, j = t & 3;
  const float* row = dpen + (size_t)b * 384;
  const float* wr = (j < 2) ? (dfc_w + j * 384) : (sw_w + (j - 2) * 384);
  double s = 0.0;
  for (int k = 0; k < 384; k++) s += (double)row[k] * (double)wr[k];
  s += (double)((j < 2) ? dfc_b[j] : sw_b[j - 2]);
  if (j < 2) out_dom[b * 2 + j] = (float)s;
  else swbuf[b * 2 + (j - 2)] = (float)s;
}

// ============================================================================
// gumbel-softmax + categorical partition choice (threefry partitionable).
// ============================================================================
__global__ __launch_bounds__(256) void partition_kernel(
    const float* __restrict__ swbuf, float* __restrict__ out_pid,
    int* __restrict__ pidxI, float* __restrict__ ysum,
    uint32_t k1a, uint32_t k1b, uint32_t k2a, uint32_t k2b) {
  int b = blockIdx.x * 256 + threadIdx.x;
  if (b >= 4096) return;
  uint32_t j0 = (uint32_t)(2 * b), j1 = (uint32_t)(2 * b + 1);
  float f0 = u01_from_bits(tf_bits32(k1a, k1b, j0));
  float f1 = u01_from_bits(tf_bits32(k1a, k1b, j1));
  const float MINV = 1e-10f;
  float u0 = fmaxf(MINV, f0 * (1.0f - MINV) + MINV);
  float u1 = fmaxf(MINV, f1 * (1.0f - MINV) + MINV);
  double g0 = -log(-log((double)u0));
  double g1 = -log(-log((double)u1));
  double s0 = (double)swbuf[2 * b], s1 = (double)swbuf[2 * b + 1];
  double x0 = (s0 + g0) / 0.1;
  double x1 = (s1 + g1) / 0.1;
  double mx = fmax(x0, x1);
  double e0 = exp(x0 - mx), e1 = exp(x1 - mx);
  double es = e0 + e1;
  double y0 = e0 / es, y1 = e1 / es;
  float h0 = u01_from_bits(tf_bits32(k2a, k2b, j0));
  float h1 = u01_from_bits(tf_bits32(k2a, k2b, j1));
  const float TINY = 1.17549435e-38f;
  float v0 = fmaxf(TINY, h0 * (1.0f - TINY) + TINY);
  float v1 = fmaxf(TINY, h1 * (1.0f - TINY) + TINY);
  double gg0 = -log(-log((double)v0));
  double gg1 = -log(-log((double)v1));
  double l0 = log(y0 + 1e-20) + gg0;
  double l1 = log(y1 + 1e-20) + gg1;
  int p = (l1 > l0) ? 1 : 0;
  out_pid[b] = (float)p;
  pidxI[b] = p;
  ysum[b] = (float)(y0 + y1);
}

// ============================================================================
// final head
// ============================================================================
__global__ __launch_bounds__(256) void final_kernel(
    const float* __restrict__ h, const float* __restrict__ p2w,
    const float* __restrict__ p2b, const int* __restrict__ pidxI,
    const float* __restrict__ ysum, float* __restrict__ out0) {
  int t = blockIdx.x * 256 + threadIdx.x;
  if (t >= 40960) return;
  int b = t / 10, c = t % 10;
  int p = pidxI[b];
  const float* hr = h + (size_t)b * 384 + p * 192;
  const float* wr = p2w + ((size_t)p * 10 + c) * 192;
  float s = 0.f;
  for (int o = 0; o < 192; o++) s += hr[o] * wr[o];
  s += p2b[p * 10 + c];
  out0[t] = s * ysum[b];
}

// ============================================================================
// Launch orchestration. MFMA conv2+conv3+pre-FC. ~235 MB ws (proven).
// ============================================================================
extern "C" void kernel_launch(void* const* d_in, const int* in_sizes, int n_in,
                              void* d_out, int out_size, void* d_ws, size_t ws_size,
                              hipStream_t stream) {
  const float* input   = (const float*)d_in[0];
  const float* conv1_w = (const float*)d_in[1];
  const float* bn1_g   = (const float*)d_in[3];
  const float* bn1_b   = (const float*)d_in[4];
  const float* conv2_w = (const float*)d_in[5];
  const float* bn2_g   = (const float*)d_in[7];
  const float* bn2_b   = (const float*)d_in[8];
  const float* conv3_w = (const float*)d_in[9];
  const float* bn3_g   = (const float*)d_in[11];
  const float* bn3_b   = (const float*)d_in[12];
  const float* pre_w   = (const float*)d_in[13];
  const float* bnp_g   = (const float*)d_in[15];
  const float* bnp_b   = (const float*)d_in[16];
  const float* disc_w  = (const float*)d_in[17];
  const float* bnd_g   = (const float*)d_in[19];
  const float* bnd_b   = (const float*)d_in[20];
  const float* dfc_w   = (const float*)d_in[21];
  const float* dfc_b   = (const float*)d_in[22];
  const float* sw_w    = (const float*)d_in[23];
  const float* sw_b    = (const float*)d_in[24];
  const float* p1_w    = (const float*)d_in[25];
  const float* p1_b    = (const float*)d_in[26];
  const float* p2_w    = (const float*)d_in[27];
  const float* p2_b    = (const float*)d_in[28];

  float* W = (float*)d_ws;
  float* pool1  = W + 0;           // [4096][32][16][16], fp32 -> packed in place
  uint32_t* pool1q = (uint32_t*)pool1;
  float* pool2  = W + 33554432;    // [4096][64][8][8], fp32 -> packed in place
  uint32_t* pool2q = (uint32_t*)pool2;
  float* act3   = W + 0;           // [4096][128][8][8], alias pool1 (dead)
  uint32_t* Acvt = (uint32_t*)(W + 0);         // act3 packed in place
  uint32_t* Bcvt = (uint32_t*)(W + 33554432);  // pre_w packed (pool2q dead then)
  float* featp  = W + 50331648;    // [4096][1024]
  short* wh3    = (short*)(W + 50331648);      // conv3 weights hi (featp region,
  short* wl3    = (short*)(W + 50368512);      //  dead until pre-FC gemm writes)
  short* wh2    = (short*)(W + 50405376);      // conv2 weights hi (9*64*32)
  short* wl2    = (short*)(W + 50414592);      // conv2 weights lo
  float* dpen   = W + 54525952;
  float* hbuf   = W + 56098816;
  float* swbuf  = W + 57671680;
  float* ysum   = W + 57679872;
  int*   pidxI  = (int*)(W + 57683968);
  float* part   = W + 57688064;
  double* sums  = (double*)(W + 58736640);
  float* scale  = W + 58769408;
  float* shift  = W + 58770432;

  float* out_cls = (float*)d_out;
  float* out_dom = out_cls + 40960;
  float* out_pid = out_cls + 49152;

  uint32_t k1a, k1b, k2a, k2b;
  threefry2x32(0u, 42u, 0u, 0u, k1a, k1b);
  threefry2x32(0u, 42u, 0u, 1u, k2a, k2b);

  // --- conv1 fused + BN ---
  conv1_fused_kernel<<<dim3(4096), dim3(256), 0, stream>>>(input, conv1_w, pool1, part);
  reduce_partials_kernel<<<dim3(64), dim3(256), 0, stream>>>(part, 4096, 64, sums);
  bn_finalize_kernel<<<dim3(1), dim3(64), 0, stream>>>(sums, 1, 0, bn1_g, bn1_b, scale, shift, 32, 1.0 / (4096.0 * 1024.0));
  bn_relu_vec4_kernel<8, 31><<<dim3(32768), dim3(256), 0, stream>>>(pool1, scale, shift, 8388608);

  // --- conv2 via MFMA implicit GEMM (fused pool) + BN ---
  cvt_bf16q_kernel<<<dim3(32768), dim3(256), 0, stream>>>(pool1, pool1q, 8388608);
  prep_w2_kernel<<<dim3(72), dim3(256), 0, stream>>>(conv2_w, wh2, wl2);
  conv2_mfma_kernel<<<dim3(4096), dim3(256), 0, stream>>>(pool1q, wh2, wl2, pool2, part);
  reduce_partials_kernel<<<dim3(128), dim3(256), 0, stream>>>(part, 4096, 128, sums);
  bn_finalize_kernel<<<dim3(1), dim3(64), 0, stream>>>(sums, 1, 0, bn2_g, bn2_b, scale, shift, 64, 1.0 / (4096.0 * 256.0));
  bn_relu_vec4_kernel<6, 63><<<dim3(16384), dim3(256), 0, stream>>>(pool2, scale, shift, 4194304);

  // --- conv3 via MFMA implicit GEMM + BN ---
  cvt_bf16q_kernel<<<dim3(16384), dim3(256), 0, stream>>>(pool2, pool2q, 4194304);
  prep_w3_kernel<<<dim3(288), dim3(256), 0, stream>>>(conv3_w, wh3, wl3);
  conv3_mfma_kernel<<<dim3(4096), dim3(256), 0, stream>>>(pool2q, wh3, wl3, act3, part);
  reduce_partials_kernel<<<dim3(256), dim3(256), 0, stream>>>(part, 4096, 256, sums);
  bn_finalize_kernel<<<dim3(1), dim3(128), 0, stream>>>(sums, 1, 0, bn3_g, bn3_b, scale, shift, 128, 1.0 / (4096.0 * 64.0));
  bn_relu_vec4_kernel<6, 127><<<dim3(32768), dim3(256), 0, stream>>>(act3, scale, shift, 8388608);

  // --- convert act3 (in-place) and pre_w to packed bf16-split ---
  cvt_bf16q_kernel<<<dim3(32768), dim3(256), 0, stream>>>(act3, Acvt, 8388608);
  cvt_bf16q_kernel<<<dim3(8192), dim3(256), 0, stream>>>(pre_w, Bcvt, 2097152);

  // --- pre FC 8192->1024 via bf16-split MFMA + BN + ReLU ---
  gemm_bf16q_kernel<<<dim3(16, 32), dim3(256), 0, stream>>>(Acvt, Bcvt, featp, 4096, 1024, 8192);
  col_stats_kernel<<<dim3(16, 8), dim3(1024), 0, stream>>>(featp, 4096, 1024, 8, sums);
  bn_finalize_kernel<<<dim3(4), dim3(256), 0, stream>>>(sums, 8, 2048, bnp_g, bnp_b, scale, shift, 1024, 1.0 / 4096.0);
  bn_relu_cols4_kernel<<<dim3(4096), dim3(256), 0, stream>>>(featp, scale, shift, 1048576, 256);

  // --- disc FC 1024->384 + BN + ReLU ---
  gemm_nt_kernel<0><<<dim3(6, 64), dim3(256), 0, stream>>>(featp, disc_w, (const float*)nullptr, dpen, 4096, 384, 1024);
  col_stats_kernel<<<dim3(6, 8), dim3(1024), 0, stream>>>(dpen, 4096, 384, 8, sums);
  bn_finalize_kernel<<<dim3(2), dim3(256), 0, stream>>>(sums, 8, 768, bnd_g, bnd_b, scale, shift, 384, 1.0 / 4096.0);
  bn_relu_cols4_kernel<<<dim3(1536), dim3(256), 0, stream>>>(dpen, scale, shift, 393216, 96);

  // --- heads + partition sampling ---
  heads_kernel<<<dim3(64), dim3(256), 0, stream>>>(dpen, dfc_w, dfc_b, sw_w, sw_b, out_dom, swbuf);
  partition_kernel<<<dim3(16), dim3(256), 0, stream>>>(swbuf, out_pid, pidxI, ysum, k1a, k1b, k2a, k2b);

  // --- experts: dense p1, then gather + p2 ---
  gemm_nt_kernel<1><<<dim3(6, 64), dim3(256), 0, stream>>>(featp, p1_w, p1_b, hbuf, 4096, 384, 1024);
  final_kernel<<<dim3(160), dim3(256), 0, stream>>>(hbuf, p2_w, p2_b, pidxI, ysum, out_cls);
}

// Round 10
// 1025.612 us; speedup vs baseline: 6.0770x; 1.2014x over previous
//
#include <hip/hip_runtime.h>
#include <cstdint>
#include <cstddef>

typedef __attribute__((ext_vector_type(8))) short short8;    // 8 bf16 (4 VGPR)
typedef __attribute__((ext_vector_type(4))) float f32x4;     // MFMA acc

// ============================================================================
// Threefry2x32 (matches jax._src.prng.threefry2x32).
// ============================================================================
__host__ __device__ inline void threefry2x32(uint32_t k0, uint32_t k1,
                                             uint32_t x0, uint32_t x1,
                                             uint32_t& o0, uint32_t& o1) {
  uint32_t ks2 = k0 ^ k1 ^ 0x1BD11BDAu;
  uint32_t v0 = x0 + k0, v1 = x1 + k1;
#define TF_R(r) { v0 += v1; v1 = (v1 << (r)) | (v1 >> (32 - (r))); v1 ^= v0; }
  TF_R(13) TF_R(15) TF_R(26) TF_R(6)
  v0 += k1; v1 += ks2 + 1u;
  TF_R(17) TF_R(29) TF_R(16) TF_R(24)
  v0 += ks2; v1 += k0 + 2u;
  TF_R(13) TF_R(15) TF_R(26) TF_R(6)
  v0 += k0; v1 += k1 + 3u;
  TF_R(17) TF_R(29) TF_R(16) TF_R(24)
  v0 += k1; v1 += ks2 + 4u;
  TF_R(13) TF_R(15) TF_R(26) TF_R(6)
  v0 += ks2; v1 += k0 + 5u;
#undef TF_R
  o0 = v0; o1 = v1;
}

__device__ __forceinline__ uint32_t tf_bits32(uint32_t k0, uint32_t k1, uint32_t j) {
  uint32_t o0, o1;
  threefry2x32(k0, k1, 0u, j, o0, o1);
  return o0 ^ o1;
}

__device__ __forceinline__ float u01_from_bits(uint32_t bits) {
  return __uint_as_float((bits >> 9) | 0x3f800000u) - 1.0f;  // [0,1)
}

__device__ __forceinline__ float waveSum(float v) {
#pragma unroll
  for (int off = 32; off > 0; off >>= 1) v += __shfl_down(v, off, 64);
  return v;
}

// ============================================================================
// conv1 fused: conv(3->32) + BN partials (unpooled) + RAW 2x2 maxpool store.
// ============================================================================
__global__ __launch_bounds__(256) void conv1_fused_kernel(
    const float* __restrict__ in, const float* __restrict__ w,
    float* __restrict__ outraw, float* __restrict__ partials) {
  __shared__ float ins[3 * 34 * 34];
  __shared__ float red[4][64];
  const int b = blockIdx.x, t = threadIdx.x;
  for (int i = t; i < 3 * 34 * 34; i += 256) {
    int ci = i / 1156, r = i % 1156, iy = r / 34, ix = r % 34;
    int y = iy - 1, x = ix - 1;
    float v = 0.f;
    if ((unsigned)y < 32u && (unsigned)x < 32u)
      v = in[(((size_t)b * 3 + ci) * 32 + y) * 32 + x];
    ins[i] = v;
  }
  __syncthreads();
  const int py = t >> 4, px = t & 15, wv = t >> 6, ln = t & 63;
  float win[3][4][4];
#pragma unroll
  for (int ci = 0; ci < 3; ci++)
#pragma unroll
    for (int r = 0; r < 4; r++)
#pragma unroll
      for (int c = 0; c < 4; c++)
        win[ci][r][c] = ins[ci * 1156 + (2 * py + r) * 34 + (2 * px + c)];
#pragma unroll 1
  for (int co = 0; co < 32; co++) {
    float acc00 = 0.f, acc01 = 0.f, acc10 = 0.f, acc11 = 0.f;
#pragma unroll
    for (int ci = 0; ci < 3; ci++) {
      const float* wp = w + (co * 3 + ci) * 9;  // wave-uniform -> s_load
#pragma unroll
      for (int dy = 0; dy < 3; dy++)
#pragma unroll
        for (int dx = 0; dx < 3; dx++) {
          float wvv = wp[dy * 3 + dx];
          acc00 += win[ci][dy][dx] * wvv;
          acc01 += win[ci][dy][dx + 1] * wvv;
          acc10 += win[ci][dy + 1][dx] * wvv;
          acc11 += win[ci][dy + 1][dx + 1] * wvv;
        }
    }
    float sm = acc00 + acc01 + acc10 + acc11;
    float sq = acc00 * acc00 + acc01 * acc01 + acc10 * acc10 + acc11 * acc11;
    float s = waveSum(sm), q = waveSum(sq);
    if (ln == 0) { red[wv][2 * co] = s; red[wv][2 * co + 1] = q; }
    float m = fmaxf(fmaxf(acc00, acc01), fmaxf(acc10, acc11));  // RAW max
    outraw[(((size_t)b * 32 + co) * 16 + py) * 16 + px] = m;
  }
  __syncthreads();
  for (int i = t; i < 64; i += 256)
    partials[(size_t)b * 64 + i] = red[0][i] + red[1][i] + red[2][i] + red[3][i];
}

// ============================================================================
// bf16-split helpers
// ============================================================================
__device__ __forceinline__ uint32_t pack_bf16q(float x) {
  uint32_t u = __float_as_uint(x);
  uint32_t hi = (u + 0x7fffu + ((u >> 16) & 1u)) & 0xffff0000u;
  float r = x - __uint_as_float(hi);
  uint32_t v = __float_as_uint(r);
  uint32_t lo = (v + 0x7fffu + ((v >> 16) & 1u)) >> 16;
  return hi | lo;
}

__global__ void cvt_bf16q_kernel(const float* X, uint32_t* Y, int n4) {
  int i = blockIdx.x * blockDim.x + threadIdx.x;
  if (i >= n4) return;
  float4 x = ((const float4*)X)[i];
  uint4 o;
  o.x = pack_bf16q(x.x); o.y = pack_bf16q(x.y);
  o.z = pack_bf16q(x.z); o.w = pack_bf16q(x.w);
  ((uint4*)Y)[i] = o;
}

// conv2 weight prepack: w [64][32][9] fp32 -> wh/wl [9][64][32] bf16 planes.
__global__ void prep_w2_kernel(const float* __restrict__ w, short* __restrict__ wh,
                               short* __restrict__ wl) {
  int idx = blockIdx.x * 256 + threadIdx.x;
  if (idx >= 64 * 32 * 9) return;
  int tp = idx % 9, rem = idx / 9;
  int ci = rem % 32, co = rem / 32;
  uint32_t pq = pack_bf16q(w[idx]);
  size_t o = ((size_t)tp * 64 + co) * 32 + ci;
  wh[o] = (short)(pq >> 16);
  wl[o] = (short)(pq & 0xffffu);
}

// conv3 weight prepack: w [128][64][9] fp32 -> wh/wl [9][128][64] bf16 planes.
__global__ void prep_w3_kernel(const float* __restrict__ w, short* __restrict__ wh,
                               short* __restrict__ wl) {
  int idx = blockIdx.x * 256 + threadIdx.x;
  if (idx >= 128 * 64 * 9) return;
  int tp = idx % 9, rem = idx / 9;
  int ci = rem % 64, co = rem / 64;
  uint32_t pq = pack_bf16q(w[idx]);
  size_t o = ((size_t)tp * 128 + co) * 64 + ci;
  wh[o] = (short)(pq >> 16);
  wl[o] = (short)(pq & 0xffffu);
}

// ============================================================================
// conv2 via MFMA implicit GEMM (bf16-split, 3 terms).
// ============================================================================
__global__ __launch_bounds__(256) void conv2_mfma_kernel(
    const uint32_t* __restrict__ inq, const short* __restrict__ wh,
    const short* __restrict__ wl, float* __restrict__ outpool,
    float* __restrict__ partials) {
  __shared__ short Xh[324 * 32], Xl[324 * 32];
  __shared__ float red[4][128];
  const int b = blockIdx.x, t = threadIdx.x;
  for (int i = t; i < 324 * 16; i += 256) {
    int row = i >> 4;
    int py = row / 18, pxx = row % 18;
    if (py == 0 || py == 17 || pxx == 0 || pxx == 17) {
      ((uint32_t*)Xh)[i] = 0u;
      ((uint32_t*)Xl)[i] = 0u;
    }
  }
  for (int i = t; i < 4096; i += 256) {
    int p = i >> 8, px = i & 255;
    int y = px >> 4, x = px & 15;
    uint32_t ua = inq[((size_t)b * 32 + 2 * p) * 256 + px];
    uint32_t ub = inq[((size_t)b * 32 + 2 * p + 1) * 256 + px];
    uint32_t h = (ua >> 16) | (ub & 0xffff0000u);
    uint32_t l = (ua & 0xffffu) | (ub << 16);
    int row = (y + 1) * 18 + (x + 1);
    int ci2 = (2 * p) ^ ((row & 3) << 3);  // swizzled, stays even
    ((uint32_t*)Xh)[(row * 32 + ci2) >> 1] = h;
    ((uint32_t*)Xl)[(row * 32 + ci2) >> 1] = l;
  }
  __syncthreads();
  const int w = t >> 6, l = t & 63;
  const int lr = l & 15, lg = l >> 4;
  f32x4 acc[4][4];  // [co block][px block]
#pragma unroll
  for (int i = 0; i < 4; i++)
#pragma unroll
    for (int j = 0; j < 4; j++) acc[i][j] = (f32x4){0.f, 0.f, 0.f, 0.f};
#pragma unroll 1
  for (int tap = 0; tap < 9; tap++) {
    const int dy = tap / 3, dx = tap % 3;
    short8 awh[4], awl[4];
#pragma unroll
    for (int i = 0; i < 4; i++) {
      size_t off = ((size_t)tap * 64 + i * 16 + lr) * 32 + lg * 8;
      awh[i] = *(const short8*)(wh + off);
      awl[i] = *(const short8*)(wl + off);
    }
    short8 bxh[4], bxl[4];
#pragma unroll
    for (int j = 0; j < 4; j++) {
      int y = w * 4 + j, x = lr;
      int row = (y + dy) * 18 + (x + dx);
      int ci = (lg * 8) ^ ((row & 3) << 3);
      bxh[j] = *(const short8*)&Xh[row * 32 + ci];
      bxl[j] = *(const short8*)&Xl[row * 32 + ci];
    }
#pragma unroll
    for (int i = 0; i < 4; i++)
#pragma unroll
      for (int j = 0; j < 4; j++) {
        acc[i][j] = __builtin_amdgcn_mfma_f32_16x16x32_bf16(awh[i], bxh[j], acc[i][j], 0, 0, 0);
        acc[i][j] = __builtin_amdgcn_mfma_f32_16x16x32_bf16(awh[i], bxl[j], acc[i][j], 0, 0, 0);
        acc[i][j] = __builtin_amdgcn_mfma_f32_16x16x32_bf16(awl[i], bxh[j], acc[i][j], 0, 0, 0);
      }
  }
#pragma unroll
  for (int i = 0; i < 4; i++)
#pragma unroll
    for (int r = 0; r < 4; r++) {
      int co = i * 16 + lg * 4 + r;
      float v0 = acc[i][0][r], v1 = acc[i][1][r], v2 = acc[i][2][r], v3 = acc[i][3][r];
      float s = v0 + v1 + v2 + v3;
      float q = v0 * v0 + v1 * v1 + v2 * v2 + v3 * v3;
#pragma unroll
      for (int off = 1; off <= 8; off <<= 1) {
        s += __shfl_xor(s, off, 64);
        q += __shfl_xor(q, off, 64);
      }
      if (lr == 0) { red[w][2 * co] = s; red[w][2 * co + 1] = q; }
      float h0 = fmaxf(v0, __shfl_xor(v0, 1, 64));
      float h1 = fmaxf(v1, __shfl_xor(v1, 1, 64));
      float h2 = fmaxf(v2, __shfl_xor(v2, 1, 64));
      float h3 = fmaxf(v3, __shfl_xor(v3, 1, 64));
      float pm0 = fmaxf(h0, h1);
      float pm1 = fmaxf(h2, h3);
      if ((lr & 1) == 0) {
        size_t base = ((size_t)b * 64 + co) * 64 + (w * 2) * 8 + (lr >> 1);
        outpool[base] = pm0;
        outpool[base + 8] = pm1;
      }
    }
  __syncthreads();
  for (int i = t; i < 128; i += 256)
    partials[(size_t)b * 128 + i] = red[0][i] + red[1][i] + red[2][i] + red[3][i];
}

// ============================================================================
// conv3 via MFMA implicit GEMM (bf16-split, 3 terms).
// ============================================================================
__global__ __launch_bounds__(256) void conv3_mfma_kernel(
    const uint32_t* __restrict__ inq, const short* __restrict__ wh,
    const short* __restrict__ wl, float* __restrict__ outraw,
    float* __restrict__ partials) {
  __shared__ short Xh[100 * 64], Xl[100 * 64];
  __shared__ float red[256];
  const int b = blockIdx.x, t = threadIdx.x;
  for (int i = t; i < 100 * 32; i += 256) {
    int row = i >> 5;
    int py = row / 10, pxx = row % 10;
    if (py == 0 || py == 9 || pxx == 0 || pxx == 9) {
      ((uint32_t*)Xh)[i] = 0u;
      ((uint32_t*)Xl)[i] = 0u;
    }
  }
  for (int i = t; i < 2048; i += 256) {
    int p = i >> 6, px = i & 63;
    int y = px >> 3, x = px & 7;
    uint32_t ua = inq[((size_t)b * 64 + 2 * p) * 64 + px];
    uint32_t ub = inq[((size_t)b * 64 + 2 * p + 1) * 64 + px];
    uint32_t h = (ua >> 16) | (ub & 0xffff0000u);
    uint32_t l = (ua & 0xffffu) | (ub << 16);
    int row = (y + 1) * 10 + (x + 1);
    int ci2 = (2 * p) ^ ((row & 7) << 3);
    ((uint32_t*)Xh)[(row * 64 + ci2) >> 1] = h;
    ((uint32_t*)Xl)[(row * 64 + ci2) >> 1] = l;
  }
  __syncthreads();
  const int w = t >> 6, l = t & 63;
  const int lr = l & 15, lg = l >> 4;
  const int co_base = w * 32;
  f32x4 acc[2][4];
#pragma unroll
  for (int i = 0; i < 2; i++)
#pragma unroll
    for (int j = 0; j < 4; j++) acc[i][j] = (f32x4){0.f, 0.f, 0.f, 0.f};
#pragma unroll 1
  for (int tap = 0; tap < 9; tap++) {
    const int dy = tap / 3, dx = tap % 3;
#pragma unroll
    for (int sl = 0; sl < 2; sl++) {
      short8 awh[2], awl[2];
#pragma unroll
      for (int i = 0; i < 2; i++) {
        size_t off = ((size_t)tap * 128 + co_base + i * 16 + lr) * 64 + sl * 32 + lg * 8;
        awh[i] = *(const short8*)(wh + off);
        awl[i] = *(const short8*)(wl + off);
      }
      short8 bxh[4], bxl[4];
#pragma unroll
      for (int j = 0; j < 4; j++) {
        int px = j * 16 + lr;
        int row = ((px >> 3) + dy) * 10 + (px & 7) + dx;
        int ci = (sl * 32 + lg * 8) ^ ((row & 7) << 3);
        bxh[j] = *(const short8*)&Xh[row * 64 + ci];
        bxl[j] = *(const short8*)&Xl[row * 64 + ci];
      }
#pragma unroll
      for (int i = 0; i < 2; i++)
#pragma unroll
        for (int j = 0; j < 4; j++) {
          acc[i][j] = __builtin_amdgcn_mfma_f32_16x16x32_bf16(awh[i], bxh[j], acc[i][j], 0, 0, 0);
          acc[i][j] = __builtin_amdgcn_mfma_f32_16x16x32_bf16(awh[i], bxl[j], acc[i][j], 0, 0, 0);
          acc[i][j] = __builtin_amdgcn_mfma_f32_16x16x32_bf16(awl[i], bxh[j], acc[i][j], 0, 0, 0);
        }
    }
  }
#pragma unroll
  for (int i = 0; i < 2; i++)
#pragma unroll
    for (int r = 0; r < 4; r++) {
      int co = co_base + i * 16 + lg * 4 + r;
      float s = 0.f, q = 0.f;
#pragma unroll
      for (int j = 0; j < 4; j++) {
        float v = acc[i][j][r];
        outraw[((size_t)b * 128 + co) * 64 + j * 16 + lr] = v;
        s += v; q += v * v;
      }
#pragma unroll
      for (int off = 1; off <= 8; off <<= 1) {
        s += __shfl_xor(s, off, 64);
        q += __shfl_xor(q, off, 64);
      }
      if (lr == 0) { red[2 * co] = s; red[2 * co + 1] = q; }
    }
  __syncthreads();
  for (int i = t; i < 256; i += 256) partials[(size_t)b * 256 + i] = red[i];
}

// ============================================================================
// BN helpers
// ============================================================================
__global__ __launch_bounds__(256) void reduce_partials_kernel(
    const float* __restrict__ partials, int nblk, int Q, double* __restrict__ sums) {
  int q = blockIdx.x;
  double acc = 0.0;
  for (int i = threadIdx.x; i < nblk; i += 256) acc += (double)partials[(size_t)i * Q + q];
  __shared__ double red[256];
  red[threadIdx.x] = acc;
  __syncthreads();
  for (int s = 128; s > 0; s >>= 1) {
    if (threadIdx.x < s) red[threadIdx.x] += red[threadIdx.x + s];
    __syncthreads();
  }
  if (threadIdx.x == 0) sums[q] = red[0];
}

__global__ __launch_bounds__(1024) void col_stats_kernel(
    const float* __restrict__ X, int R, int C, int nch, double* __restrict__ sums) {
  int c0 = blockIdx.x * 64, chunk = blockIdx.y;
  int cl = threadIdx.x & 63, rg = threadIdx.x >> 6;
  int rows = R / nch, rbeg = chunk * rows, rend = rbeg + rows;
  double s = 0.0, sq = 0.0;
  for (int r = rbeg + rg; r < rend; r += 16) {
    float v = X[(size_t)r * C + c0 + cl];
    s += v; sq += (double)v * (double)v;
  }
  __shared__ double red[16][64][2];
  red[rg][cl][0] = s; red[rg][cl][1] = sq;
  __syncthreads();
  if (rg == 0) {
    for (int i = 1; i < 16; i++) { s += red[i][cl][0]; sq += red[i][cl][1]; }
    sums[(size_t)chunk * 2 * C + 2 * (c0 + cl)] = s;
    sums[(size_t)chunk * 2 * C + 2 * (c0 + cl) + 1] = sq;
  }
}

__global__ void bn_finalize_kernel(const double* __restrict__ sums, int nch, int cst2,
                                   const float* __restrict__ g, const float* __restrict__ b,
                                   float* __restrict__ scale, float* __restrict__ shift,
                                   int C, double invN) {
  int c = blockIdx.x * blockDim.x + threadIdx.x;
  if (c >= C) return;
  double s = 0.0, sq = 0.0;
  for (int ch = 0; ch < nch; ch++) {
    s += sums[(size_t)ch * cst2 + 2 * c];
    sq += sums[(size_t)ch * cst2 + 2 * c + 1];
  }
  double m = s * invN;
  double v = sq * invN - m * m;
  double sc = (double)g[c] / sqrt(v + 1e-5);
  scale[c] = (float)sc;
  shift[c] = (float)((double)b[c] - m * sc);
}

// BN+ReLU+bf16q-pack fused, NCHW layout, in place (fp32 -> packed u32).
template <int LOGHW, int CMASK>
__global__ void bn_relu_pack_vec4_kernel(float* __restrict__ X,
                                         const float* __restrict__ scale,
                                         const float* __restrict__ shift, int n4) {
  int i = blockIdx.x * blockDim.x + threadIdx.x;
  if (i >= n4) return;
  int c = ((i << 2) >> LOGHW) & CMASK;
  float4 v = ((float4*)X)[i];
  float sc = scale[c], sh = shift[c];
  uint4 o;
  o.x = pack_bf16q(fmaxf(v.x * sc + sh, 0.f));
  o.y = pack_bf16q(fmaxf(v.y * sc + sh, 0.f));
  o.z = pack_bf16q(fmaxf(v.z * sc + sh, 0.f));
  o.w = pack_bf16q(fmaxf(v.w * sc + sh, 0.f));
  ((uint4*)X)[i] = o;
}

// BN+ReLU+pack for [R][C] row-major, in place. C4 = C/4.
__global__ void bn_relu_pack_cols4_kernel(float* __restrict__ X,
                                          const float* __restrict__ scale,
                                          const float* __restrict__ shift,
                                          int n4, int C4) {
  int i = blockIdx.x * blockDim.x + threadIdx.x;
  if (i >= n4) return;
  int c4 = i % C4;
  float4 v = ((float4*)X)[i];
  float4 sc = ((const float4*)scale)[c4];
  float4 sh = ((const float4*)shift)[c4];
  uint4 o;
  o.x = pack_bf16q(fmaxf(v.x * sc.x + sh.x, 0.f));
  o.y = pack_bf16q(fmaxf(v.y * sc.y + sh.y, 0.f));
  o.z = pack_bf16q(fmaxf(v.z * sc.z + sh.z, 0.f));
  o.w = pack_bf16q(fmaxf(v.w * sc.w + sh.w, 0.f));
  ((uint4*)X)[i] = o;
}

// BN+ReLU (fp32 out) for [R][C] row-major, in place. C4 = C/4.
__global__ void bn_relu_cols4_kernel(float* __restrict__ X, const float* __restrict__ scale,
                                     const float* __restrict__ shift, int n4, int C4) {
  int i = blockIdx.x * blockDim.x + threadIdx.x;
  if (i >= n4) return;
  int c4 = i % C4;
  float4 v = ((float4*)X)[i];
  float4 sc = ((const float4*)scale)[c4];
  float4 sh = ((const float4*)shift)[c4];
  v.x = fmaxf(v.x * sc.x + sh.x, 0.f);
  v.y = fmaxf(v.y * sc.y + sh.y, 0.f);
  v.z = fmaxf(v.z * sc.z + sh.z, 0.f);
  v.w = fmaxf(v.w * sc.w + sh.w, 0.f);
  ((float4*)X)[i] = v;
}

// ============================================================================
// bf16-split MFMA GEMM (3 terms): C[M,N] = A[M,K]*B[N,K]^T (+bias+relu).
// Tile 128x64, BK=32. 1D grid with XCD-aware tile mapping: xcd = bid&7 owns
// nTM/8 contiguous m-tiles x all n-tiles (A-slab stays in that XCD's L2).
// Requires (M/128) % 8 == 0.
// ============================================================================
template <int BIASRELU>
__global__ __launch_bounds__(256) void gemm_bf16q_kernel(
    const uint32_t* __restrict__ A, const uint32_t* __restrict__ B,
    const float* __restrict__ bias, float* __restrict__ C, int M, int N, int K) {
  __shared__ short Ah[128 * 32], Al[128 * 32], Bh[64 * 32], Bl[64 * 32];
  const int t = threadIdx.x;
  const int nTN = N >> 6;
  const int mPer = (M >> 7) >> 3;
  const int bid = blockIdx.x;
  const int xcd = bid & 7, qq = bid >> 3;
  const int m0 = (xcd * mPer + qq / nTN) << 7;
  const int n0 = (qq % nTN) << 6;
  const int w = t >> 6, l = t & 63;
  const int wrow = (w >> 1) << 6, wcol = (w & 1) << 5;
  const int lr = l & 15, lg = l >> 4;
  const int ar = t >> 1, akh = (t & 1) << 4;
  const int br = t >> 2, bkh = (t & 3) << 3;
  const int asw = (ar & 3) << 3, bsw = (br & 3) << 3;
  const uint32_t* Ap = A + (size_t)(m0 + ar) * K + akh;
  const uint32_t* Bp = B + (size_t)(n0 + br) * K + bkh;
  f32x4 acc[4][2];
#pragma unroll
  for (int i = 0; i < 4; i++)
#pragma unroll
    for (int j = 0; j < 2; j++) acc[i][j] = (f32x4){0.f, 0.f, 0.f, 0.f};
  uint4 ra0 = *(const uint4*)(Ap + 0), ra1 = *(const uint4*)(Ap + 4);
  uint4 ra2 = *(const uint4*)(Ap + 8), ra3 = *(const uint4*)(Ap + 12);
  uint4 rb0 = *(const uint4*)(Bp + 0), rb1 = *(const uint4*)(Bp + 4);
  const int NS = K >> 5;
  for (int s = 0; s < NS; s++) {
    __syncthreads();
#define STORE_G(ARR_H, ARR_L, ROW, KB, SW, U)                                   \
    {                                                                           \
      uint32_t h0 = (U.x >> 16) | (U.y & 0xffff0000u);                          \
      uint32_t h1 = (U.z >> 16) | (U.w & 0xffff0000u);                          \
      uint32_t l0 = (U.x & 0xffffu) | (U.y << 16);                              \
      uint32_t l1 = (U.z & 0xffffu) | (U.w << 16);                              \
      int idx = (ROW) * 32 + ((KB) ^ (SW));                                     \
      *(uint2*)&ARR_H[idx] = make_uint2(h0, h1);                                \
      *(uint2*)&ARR_L[idx] = make_uint2(l0, l1);                                \
    }
    STORE_G(Ah, Al, ar, akh + 0, asw, ra0)
    STORE_G(Ah, Al, ar, akh + 4, asw, ra1)
    STORE_G(Ah, Al, ar, akh + 8, asw, ra2)
    STORE_G(Ah, Al, ar, akh + 12, asw, ra3)
    STORE_G(Bh, Bl, br, bkh + 0, bsw, rb0)
    STORE_G(Bh, Bl, br, bkh + 4, bsw, rb1)
#undef STORE_G
    __syncthreads();
    if (s + 1 < NS) {
      int ko = (s + 1) << 5;
      ra0 = *(const uint4*)(Ap + ko); ra1 = *(const uint4*)(Ap + ko + 4);
      ra2 = *(const uint4*)(Ap + ko + 8); ra3 = *(const uint4*)(Ap + ko + 12);
      rb0 = *(const uint4*)(Bp + ko); rb1 = *(const uint4*)(Bp + ko + 4);
    }
    short8 ahf[4], alf[4], bhf[2], blf[2];
#pragma unroll
    for (int i = 0; i < 4; i++) {
      int R = wrow + i * 16 + lr;
      int kk = (lg << 3) ^ ((R & 3) << 3);
      ahf[i] = *(const short8*)&Ah[R * 32 + kk];
      alf[i] = *(const short8*)&Al[R * 32 + kk];
    }
#pragma unroll
    for (int j = 0; j < 2; j++) {
      int Cc = wcol + j * 16 + lr;
      int kk = (lg << 3) ^ ((Cc & 3) << 3);
      bhf[j] = *(const short8*)&Bh[Cc * 32 + kk];
      blf[j] = *(const short8*)&Bl[Cc * 32 + kk];
    }
#pragma unroll
    for (int i = 0; i < 4; i++)
#pragma unroll
      for (int j = 0; j < 2; j++) {
        acc[i][j] = __builtin_amdgcn_mfma_f32_16x16x32_bf16(ahf[i], bhf[j], acc[i][j], 0, 0, 0);
        acc[i][j] = __builtin_amdgcn_mfma_f32_16x16x32_bf16(ahf[i], blf[j], acc[i][j], 0, 0, 0);
        acc[i][j] = __builtin_amdgcn_mfma_f32_16x16x32_bf16(alf[i], bhf[j], acc[i][j], 0, 0, 0);
      }
  }
#pragma unroll
  for (int i = 0; i < 4; i++)
#pragma unroll
    for (int j = 0; j < 2; j++) {
      int n = n0 + wcol + j * 16 + lr;
#pragma unroll
      for (int r = 0; r < 4; r++) {
        int m = m0 + wrow + i * 16 + lg * 4 + r;
        float v = acc[i][j][r];
        if (BIASRELU) v = fmaxf(v + bias[n], 0.f);
        C[(size_t)m * N + n] = v;
      }
    }
}

// ============================================================================
// heads (double accumulation; sw_logits amplified 10x by TAU)
// ============================================================================
__global__ __launch_bounds__(256) void heads_kernel(
    const float* __restrict__ dpen, const float* __restrict__ dfc_w,
    const float* __restrict__ dfc_b, const float* __restrict__ sw_w,
    const float* __restrict__ sw_b, float* __restrict__ out_dom,
    float* __restrict__ swbuf) {
  int t = blockIdx.x * 256 + threadIdx.x;
  int b = t >> 2, j = t & 3;
  const float* row = dpen + (size_t)b * 384;
  const float* wr = (j < 2) ? (dfc_w + j * 384) : (sw_w + (j - 2) * 384);
  double s = 0.0;
  for (int k = 0; k < 384; k++) s += (double)row[k] * (double)wr[k];
  s += (double)((j < 2) ? dfc_b[j] : sw_b[j - 2]);
  if (j < 2) out_dom[b * 2 + j] = (float)s;
  else swbuf[b * 2 + (j - 2)] = (float)s;
}

// ============================================================================
// gumbel-softmax + categorical partition choice (threefry partitionable).
// ============================================================================
__global__ __launch_bounds__(256) void partition_kernel(
    const float* __restrict__ swbuf, float* __restrict__ out_pid,
    int* __restrict__ pidxI, float* __restrict__ ysum,
    uint32_t k1a, uint32_t k1b, uint32_t k2a, uint32_t k2b) {
  int b = blockIdx.x * 256 + threadIdx.x;
  if (b >= 4096) return;
  uint32_t j0 = (uint32_t)(2 * b), j1 = (uint32_t)(2 * b + 1);
  float f0 = u01_from_bits(tf_bits32(k1a, k1b, j0));
  float f1 = u01_from_bits(tf_bits32(k1a, k1b, j1));
  const float MINV = 1e-10f;
  float u0 = fmaxf(MINV, f0 * (1.0f - MINV) + MINV);
  float u1 = fmaxf(MINV, f1 * (1.0f - MINV) + MINV);
  double g0 = -log(-log((double)u0));
  double g1 = -log(-log((double)u1));
  double s0 = (double)swbuf[2 * b], s1 = (double)swbuf[2 * b + 1];
  double x0 = (s0 + g0) / 0.1;
  double x1 = (s1 + g1) / 0.1;
  double mx = fmax(x0, x1);
  double e0 = exp(x0 - mx), e1 = exp(x1 - mx);
  double es = e0 + e1;
  double y0 = e0 / es, y1 = e1 / es;
  float h0 = u01_from_bits(tf_bits32(k2a, k2b, j0));
  float h1 = u01_from_bits(tf_bits32(k2a, k2b, j1));
  const float TINY = 1.17549435e-38f;
  float v0 = fmaxf(TINY, h0 * (1.0f - TINY) + TINY);
  float v1 = fmaxf(TINY, h1 * (1.0f - TINY) + TINY);
  double gg0 = -log(-log((double)v0));
  double gg1 = -log(-log((double)v1));
  double l0 = log(y0 + 1e-20) + gg0;
  double l1 = log(y1 + 1e-20) + gg1;
  int p = (l1 > l0) ? 1 : 0;
  out_pid[b] = (float)p;
  pidxI[b] = p;
  ysum[b] = (float)(y0 + y1);
}

// ============================================================================
// final head
// ============================================================================
__global__ __launch_bounds__(256) void final_kernel(
    const float* __restrict__ h, const float* __restrict__ p2w,
    const float* __restrict__ p2b, const int* __restrict__ pidxI,
    const float* __restrict__ ysum, float* __restrict__ out0) {
  int t = blockIdx.x * 256 + threadIdx.x;
  if (t >= 40960) return;
  int b = t / 10, c = t % 10;
  int p = pidxI[b];
  const float* hr = h + (size_t)b * 384 + p * 192;
  const float* wr = p2w + ((size_t)p * 10 + c) * 192;
  float s = 0.f;
  for (int o = 0; o < 192; o++) s += hr[o] * wr[o];
  s += p2b[p * 10 + c];
  out0[t] = s * ysum[b];
}

// ============================================================================
// Launch orchestration. All big matmuls on MFMA (3-term bf16 split).
// ~235 MB workspace (proven layout).
// ============================================================================
extern "C" void kernel_launch(void* const* d_in, const int* in_sizes, int n_in,
                              void* d_out, int out_size, void* d_ws, size_t ws_size,
                              hipStream_t stream) {
  const float* input   = (const float*)d_in[0];
  const float* conv1_w = (const float*)d_in[1];
  const float* bn1_g   = (const float*)d_in[3];
  const float* bn1_b   = (const float*)d_in[4];
  const float* conv2_w = (const float*)d_in[5];
  const float* bn2_g   = (const float*)d_in[7];
  const float* bn2_b   = (const float*)d_in[8];
  const float* conv3_w = (const float*)d_in[9];
  const float* bn3_g   = (const float*)d_in[11];
  const float* bn3_b   = (const float*)d_in[12];
  const float* pre_w   = (const float*)d_in[13];
  const float* bnp_g   = (const float*)d_in[15];
  const float* bnp_b   = (const float*)d_in[16];
  const float* disc_w  = (const float*)d_in[17];
  const float* bnd_g   = (const float*)d_in[19];
  const float* bnd_b   = (const float*)d_in[20];
  const float* dfc_w   = (const float*)d_in[21];
  const float* dfc_b   = (const float*)d_in[22];
  const float* sw_w    = (const float*)d_in[23];
  const float* sw_b    = (const float*)d_in[24];
  const float* p1_w    = (const float*)d_in[25];
  const float* p1_b    = (const float*)d_in[26];
  const float* p2_w    = (const float*)d_in[27];
  const float* p2_b    = (const float*)d_in[28];

  float* W = (float*)d_ws;
  float* pool1  = W + 0;           // [4096][32][16][16], raw -> packed in place
  uint32_t* pool1q = (uint32_t*)pool1;
  float* pool2  = W + 33554432;    // [4096][64][8][8], raw -> packed in place
  uint32_t* pool2q = (uint32_t*)pool2;
  float* act3   = W + 0;           // [4096][128][8][8], alias pool1 (dead)
  uint32_t* Acvt = (uint32_t*)(W + 0);          // act3 packed in place
  uint32_t* Bcvt = (uint32_t*)(W + 33554432);   // pre_w packed (pool2q dead then)
  uint32_t* discq = (uint32_t*)(W + 41943040);  // disc_w packed (dead region)
  uint32_t* p1q   = (uint32_t*)(W + 42336256);  // p1_w packed
  float* featp  = W + 50331648;    // [4096][1024], raw -> packed in place
  uint32_t* featq = (uint32_t*)featp;
  short* wh3    = (short*)(W + 50331648);       // conv3 w hi (dead until pre-FC)
  short* wl3    = (short*)(W + 50368512);
  short* wh2    = (short*)(W + 50405376);       // conv2 w hi
  short* wl2    = (short*)(W + 50414592);
  float* dpen   = W + 54525952;
  float* hbuf   = W + 56098816;
  float* swbuf  = W + 57671680;
  float* ysum   = W + 57679872;
  int*   pidxI  = (int*)(W + 57683968);
  float* part   = W + 57688064;
  double* sums  = (double*)(W + 58736640);
  float* scale  = W + 58769408;
  float* shift  = W + 58770432;

  float* out_cls = (float*)d_out;
  float* out_dom = out_cls + 40960;
  float* out_pid = out_cls + 49152;

  uint32_t k1a, k1b, k2a, k2b;
  threefry2x32(0u, 42u, 0u, 0u, k1a, k1b);
  threefry2x32(0u, 42u, 0u, 1u, k2a, k2b);

  // --- conv1 fused + BN + pack ---
  conv1_fused_kernel<<<dim3(4096), dim3(256), 0, stream>>>(input, conv1_w, pool1, part);
  reduce_partials_kernel<<<dim3(64), dim3(256), 0, stream>>>(part, 4096, 64, sums);
  bn_finalize_kernel<<<dim3(1), dim3(64), 0, stream>>>(sums, 1, 0, bn1_g, bn1_b, scale, shift, 32, 1.0 / (4096.0 * 1024.0));
  bn_relu_pack_vec4_kernel<8, 31><<<dim3(32768), dim3(256), 0, stream>>>(pool1, scale, shift, 8388608);

  // --- conv2 via MFMA (fused pool) + BN + pack ---
  prep_w2_kernel<<<dim3(72), dim3(256), 0, stream>>>(conv2_w, wh2, wl2);
  conv2_mfma_kernel<<<dim3(4096), dim3(256), 0, stream>>>(pool1q, wh2, wl2, pool2, part);
  reduce_partials_kernel<<<dim3(128), dim3(256), 0, stream>>>(part, 4096, 128, sums);
  bn_finalize_kernel<<<dim3(1), dim3(64), 0, stream>>>(sums, 1, 0, bn2_g, bn2_b, scale, shift, 64, 1.0 / (4096.0 * 256.0));
  bn_relu_pack_vec4_kernel<6, 63><<<dim3(16384), dim3(256), 0, stream>>>(pool2, scale, shift, 4194304);

  // --- conv3 via MFMA + BN + pack ---
  prep_w3_kernel<<<dim3(288), dim3(256), 0, stream>>>(conv3_w, wh3, wl3);
  conv3_mfma_kernel<<<dim3(4096), dim3(256), 0, stream>>>(pool2q, wh3, wl3, act3, part);
  reduce_partials_kernel<<<dim3(256), dim3(256), 0, stream>>>(part, 4096, 256, sums);
  bn_finalize_kernel<<<dim3(1), dim3(128), 0, stream>>>(sums, 1, 0, bn3_g, bn3_b, scale, shift, 128, 1.0 / (4096.0 * 64.0));
  bn_relu_pack_vec4_kernel<6, 127><<<dim3(32768), dim3(256), 0, stream>>>(act3, scale, shift, 8388608);

  // --- pre FC 8192->1024 via MFMA + BN + ReLU + pack ---
  cvt_bf16q_kernel<<<dim3(8192), dim3(256), 0, stream>>>(pre_w, Bcvt, 2097152);
  gemm_bf16q_kernel<0><<<dim3(512), dim3(256), 0, stream>>>(Acvt, Bcvt, (const float*)nullptr, featp, 4096, 1024, 8192);
  col_stats_kernel<<<dim3(16, 8), dim3(1024), 0, stream>>>(featp, 4096, 1024, 8, sums);
  bn_finalize_kernel<<<dim3(4), dim3(256), 0, stream>>>(sums, 8, 2048, bnp_g, bnp_b, scale, shift, 1024, 1.0 / 4096.0);
  bn_relu_pack_cols4_kernel<<<dim3(4096), dim3(256), 0, stream>>>(featp, scale, shift, 1048576, 256);

  // --- disc FC 1024->384 via MFMA + BN + ReLU (fp32 out for heads) ---
  cvt_bf16q_kernel<<<dim3(384), dim3(256), 0, stream>>>(disc_w, discq, 98304);
  cvt_bf16q_kernel<<<dim3(384), dim3(256), 0, stream>>>(p1_w, p1q, 98304);
  gemm_bf16q_kernel<0><<<dim3(192), dim3(256), 0, stream>>>(featq, discq, (const float*)nullptr, dpen, 4096, 384, 1024);
  col_stats_kernel<<<dim3(6, 8), dim3(1024), 0, stream>>>(dpen, 4096, 384, 8, sums);
  bn_finalize_kernel<<<dim3(2), dim3(256), 0, stream>>>(sums, 8, 768, bnd_g, bnd_b, scale, shift, 384, 1.0 / 4096.0);
  bn_relu_cols4_kernel<<<dim3(1536), dim3(256), 0, stream>>>(dpen, scale, shift, 393216, 96);

  // --- heads + partition sampling ---
  heads_kernel<<<dim3(64), dim3(256), 0, stream>>>(dpen, dfc_w, dfc_b, sw_w, sw_b, out_dom, swbuf);
  partition_kernel<<<dim3(16), dim3(256), 0, stream>>>(swbuf, out_pid, pidxI, ysum, k1a, k1b, k2a, k2b);

  // --- experts: p1 via MFMA (bias+relu epilogue), then gather + p2 ---
  gemm_bf16q_kernel<1><<<dim3(192), dim3(256), 0, stream>>>(featq, p1q, p1_b, hbuf, 4096, 384, 1024);
  final_kernel<<<dim3(160), dim3(256), 0, stream>>>(hbuf, p2_w, p2_b, pidxI, ysum, out_cls);
}